// Round 5
// baseline (544.725 us; speedup 1.0000x reference)
//
#include <hip/hip_runtime.h>
#include <hip/hip_bf16.h>

#define B_ 4096
#define T_ 2
#define S_ 4
#define E_ 128
#define NF_ 11
#define ID_ 55
#define MID_ 4
#define NG_ 6
#define SI_ 4
#define EPSf 1e-5f

// triu_indices(11, k=1) pairs, padded to 64 rows (rows 55..63: PR=PC=0, masked by iw=0)
__device__ const int PR[64]={0,0,0,0,0,0,0,0,0,0,1,1,1,1,1,1,1,1,1,2,2,2,2,2,2,2,2,3,3,3,3,3,3,3,4,4,4,4,4,4,5,5,5,5,5,6,6,6,6,7,7,7,8,8,9,0,0,0,0,0,0,0,0,0};
__device__ const int PC[64]={1,2,3,4,5,6,7,8,9,10,2,3,4,5,6,7,8,9,10,3,4,5,6,7,8,9,10,4,5,6,7,8,9,10,5,6,7,8,9,10,6,7,8,9,10,7,8,9,10,8,9,10,9,10,10,0,0,0,0,0,0,0,0,0};

// -------- prep: unified weight matrices Wu/lWu [64 rows][128 k] -------------
// rows 0-47: gate (st*6+g) E-part; rows 48-61: sb_W; rows 62-63: zero
__global__ void k_prep(const float* __restrict__ gW, const float* __restrict__ lgW,
                       const float* __restrict__ sbW, const float* __restrict__ lsbW,
                       float* __restrict__ Wu, float* __restrict__ lWu){
  int k = blockIdx.x*256 + threadIdx.x;
  if (k < 16384){
    int arr = k >> 13, rem = k & 8191;
    int o = rem >> 7, e = rem & 127;
    const float* g = arr ? lgW : gW;
    const float* s = arr ? lsbW : sbW;
    float v;
    if (o < 48) v = g[o*132 + 4 + e];
    else if (o < 62) v = s[(o-48)*128 + e];
    else v = 0.f;
    (arr ? lWu : Wu)[o*128 + e] = v;
  }
}

// -------- fields: gathers + user/item projections ---------------------------
__global__ __launch_bounds__(128) void k_fields(
    const int* __restrict__ cat, const float* __restrict__ num,
    const float* __restrict__ embT, const float* __restrict__ linT,
    const float* __restrict__ uW, const float* __restrict__ ub,
    const float* __restrict__ iW, const float* __restrict__ ib,
    const float* __restrict__ ulW, const float* __restrict__ ulb,
    const float* __restrict__ ilW, const float* __restrict__ ilb,
    float* __restrict__ fields, float* __restrict__ lfields)
{
  const int b = blockIdx.x, e = threadIdx.x;
  __shared__ float s_num[63];
  if (e < 63) s_num[e] = num[(size_t)b*63 + e];
  __syncthreads();
  const int* cb = cat + (size_t)b*10;
  float* fo = fields  + (size_t)b*NF_*E_;
  float* lo = lfields + (size_t)b*NF_*E_;
  for (int j = 0; j < 9; ++j){
    int id = cb[1+j] + j*1000;
    fo[j*E_+e] = embT[(size_t)id*E_+e];
    lo[j*E_+e] = linT[(size_t)id*E_+e];
  }
  float a0 = ub[e], a1 = ulb[e];
  for (int k = 0; k < 23; ++k){ float x = s_num[k]; a0 += x*uW[e*23+k]; a1 += x*ulW[e*23+k]; }
  fo[9*E_+e] = a0; lo[9*E_+e] = a1;
  float a2 = ib[e], a3 = ilb[e];
  for (int k = 0; k < 40; ++k){ float x = s_num[23+k]; a2 += x*iW[e*40+k]; a3 += x*ilW[e*40+k]; }
  fo[10*E_+e] = a2; lo[10*E_+e] = a3;
}

// -------- moe1: split-pipe GEMM -> softmax/experts -> w_g -------------------
// R3 structure (ct=tid>>5 col-tiles, rt=tid&31 row-pairs, acc[2][8]), but Wu
// reads come from GLOBAL (vmcnt/VMEM pipe, L1-resident 32KB) instead of LDS:
// LDS pipe carries only the 4 fld b128/k4 (3x fewer LDS instrs), and vmcnt is
// independent of lgkmcnt (no R4-style cross-drain). No s_Wu staging/overlay.
// LDS floats: s_fld 1452 | s_stig 48 | s_C 64x69=4416 | s_w 1760 | s_sh 935
//   total 8611 (33.6 KB) -> 4 blk/CU
__global__ __launch_bounds__(256) void k_moe1(
    const int* __restrict__ cat,
    const float* __restrict__ scen_emb, const float* __restrict__ task_emb,
    const float* __restrict__ st_w, const float* __restrict__ interact_w,
    const float* __restrict__ sb_b,
    const float* __restrict__ shexp_W, const float* __restrict__ shexp_b,
    const float* __restrict__ spexp_W, const float* __restrict__ spexp_b,
    const float* __restrict__ gate_W, const float* __restrict__ gate_b,
    const float* __restrict__ fields, const float* __restrict__ Wu,
    float* __restrict__ w_g)
{
  __shared__ float sm[8611];
  float* s_fld = sm;           // 11 x 132
  float* s_stig= sm + 1452;    // 48
  float* s_C   = sm + 1500;    // 64 x 69
  float* s_w   = sm + 5916;    // 8 x 220
  float* s_sh  = sm + 7676;    // 55 x 17
  const int tid = threadIdx.x, b = blockIdx.x;
  const int scen = cat[(size_t)b*10];

  // stage fields (stride 132) + stig
  for (int idx = tid; idx < 352; idx += 256){
    int f = idx >> 5, q = idx & 31;
    *(float4*)&s_fld[f*132 + q*4] = *(const float4*)&fields[(size_t)b*1408 + idx*4];
  }
  if (tid < 48){
    int st = tid/6, t = (tid/6)%T_;
    float stw = st_w[t*S_ + scen];
    float acc = gate_b[tid];
    for (int i = 0; i < 4; ++i){
      float sti = scen_emb[scen*4+i] * task_emb[t*4+i] * stw;
      acc += sti * gate_W[tid*132 + i];
    }
    s_stig[tid] = acc;
  }
  __syncthreads();

  // GEMM: each thread owns rows {2rt, 2rt+1} x cols [8ct, 8ct+8), full K=128
  {
    const int ct = tid >> 5;          // 0..7
    const int rt = tid & 31;          // 0..31
    const int r0 = rt*2;
    const int ra0 = PR[r0]*132,   ca0 = PC[r0]*132;
    const int ra1 = PR[r0+1]*132, ca1 = PC[r0+1]*132;
    float acc[2][8];
    for (int c = 0; c < 8; ++c){ acc[0][c] = 0.f; acc[1][c] = 0.f; }
    const float4* __restrict__ Wu4 = (const float4*)Wu;   // global, L1-resident
    #pragma unroll 1
    for (int kk = 0; kk < 128; kk += 4){
      int wb = kk >> 2;
      float4 x0 = *(const float4*)&s_fld[ra0 + kk];
      float4 y0 = *(const float4*)&s_fld[ca0 + kk];
      float4 x1 = *(const float4*)&s_fld[ra1 + kk];
      float4 y1 = *(const float4*)&s_fld[ca1 + kk];
      float4 p0, p1;
      p0.x = x0.x*y0.x; p0.y = x0.y*y0.y; p0.z = x0.z*y0.z; p0.w = x0.w*y0.w;
      p1.x = x1.x*y1.x; p1.y = x1.y*y1.y; p1.z = x1.z*y1.z; p1.w = x1.w*y1.w;
      for (int h = 0; h < 2; ++h){
        float4 wv[4];
        for (int c = 0; c < 4; ++c) wv[c] = Wu4[(ct*8 + h*4 + c)*32 + wb];
        for (int c = 0; c < 4; ++c){
          acc[0][h*4+c] += p0.x*wv[c].x + p0.y*wv[c].y + p0.z*wv[c].z + p0.w*wv[c].w;
          acc[1][h*4+c] += p1.x*wv[c].x + p1.y*wv[c].y + p1.z*wv[c].z + p1.w*wv[c].w;
        }
      }
    }
    for (int r = 0; r < 2; ++r){
      int row = r0 + r;
      float iw = (row < 55) ? interact_w[row] : 0.f;  // iw distributes out of K-sum
      for (int c = 0; c < 8; ++c){
        int col = ct*8 + c;
        float bias = (col < 48) ? s_stig[col] : ((col < 62) ? sb_b[col-48] : 0.f);
        s_C[row*69 + col] = acc[r][c]*iw + bias;
      }
    }
  }
  __syncthreads();
  // shared experts: sh[f][g*4+m] over ein = C[f][48..61]
  for (int o = tid; o < 880; o += 256){
    int f = o >> 4, j = o & 15;
    float acc = shexp_b[j];
    const float* ein = &s_C[f*69 + 48];
    const float* wp = &shexp_W[j*14];
    for (int i = 0; i < 14; ++i) acc += ein[i] * wp[i];
    s_sh[f*17 + j] = acc;
  }
  __syncthreads();
  // softmax + specific experts + mixture
  for (int task = tid; task < 440; task += 256){
    int st = task / 55, f = task % 55;
    float ein[14];
    for (int i = 0; i < 14; ++i) ein[i] = s_C[f*69 + 48 + i];
    float lg[6], mx = -1e30f;
    for (int g = 0; g < 6; ++g){ lg[g] = s_C[f*69 + st*6 + g]; mx = fmaxf(mx, lg[g]); }
    float sum = 0.f;
    for (int g = 0; g < 6; ++g){ lg[g] = __expf(lg[g]-mx); sum += lg[g]; }
    float inv = 1.f/sum;
    float wv[4] = {0,0,0,0};
    for (int g = 0; g < 4; ++g){
      float gg = lg[g]*inv;
      for (int m = 0; m < 4; ++m) wv[m] += gg * s_sh[f*17 + g*4 + m];
    }
    for (int ee = 0; ee < 2; ++ee){
      float gg = lg[4+ee]*inv;
      for (int m = 0; m < 4; ++m){
        float acc = spexp_b[(st*2+ee)*4+m];
        const float* wp = spexp_W + ((st*2+ee)*4+m)*14;
        for (int i = 0; i < 14; ++i) acc += ein[i] * wp[i];
        wv[m] += gg*acc;
      }
    }
    float4 o4; o4.x = wv[0]; o4.y = wv[1]; o4.z = wv[2]; o4.w = wv[3];
    *(float4*)&s_w[st*220 + f*4] = o4;
  }
  __syncthreads();
  // write w_g[b][st][224] (zero-padded cols 220..223), coalesced f4
  for (int idx = tid; idx < 448; idx += 256){
    int st = idx / 56, q = idx % 56;
    float4 v;
    if (q < 55) v = *(float4*)&s_w[st*220 + q*4];
    else { v.x=v.y=v.z=v.w=0.f; }
    *(float4*)&w_g[((size_t)b*8 + st)*224 + q*4] = v;
  }
}

// -------- mask batch GEMM: m1[st*55+oo][b] = mW[st] x w^T + mb --------------
// grid: 512 blocks = 8 st x 64 b-tiles(64). LDS: s_mw[56*116] + s_wb[64*116]
__global__ __launch_bounds__(256) void k_mask(
    const float* __restrict__ w_g, const float* __restrict__ mask_W,
    const float* __restrict__ mask_b, float* __restrict__ m1)
{
  __shared__ float s_mw[56*116];
  __shared__ float s_wb[64*116];
  const int tid = threadIdx.x;
  const int st = blockIdx.x >> 6, bt = blockIdx.x & 63;
  const int b0 = bt*64;
  const int btl = tid & 15, ot = tid >> 4;   // ot<14 active
  float acc[4][4];
  for (int c = 0; c < 4; ++c) for (int j = 0; j < 4; ++j) acc[c][j] = 0.f;

  for (int kc = 0; kc < 2; ++kc){
    __syncthreads();
    for (int idx = tid; idx < 64*112; idx += 256){
      int r = idx / 112, k = idx % 112;
      s_wb[r*116 + k] = w_g[((size_t)(b0+r)*8 + st)*224 + kc*112 + k];
    }
    for (int idx = tid; idx < 56*112; idx += 256){
      int r = idx / 112, k = idx % 112;
      int kg = kc*112 + k;
      s_mw[r*116 + k] = (r < 55 && kg < 220) ? mask_W[((size_t)st*55 + r)*220 + kg] : 0.f;
    }
    __syncthreads();
    if (ot < 14){
      for (int k4 = 0; k4 < 112; k4 += 4){
        float4 a[4], wb[4];
        for (int c = 0; c < 4; ++c) a[c]  = *(float4*)&s_mw[(ot*4+c)*116 + k4];
        for (int j = 0; j < 4; ++j) wb[j] = *(float4*)&s_wb[(btl*4+j)*116 + k4];
        for (int c = 0; c < 4; ++c)
          for (int j = 0; j < 4; ++j)
            acc[c][j] += a[c].x*wb[j].x + a[c].y*wb[j].y + a[c].z*wb[j].z + a[c].w*wb[j].w;
      }
    }
  }
  if (ot < 14){
    for (int c = 0; c < 4; ++c){
      int row = ot*4 + c;
      if (row < 55){
        float mb = mask_b[st*55 + row];
        float4 v; v.x = acc[c][0]+mb; v.y = acc[c][1]+mb; v.z = acc[c][2]+mb; v.w = acc[c][3]+mb;
        *(float4*)&m1[(size_t)(st*55+row)*B_ + b0 + btl*4] = v;
      }
    }
  }
}

// -------- per-row batch stats (mean, rsqrt(var+eps)) ------------------------
__global__ __launch_bounds__(256) void k_stats(const float* __restrict__ x, float* __restrict__ stats){
  const int row = blockIdx.x, tid = threadIdx.x;
  const float* xr = x + (size_t)row*B_;
  float s = 0.f, s2 = 0.f;
  for (int i = tid; i < B_; i += 256){ float v = xr[i]; s += v; s2 += v*v; }
  for (int off = 32; off > 0; off >>= 1){ s += __shfl_down(s, off); s2 += __shfl_down(s2, off); }
  __shared__ float red[8];
  if ((tid & 63) == 0){ red[(tid>>6)*2] = s; red[(tid>>6)*2+1] = s2; }
  __syncthreads();
  if (tid == 0){
    float Ssum = red[0]+red[2]+red[4]+red[6], S2 = red[1]+red[3]+red[5]+red[7];
    float mean = Ssum*(1.f/B_), var = S2*(1.f/B_) - mean*mean;
    stats[row*2] = mean; stats[row*2+1] = rsqrtf(fmaxf(var, 0.f) + EPSf);
  }
}

// -------- inter: bn(m)->tanh->relu, weighted pe contraction -> h[:, :128] ---
__global__ __launch_bounds__(128) void k_inter(
    const int* __restrict__ cat, const float* __restrict__ fields,
    const float* __restrict__ m1, const float* __restrict__ stm,
    const float* __restrict__ att_W, const float* __restrict__ interact_w,
    float* __restrict__ hbuf)
{
  __shared__ float s_fld[NF_*E_];
  __shared__ float s_co[110];
  const int b = blockIdx.x, e = threadIdx.x;
  const int scen = cat[(size_t)b*10];
  for (int k = e; k < NF_*E_; k += 128) s_fld[k] = fields[(size_t)b*NF_*E_ + k];
  if (e < 110){
    int t = e/55, f = e%55, row = (scen*T_+t)*55 + f;
    float v = (m1[(size_t)row*B_+b] - stm[row*2]) * stm[row*2+1];
    v = fmaxf(tanhf(v), 0.f);
    s_co[e] = v * att_W[(scen*T_+t)*55 + f];
  }
  __syncthreads();
  float a0 = 0.f, a1 = 0.f;
  for (int f = 0; f < 55; ++f){
    float pe = s_fld[PR[f]*E_+e] * s_fld[PC[f]*E_+e] * interact_w[f];
    a0 += s_co[f]*pe; a1 += s_co[55+f]*pe;
  }
  hbuf[(size_t)(0*256+e)*B_ + b] = a0;
  hbuf[(size_t)(1*256+e)*B_ + b] = a1;
}

// -------- moe2 (linear path, F=11): 4-wave GEMM + experts + ltower ----------
// LDS floats: s_lf[12*132]=1584 | s_C[12*69]=828 | s_w[352] | s_sh[187] | s_stig[48]
__global__ __launch_bounds__(256) void k_moe2(
    const int* __restrict__ cat,
    const float* __restrict__ scen_emb, const float* __restrict__ task_emb, const float* __restrict__ st_w,
    const float* __restrict__ lsb_b,
    const float* __restrict__ lshexp_W, const float* __restrict__ lshexp_b,
    const float* __restrict__ lspexp_W, const float* __restrict__ lspexp_b,
    const float* __restrict__ lgate_W, const float* __restrict__ lgate_b,
    const float* __restrict__ ltower_W, const float* __restrict__ ltower_b,
    const float* __restrict__ lfields, const float* __restrict__ lWu,
    float* __restrict__ lt1)
{
  __shared__ float sm[2999];
  float* s_lf = sm;            // 12 x 132
  float* s_C  = sm + 1584;     // 12 x 69
  float* s_w  = sm + 2412;     // 8 x 44
  float* s_sh = sm + 2764;     // 11 x 17
  float* s_stig = sm + 2951;   // 48
  const int tid = threadIdx.x, b = blockIdx.x;
  const int scen = cat[(size_t)b*10];

  for (int idx = tid; idx < 352; idx += 256){
    int f = idx >> 5, q = idx & 31;
    *(float4*)&s_lf[f*132 + q*4] = *(const float4*)&lfields[(size_t)b*1408 + f*128 + q*4];
  }
  if (tid >= 224){ // zero row 11 (32 threads)
    int q = tid - 224;
    float4 z = {0,0,0,0}; *(float4*)&s_lf[11*132 + q*4] = z;
  }
  if (tid < 48){
    int st = tid/6, t = (tid/6)%T_;
    float stw = st_w[t*S_ + scen];
    float acc = lgate_b[tid];
    for (int i = 0; i < 4; ++i){
      float sti = scen_emb[scen*4+i] * task_emb[t*4+i] * stw;
      acc += sti * lgate_W[tid*132 + i];
    }
    s_stig[tid] = acc;
  }
  __syncthreads();
  // GEMM over all 4 waves: C[12][64] = lf[12][128] * lWu^T
  {
    const int lane = tid & 63, wv_ = tid >> 6;
    const int pr = wv_*16 + (lane & 15);     // 0..63
    const int ks = lane >> 4;                // 4-way K split
    const int ft = pr & 1, ot = pr >> 1;     // 2 row-tiles x 32 col-tiles(2)
    const int r0 = ft*6, k0 = ks*32;
    float acc[6][2];
    for (int r = 0; r < 6; ++r){ acc[r][0] = 0.f; acc[r][1] = 0.f; }
    const float4* W4 = (const float4*)lWu;
    #pragma unroll 1
    for (int kc = 0; kc < 32; kc += 4){
      int kk = k0 + ((kc + ks*8) & 31);
      float4 w0 = W4[(ot*2+0)*32 + (kk>>2)];
      float4 w1 = W4[(ot*2+1)*32 + (kk>>2)];
      for (int r = 0; r < 6; ++r){
        float4 a = *(const float4*)&s_lf[(r0+r)*132 + kk];
        acc[r][0] += a.x*w0.x + a.y*w0.y + a.z*w0.z + a.w*w0.w;
        acc[r][1] += a.x*w1.x + a.y*w1.y + a.z*w1.z + a.w*w1.w;
      }
    }
    for (int r = 0; r < 6; ++r) for (int c = 0; c < 2; ++c){
      float v = acc[r][c];
      v += __shfl_xor(v, 16); v += __shfl_xor(v, 32);
      acc[r][c] = v;
    }
    if (ks == 0){
      for (int r = 0; r < 6; ++r) for (int c = 0; c < 2; ++c){
        int col = ot*2 + c, row = r0 + r;
        float bias = (col < 48) ? s_stig[col] : ((col < 62) ? lsb_b[col-48] : 0.f);
        s_C[row*69 + col] = acc[r][c] + bias;
      }
    }
  }
  __syncthreads();
  if (tid < 176){
    int f = tid >> 4, j = tid & 15;
    float acc = lshexp_b[j];
    const float* ein = &s_C[f*69 + 48];
    for (int i = 0; i < 14; ++i) acc += ein[i] * lshexp_W[j*14+i];
    s_sh[f*17 + j] = acc;
  }
  __syncthreads();
  if (tid < 88){
    int st = tid / 11, f = tid % 11;
    float ein[14];
    for (int i = 0; i < 14; ++i) ein[i] = s_C[f*69 + 48 + i];
    float lg[6], mx = -1e30f;
    for (int g = 0; g < 6; ++g){ lg[g] = s_C[f*69 + st*6 + g]; mx = fmaxf(mx, lg[g]); }
    float sum = 0.f;
    for (int g = 0; g < 6; ++g){ lg[g] = __expf(lg[g]-mx); sum += lg[g]; }
    float inv = 1.f/sum;
    float wv[4] = {0,0,0,0};
    for (int g = 0; g < 4; ++g){
      float gg = lg[g]*inv;
      for (int m = 0; m < 4; ++m) wv[m] += gg * s_sh[f*17 + g*4 + m];
    }
    for (int ee = 0; ee < 2; ++ee){
      float gg = lg[4+ee]*inv;
      for (int m = 0; m < 4; ++m){
        float acc = lspexp_b[(st*2+ee)*4+m];
        const float* wp = lspexp_W + ((st*2+ee)*4+m)*14;
        for (int i = 0; i < 14; ++i) acc += ein[i] * wp[i];
        wv[m] += gg*acc;
      }
    }
    float4 o4; o4.x = wv[0]; o4.y = wv[1]; o4.z = wv[2]; o4.w = wv[3];
    *(float4*)&s_w[st*44 + f*4] = o4;
  }
  __syncthreads();
  if (tid < 88){
    int st = tid / 11, oo = tid % 11;
    float acc = ltower_b[st*11+oo];
    const float* tw = ltower_W + (st*11+oo)*44;
    const float* wp = s_w + st*44;
    for (int i = 0; i < 44; ++i) acc += wp[i] * tw[i];
    lt1[(size_t)(st*11+oo)*B_ + b] = acc;
  }
}

// -------- linf: bn(lt)->softmax over fields, weighted lfields -> h[:,128:] --
__global__ __launch_bounds__(128) void k_linf(
    const int* __restrict__ cat, const float* __restrict__ lfields,
    const float* __restrict__ lt1, const float* __restrict__ stl,
    const float* __restrict__ bias_p, float* __restrict__ hbuf)
{
  __shared__ float s_lf[NF_*E_];
  __shared__ float s_lw[22];
  const int b = blockIdx.x, e = threadIdx.x;
  const int scen = cat[(size_t)b*10];
  for (int k = e; k < NF_*E_; k += 128) s_lf[k] = lfields[(size_t)b*NF_*E_ + k];
  if (e < 22){
    int t = e/11, f = e%11, row = (scen*T_+t)*11 + f;
    s_lw[e] = (lt1[(size_t)row*B_+b] - stl[row*2]) * stl[row*2+1];
  }
  __syncthreads();
  if (e < 2){
    int t = e; float mx = -1e30f;
    for (int f = 0; f < 11; ++f) mx = fmaxf(mx, s_lw[t*11+f]);
    float sum = 0.f;
    for (int f = 0; f < 11; ++f){ float x = __expf(s_lw[t*11+f]-mx); s_lw[t*11+f] = x; sum += x; }
    float inv = 1.f/sum;
    for (int f = 0; f < 11; ++f) s_lw[t*11+f] *= inv;
  }
  __syncthreads();
  for (int t = 0; t < 2; ++t){
    float acc = bias_p[(size_t)(t*S_+scen)*E_ + e];
    for (int f = 0; f < 11; ++f) acc += s_lw[t*11+f] * s_lf[f*E_+e];
    hbuf[(size_t)(t*256+128+e)*B_ + b] = acc;
  }
}

// -------- final MLP ---------------------------------------------------------
__global__ __launch_bounds__(256) void k_last1(const float* __restrict__ hbuf,
    const float* __restrict__ W1, const float* __restrict__ b1, float* __restrict__ h1){
  int bz = blockIdx.x, t = bz/80, r = bz%80, og = r/16, bc = r%16;
  __shared__ float s_w1[8*256];
  int tid = threadIdx.x;
  for (int k = tid; k < 2048; k += 256){
    int oo = k>>8, i = k&255;
    s_w1[k] = W1[(size_t)(t*40 + og*8 + oo)*256 + i];
  }
  __syncthreads();
  int b = bc*256 + tid;
  float acc[8];
  for (int oo = 0; oo < 8; ++oo) acc[oo] = b1[t*40 + og*8 + oo];
  for (int i = 0; i < 256; ++i){
    float hv = hbuf[(size_t)(t*256+i)*B_ + b];
    for (int oo = 0; oo < 8; ++oo) acc[oo] += hv * s_w1[oo*256+i];
  }
  for (int oo = 0; oo < 8; ++oo) h1[(size_t)(t*40 + og*8 + oo)*B_ + b] = acc[oo];
}

__global__ __launch_bounds__(256) void k_last2(const float* __restrict__ h1, const float* __restrict__ st1,
    const float* __restrict__ W2, const float* __restrict__ b2v, float* __restrict__ h2){
  int bz = blockIdx.x, t = bz/16, bc = bz%16, tid = threadIdx.x, b = bc*256 + tid;
  __shared__ float s_w2[1280];
  for (int k = tid; k < 1280; k += 256) s_w2[k] = W2[t*1280 + k];
  __syncthreads();
  float hv[40];
  for (int i = 0; i < 40; ++i){
    int row = t*40 + i;
    hv[i] = fmaxf((h1[(size_t)row*B_+b] - st1[row*2]) * st1[row*2+1], 0.f);
  }
  for (int o = 0; o < 32; ++o){
    float acc = b2v[t*32+o];
    for (int i = 0; i < 40; ++i) acc += hv[i] * s_w2[o*40+i];
    h2[(size_t)(t*32+o)*B_ + b] = acc;
  }
}

__global__ __launch_bounds__(256) void k_last3(const float* __restrict__ h2, const float* __restrict__ st2,
    const float* __restrict__ W3, const float* __restrict__ b3v, float* __restrict__ h3){
  int bz = blockIdx.x, t = bz/16, bc = bz%16, tid = threadIdx.x, b = bc*256 + tid;
  __shared__ float s_w3[256];
  if (tid < 256) s_w3[tid] = W3[t*256 + tid];
  __syncthreads();
  float hv[32];
  for (int i = 0; i < 32; ++i){
    int row = t*32 + i;
    hv[i] = fmaxf((h2[(size_t)row*B_+b] - st2[row*2]) * st2[row*2+1], 0.f);
  }
  for (int o = 0; o < 8; ++o){
    float acc = b3v[t*8+o];
    for (int i = 0; i < 32; ++i) acc += hv[i] * s_w3[o*32+i];
    h3[(size_t)(t*8+o)*B_ + b] = acc;
  }
}

__global__ __launch_bounds__(256) void k_out(const float* __restrict__ h3, const float* __restrict__ st3,
    const float* __restrict__ W4, const float* __restrict__ b4v, float* __restrict__ out){
  int idx = blockIdx.x*256 + threadIdx.x;
  int t = idx / B_, b = idx % B_;
  float acc = b4v[t];
  for (int i = 0; i < 8; ++i){
    int row = t*8 + i;
    float v = fmaxf((h3[(size_t)row*B_+b] - st3[row*2]) * st3[row*2+1], 0.f);
    acc += v * W4[t*8+i];
  }
  out[idx] = 1.f/(1.f + __expf(-acc));
}

extern "C" void kernel_launch(void* const* d_in, const int* in_sizes, int n_in,
                              void* d_out, int out_size, void* d_ws, size_t ws_size,
                              hipStream_t stream)
{
  const int*   cat      = (const int*)  d_in[0];
  const float* num      = (const float*)d_in[1];
  const float* embT     = (const float*)d_in[2];
  const float* linT     = (const float*)d_in[3];
  const float* uW = (const float*)d_in[4];  const float* ub = (const float*)d_in[5];
  const float* iW = (const float*)d_in[6];  const float* ib = (const float*)d_in[7];
  const float* ulW = (const float*)d_in[8]; const float* ulb = (const float*)d_in[9];
  const float* ilW = (const float*)d_in[10];const float* ilb = (const float*)d_in[11];
  const float* scen_emb = (const float*)d_in[12];
  const float* task_emb = (const float*)d_in[13];
  const float* st_w     = (const float*)d_in[14];
  const float* interact_w=(const float*)d_in[15];
  const float* sbW = (const float*)d_in[16]; const float* sbb = (const float*)d_in[17];
  const float* lsbW = (const float*)d_in[18];const float* lsbb = (const float*)d_in[19];
  const float* shW = (const float*)d_in[20]; const float* shb = (const float*)d_in[21];
  const float* spW = (const float*)d_in[22]; const float* spb = (const float*)d_in[23];
  const float* lshW = (const float*)d_in[24];const float* lshb = (const float*)d_in[25];
  const float* lspW = (const float*)d_in[26];const float* lspb = (const float*)d_in[27];
  const float* gW = (const float*)d_in[28];  const float* gb = (const float*)d_in[29];
  const float* lgW = (const float*)d_in[30]; const float* lgb = (const float*)d_in[31];
  const float* mW = (const float*)d_in[32];  const float* mb = (const float*)d_in[33];
  const float* attW = (const float*)d_in[34];
  const float* ltW = (const float*)d_in[35]; const float* ltb = (const float*)d_in[36];
  const float* biasP = (const float*)d_in[37];
  const float* W1 = (const float*)d_in[38];  const float* b1 = (const float*)d_in[39];
  const float* W2 = (const float*)d_in[40];  const float* b2v = (const float*)d_in[41];
  const float* W3 = (const float*)d_in[42];  const float* b3v = (const float*)d_in[43];
  const float* W4 = (const float*)d_in[44];  const float* b4v = (const float*)d_in[45];
  float* out = (float*)d_out;

  float* ws = (float*)d_ws;
  size_t o = 0;
  float* fieldsB  = ws + o; o += (size_t)B_*NF_*E_;
  float* lfieldsB = ws + o; o += (size_t)B_*NF_*E_;
  float* Wu   = ws + o; o += 8192;
  float* lWu  = ws + o; o += 8192;
  float* w_g  = ws + o; o += (size_t)B_*8*224;
  float* m1   = ws + o; o += (size_t)440*B_;
  float* stm  = ws + o; o += 880;
  float* lt1  = ws + o; o += (size_t)88*B_;
  float* stl  = ws + o; o += 176;
  float* hbuf = ws + o; o += (size_t)T_*256*B_;
  float* h1   = ws + o; o += (size_t)80*B_;
  float* st1  = ws + o; o += 160;
  float* h2   = ws + o; o += (size_t)64*B_;
  float* st2  = ws + o; o += 128;
  float* h3   = ws + o; o += (size_t)16*B_;
  float* st3  = ws + o; o += 32;

  k_prep<<<64, 256, 0, stream>>>(gW, lgW, sbW, lsbW, Wu, lWu);
  k_fields<<<B_, 128, 0, stream>>>(cat, num, embT, linT, uW, ub, iW, ib, ulW, ulb, ilW, ilb, fieldsB, lfieldsB);
  k_moe1<<<B_, 256, 0, stream>>>(cat, scen_emb, task_emb, st_w, interact_w, sbb, shW, shb,
                                 spW, spb, gW, gb, fieldsB, Wu, w_g);
  k_mask<<<512, 256, 0, stream>>>(w_g, mW, mb, m1);
  k_stats<<<440, 256, 0, stream>>>(m1, stm);
  k_inter<<<B_, 128, 0, stream>>>(cat, fieldsB, m1, stm, attW, interact_w, hbuf);
  k_moe2<<<B_, 256, 0, stream>>>(cat, scen_emb, task_emb, st_w, lsbb, lshW, lshb,
                                 lspW, lspb, lgW, lgb, ltW, ltb, lfieldsB, lWu, lt1);
  k_stats<<<88, 256, 0, stream>>>(lt1, stl);
  k_linf<<<B_, 128, 0, stream>>>(cat, lfieldsB, lt1, stl, biasP, hbuf);
  k_last1<<<160, 256, 0, stream>>>(hbuf, W1, b1, h1);
  k_stats<<<80, 256, 0, stream>>>(h1, st1);
  k_last2<<<32, 256, 0, stream>>>(h1, st1, W2, b2v, h2);
  k_stats<<<64, 256, 0, stream>>>(h2, st2);
  k_last3<<<32, 256, 0, stream>>>(h2, st2, W3, b3v, h3);
  k_stats<<<16, 256, 0, stream>>>(h3, st3);
  k_out<<<32, 256, 0, stream>>>(h3, st3, W4, b4v, out);
}

// Round 6
// 487.549 us; speedup vs baseline: 1.1173x; 1.1173x over previous
//
#include <hip/hip_runtime.h>
#include <hip/hip_bf16.h>

#define B_ 4096
#define T_ 2
#define S_ 4
#define E_ 128
#define NF_ 11
#define ID_ 55
#define MID_ 4
#define NG_ 6
#define SI_ 4
#define EPSf 1e-5f

// triu_indices(11, k=1) pairs, padded to 64 rows (rows 55..63: PR=PC=0, masked by iw=0)
__device__ const int PR[64]={0,0,0,0,0,0,0,0,0,0,1,1,1,1,1,1,1,1,1,2,2,2,2,2,2,2,2,3,3,3,3,3,3,3,4,4,4,4,4,4,5,5,5,5,5,6,6,6,6,7,7,7,8,8,9,0,0,0,0,0,0,0,0,0};
__device__ const int PC[64]={1,2,3,4,5,6,7,8,9,10,2,3,4,5,6,7,8,9,10,3,4,5,6,7,8,9,10,4,5,6,7,8,9,10,5,6,7,8,9,10,6,7,8,9,10,7,8,9,10,8,9,10,9,10,10,0,0,0,0,0,0,0,0,0};

// -------- prep: unified weight matrices Wu/lWu [64 rows][128 k] -------------
// rows 0-47: gate (st*6+g) E-part; rows 48-61: sb_W; rows 62-63: zero
__global__ void k_prep(const float* __restrict__ gW, const float* __restrict__ lgW,
                       const float* __restrict__ sbW, const float* __restrict__ lsbW,
                       float* __restrict__ Wu, float* __restrict__ lWu){
  int k = blockIdx.x*256 + threadIdx.x;
  if (k < 16384){
    int arr = k >> 13, rem = k & 8191;
    int o = rem >> 7, e = rem & 127;
    const float* g = arr ? lgW : gW;
    const float* s = arr ? lsbW : sbW;
    float v;
    if (o < 48) v = g[o*132 + 4 + e];
    else if (o < 62) v = s[(o-48)*128 + e];
    else v = 0.f;
    (arr ? lWu : Wu)[o*128 + e] = v;
  }
}

// -------- fields: gathers + user/item projections ---------------------------
__global__ __launch_bounds__(128) void k_fields(
    const int* __restrict__ cat, const float* __restrict__ num,
    const float* __restrict__ embT, const float* __restrict__ linT,
    const float* __restrict__ uW, const float* __restrict__ ub,
    const float* __restrict__ iW, const float* __restrict__ ib,
    const float* __restrict__ ulW, const float* __restrict__ ulb,
    const float* __restrict__ ilW, const float* __restrict__ ilb,
    float* __restrict__ fields, float* __restrict__ lfields)
{
  const int b = blockIdx.x, e = threadIdx.x;
  __shared__ float s_num[63];
  if (e < 63) s_num[e] = num[(size_t)b*63 + e];
  __syncthreads();
  const int* cb = cat + (size_t)b*10;
  float* fo = fields  + (size_t)b*NF_*E_;
  float* lo = lfields + (size_t)b*NF_*E_;
  for (int j = 0; j < 9; ++j){
    int id = cb[1+j] + j*1000;
    fo[j*E_+e] = embT[(size_t)id*E_+e];
    lo[j*E_+e] = linT[(size_t)id*E_+e];
  }
  float a0 = ub[e], a1 = ulb[e];
  for (int k = 0; k < 23; ++k){ float x = s_num[k]; a0 += x*uW[e*23+k]; a1 += x*ulW[e*23+k]; }
  fo[9*E_+e] = a0; lo[9*E_+e] = a1;
  float a2 = ib[e], a3 = ilb[e];
  for (int k = 0; k < 40; ++k){ float x = s_num[23+k]; a2 += x*iW[e*40+k]; a3 += x*ilW[e*40+k]; }
  fo[10*E_+e] = a2; lo[10*E_+e] = a3;
}

// -------- moe1: (R=4,C=8) LDS GEMM -> softmax/experts -> w_g ----------------
// 128 threads. rt=tid>>3 owns rows [4rt,4rt+4); ct=tid&7 owns cols {8j+ct}.
// LDS instr/batch: 2 waves x 32 k4 x (8 fld + 8 Wu) = 1024 b128 (R3 was 1536).
// s_Wu stride 132: Dcol-row=1 -> bank shift 4 -> 8 wave addrs cover 32 banks
// (stride 128 would alias all to one bank group). Per-element FMA order is
// unchanged from R3 -> bit-identical output.
// LDS floats: s_fld 1452 | s_stig 48 | s_Wu 64x132=8448 (overlay after GEMM:
//   s_C 64x69=4416 | s_w 1760 | s_sh 935)  total 9948 (38.9 KB) -> 4 blk/CU
__global__ __launch_bounds__(128) void k_moe1(
    const int* __restrict__ cat,
    const float* __restrict__ scen_emb, const float* __restrict__ task_emb,
    const float* __restrict__ st_w, const float* __restrict__ interact_w,
    const float* __restrict__ sb_b,
    const float* __restrict__ shexp_W, const float* __restrict__ shexp_b,
    const float* __restrict__ spexp_W, const float* __restrict__ spexp_b,
    const float* __restrict__ gate_W, const float* __restrict__ gate_b,
    const float* __restrict__ fields, const float* __restrict__ Wu,
    float* __restrict__ w_g)
{
  __shared__ float sm[9948];
  float* s_fld = sm;           // 11 x 132
  float* s_stig= sm + 1452;    // 48
  float* s_Wu  = sm + 1500;    // 64 x 132 (GEMM phase)
  float* s_C   = sm + 1500;    // overlay: 64 x 69
  float* s_w   = sm + 5916;    // overlay: 8 x 220
  float* s_sh  = sm + 7676;    // overlay: 55 x 17
  const int tid = threadIdx.x, b = blockIdx.x;
  const int scen = cat[(size_t)b*10];

  // stage fields (stride 132), Wu (stride 132), stig
  for (int idx = tid; idx < 352; idx += 128){
    int f = idx >> 5, q = idx & 31;
    *(float4*)&s_fld[f*132 + q*4] = *(const float4*)&fields[(size_t)b*1408 + idx*4];
  }
  for (int idx = tid; idx < 2048; idx += 128){
    int row = idx >> 5, q = idx & 31;
    *(float4*)&s_Wu[row*132 + q*4] = *(const float4*)&Wu[idx*4];
  }
  if (tid < 48){
    int st = tid/6, t = (tid/6)%T_;
    float stw = st_w[t*S_ + scen];
    float acc = gate_b[tid];
    for (int i = 0; i < 4; ++i){
      float sti = scen_emb[scen*4+i] * task_emb[t*4+i] * stw;
      acc += sti * gate_W[tid*132 + i];
    }
    s_stig[tid] = acc;
  }
  __syncthreads();

  // GEMM: thread owns rows [4rt,4rt+4) x cols {8j+ct : j=0..7}, full K=128
  {
    const int ct = tid & 7;           // 0..7 (fast in-wave -> conflict-free Wu)
    const int rt = tid >> 3;          // 0..15
    const int r0 = rt*4;
    int ra[4], ca[4];
    for (int r = 0; r < 4; ++r){ ra[r] = PR[r0+r]*132; ca[r] = PC[r0+r]*132; }
    float acc[4][8];
    for (int r = 0; r < 4; ++r) for (int c = 0; c < 8; ++c) acc[r][c] = 0.f;
    #pragma unroll 1
    for (int kk = 0; kk < 128; kk += 4){
      float4 p[4];
      for (int r = 0; r < 4; ++r){
        float4 x = *(const float4*)&s_fld[ra[r] + kk];
        float4 y = *(const float4*)&s_fld[ca[r] + kk];
        p[r].x = x.x*y.x; p[r].y = x.y*y.y; p[r].z = x.z*y.z; p[r].w = x.w*y.w;
      }
      for (int h = 0; h < 4; ++h){
        float4 w0 = *(const float4*)&s_Wu[((h*2+0)*8 + ct)*132 + kk];
        float4 w1 = *(const float4*)&s_Wu[((h*2+1)*8 + ct)*132 + kk];
        for (int r = 0; r < 4; ++r){
          acc[r][h*2+0] += p[r].x*w0.x + p[r].y*w0.y + p[r].z*w0.z + p[r].w*w0.w;
          acc[r][h*2+1] += p[r].x*w1.x + p[r].y*w1.y + p[r].z*w1.z + p[r].w*w1.w;
        }
      }
    }
    __syncthreads();   // all s_Wu reads complete before s_C overlays it
    for (int r = 0; r < 4; ++r){
      int row = r0 + r;
      float iw = (row < 55) ? interact_w[row] : 0.f;  // iw distributes out of K-sum
      for (int c = 0; c < 8; ++c){
        int col = c*8 + ct;
        float bias = (col < 48) ? s_stig[col] : ((col < 62) ? sb_b[col-48] : 0.f);
        s_C[row*69 + col] = acc[r][c]*iw + bias;
      }
    }
  }
  __syncthreads();
  // shared experts: sh[f][g*4+m] over ein = C[f][48..61]
  for (int o = tid; o < 880; o += 128){
    int f = o >> 4, j = o & 15;
    float acc = shexp_b[j];
    const float* ein = &s_C[f*69 + 48];
    const float* wp = &shexp_W[j*14];
    for (int i = 0; i < 14; ++i) acc += ein[i] * wp[i];
    s_sh[f*17 + j] = acc;
  }
  __syncthreads();
  // softmax + specific experts + mixture
  for (int task = tid; task < 440; task += 128){
    int st = task / 55, f = task % 55;
    float ein[14];
    for (int i = 0; i < 14; ++i) ein[i] = s_C[f*69 + 48 + i];
    float lg[6], mx = -1e30f;
    for (int g = 0; g < 6; ++g){ lg[g] = s_C[f*69 + st*6 + g]; mx = fmaxf(mx, lg[g]); }
    float sum = 0.f;
    for (int g = 0; g < 6; ++g){ lg[g] = __expf(lg[g]-mx); sum += lg[g]; }
    float inv = 1.f/sum;
    float wv[4] = {0,0,0,0};
    for (int g = 0; g < 4; ++g){
      float gg = lg[g]*inv;
      for (int m = 0; m < 4; ++m) wv[m] += gg * s_sh[f*17 + g*4 + m];
    }
    for (int ee = 0; ee < 2; ++ee){
      float gg = lg[4+ee]*inv;
      for (int m = 0; m < 4; ++m){
        float acc = spexp_b[(st*2+ee)*4+m];
        const float* wp = spexp_W + ((st*2+ee)*4+m)*14;
        for (int i = 0; i < 14; ++i) acc += ein[i] * wp[i];
        wv[m] += gg*acc;
      }
    }
    float4 o4; o4.x = wv[0]; o4.y = wv[1]; o4.z = wv[2]; o4.w = wv[3];
    *(float4*)&s_w[st*220 + f*4] = o4;
  }
  __syncthreads();
  // write w_g[b][st][224] (zero-padded cols 220..223), coalesced f4
  for (int idx = tid; idx < 448; idx += 128){
    int st = idx / 56, q = idx % 56;
    float4 v;
    if (q < 55) v = *(float4*)&s_w[st*220 + q*4];
    else { v.x=v.y=v.z=v.w=0.f; }
    *(float4*)&w_g[((size_t)b*8 + st)*224 + q*4] = v;
  }
}

// -------- mask batch GEMM: m1[st*55+oo][b] = mW[st] x w^T + mb --------------
// grid: 512 blocks = 8 st x 64 b-tiles(64). LDS: s_mw[56*116] + s_wb[64*116]
__global__ __launch_bounds__(256) void k_mask(
    const float* __restrict__ w_g, const float* __restrict__ mask_W,
    const float* __restrict__ mask_b, float* __restrict__ m1)
{
  __shared__ float s_mw[56*116];
  __shared__ float s_wb[64*116];
  const int tid = threadIdx.x;
  const int st = blockIdx.x >> 6, bt = blockIdx.x & 63;
  const int b0 = bt*64;
  const int btl = tid & 15, ot = tid >> 4;   // ot<14 active
  float acc[4][4];
  for (int c = 0; c < 4; ++c) for (int j = 0; j < 4; ++j) acc[c][j] = 0.f;

  for (int kc = 0; kc < 2; ++kc){
    __syncthreads();
    for (int idx = tid; idx < 64*112; idx += 256){
      int r = idx / 112, k = idx % 112;
      s_wb[r*116 + k] = w_g[((size_t)(b0+r)*8 + st)*224 + kc*112 + k];
    }
    for (int idx = tid; idx < 56*112; idx += 256){
      int r = idx / 112, k = idx % 112;
      int kg = kc*112 + k;
      s_mw[r*116 + k] = (r < 55 && kg < 220) ? mask_W[((size_t)st*55 + r)*220 + kg] : 0.f;
    }
    __syncthreads();
    if (ot < 14){
      for (int k4 = 0; k4 < 112; k4 += 4){
        float4 a[4], wb[4];
        for (int c = 0; c < 4; ++c) a[c]  = *(float4*)&s_mw[(ot*4+c)*116 + k4];
        for (int j = 0; j < 4; ++j) wb[j] = *(float4*)&s_wb[(btl*4+j)*116 + k4];
        for (int c = 0; c < 4; ++c)
          for (int j = 0; j < 4; ++j)
            acc[c][j] += a[c].x*wb[j].x + a[c].y*wb[j].y + a[c].z*wb[j].z + a[c].w*wb[j].w;
      }
    }
  }
  if (ot < 14){
    for (int c = 0; c < 4; ++c){
      int row = ot*4 + c;
      if (row < 55){
        float mb = mask_b[st*55 + row];
        float4 v; v.x = acc[c][0]+mb; v.y = acc[c][1]+mb; v.z = acc[c][2]+mb; v.w = acc[c][3]+mb;
        *(float4*)&m1[(size_t)(st*55+row)*B_ + b0 + btl*4] = v;
      }
    }
  }
}

// -------- per-row batch stats (mean, rsqrt(var+eps)) ------------------------
__global__ __launch_bounds__(256) void k_stats(const float* __restrict__ x, float* __restrict__ stats){
  const int row = blockIdx.x, tid = threadIdx.x;
  const float* xr = x + (size_t)row*B_;
  float s = 0.f, s2 = 0.f;
  for (int i = tid; i < B_; i += 256){ float v = xr[i]; s += v; s2 += v*v; }
  for (int off = 32; off > 0; off >>= 1){ s += __shfl_down(s, off); s2 += __shfl_down(s2, off); }
  __shared__ float red[8];
  if ((tid & 63) == 0){ red[(tid>>6)*2] = s; red[(tid>>6)*2+1] = s2; }
  __syncthreads();
  if (tid == 0){
    float Ssum = red[0]+red[2]+red[4]+red[6], S2 = red[1]+red[3]+red[5]+red[7];
    float mean = Ssum*(1.f/B_), var = S2*(1.f/B_) - mean*mean;
    stats[row*2] = mean; stats[row*2+1] = rsqrtf(fmaxf(var, 0.f) + EPSf);
  }
}

// -------- fused stats for two row-batches (m1: n1 rows, then x2) ------------
__global__ __launch_bounds__(256) void k_stats2(const float* __restrict__ x1, const float* __restrict__ x2,
                                                int n1, float* __restrict__ st1o, float* __restrict__ st2o){
  const int row = blockIdx.x, tid = threadIdx.x;
  const float* xr; float* sto;
  if (row < n1){ xr = x1 + (size_t)row*B_; sto = st1o + row*2; }
  else { int r = row - n1; xr = x2 + (size_t)r*B_; sto = st2o + r*2; }
  float s = 0.f, s2 = 0.f;
  for (int i = tid; i < B_; i += 256){ float v = xr[i]; s += v; s2 += v*v; }
  for (int off = 32; off > 0; off >>= 1){ s += __shfl_down(s, off); s2 += __shfl_down(s2, off); }
  __shared__ float red[8];
  if ((tid & 63) == 0){ red[(tid>>6)*2] = s; red[(tid>>6)*2+1] = s2; }
  __syncthreads();
  if (tid == 0){
    float Ssum = red[0]+red[2]+red[4]+red[6], S2 = red[1]+red[3]+red[5]+red[7];
    float mean = Ssum*(1.f/B_), var = S2*(1.f/B_) - mean*mean;
    sto[0] = mean; sto[1] = rsqrtf(fmaxf(var, 0.f) + EPSf);
  }
}

// -------- inter: bn(m)->tanh->relu, weighted pe contraction -> h[:, :128] ---
__global__ __launch_bounds__(128) void k_inter(
    const int* __restrict__ cat, const float* __restrict__ fields,
    const float* __restrict__ m1, const float* __restrict__ stm,
    const float* __restrict__ att_W, const float* __restrict__ interact_w,
    float* __restrict__ hbuf)
{
  __shared__ float s_fld[NF_*E_];
  __shared__ float s_co[110];
  const int b = blockIdx.x, e = threadIdx.x;
  const int scen = cat[(size_t)b*10];
  for (int k = e; k < NF_*E_; k += 128) s_fld[k] = fields[(size_t)b*NF_*E_ + k];
  if (e < 110){
    int t = e/55, f = e%55, row = (scen*T_+t)*55 + f;
    float v = (m1[(size_t)row*B_+b] - stm[row*2]) * stm[row*2+1];
    v = fmaxf(tanhf(v), 0.f);
    s_co[e] = v * att_W[(scen*T_+t)*55 + f];
  }
  __syncthreads();
  float a0 = 0.f, a1 = 0.f;
  for (int f = 0; f < 55; ++f){
    float pe = s_fld[PR[f]*E_+e] * s_fld[PC[f]*E_+e] * interact_w[f];
    a0 += s_co[f]*pe; a1 += s_co[55+f]*pe;
  }
  hbuf[(size_t)(0*256+e)*B_ + b] = a0;
  hbuf[(size_t)(1*256+e)*B_ + b] = a1;
}

// -------- moe2 (linear path, F=11): 4-wave GEMM + experts + ltower ----------
// LDS floats: s_lf[12*132]=1584 | s_C[12*69]=828 | s_w[352] | s_sh[187] | s_stig[48]
__global__ __launch_bounds__(256) void k_moe2(
    const int* __restrict__ cat,
    const float* __restrict__ scen_emb, const float* __restrict__ task_emb, const float* __restrict__ st_w,
    const float* __restrict__ lsb_b,
    const float* __restrict__ lshexp_W, const float* __restrict__ lshexp_b,
    const float* __restrict__ lspexp_W, const float* __restrict__ lspexp_b,
    const float* __restrict__ lgate_W, const float* __restrict__ lgate_b,
    const float* __restrict__ ltower_W, const float* __restrict__ ltower_b,
    const float* __restrict__ lfields, const float* __restrict__ lWu,
    float* __restrict__ lt1)
{
  __shared__ float sm[2999];
  float* s_lf = sm;            // 12 x 132
  float* s_C  = sm + 1584;     // 12 x 69
  float* s_w  = sm + 2412;     // 8 x 44
  float* s_sh = sm + 2764;     // 11 x 17
  float* s_stig = sm + 2951;   // 48
  const int tid = threadIdx.x, b = blockIdx.x;
  const int scen = cat[(size_t)b*10];

  for (int idx = tid; idx < 352; idx += 256){
    int f = idx >> 5, q = idx & 31;
    *(float4*)&s_lf[f*132 + q*4] = *(const float4*)&lfields[(size_t)b*1408 + f*128 + q*4];
  }
  if (tid >= 224){ // zero row 11 (32 threads)
    int q = tid - 224;
    float4 z = {0,0,0,0}; *(float4*)&s_lf[11*132 + q*4] = z;
  }
  if (tid < 48){
    int st = tid/6, t = (tid/6)%T_;
    float stw = st_w[t*S_ + scen];
    float acc = lgate_b[tid];
    for (int i = 0; i < 4; ++i){
      float sti = scen_emb[scen*4+i] * task_emb[t*4+i] * stw;
      acc += sti * lgate_W[tid*132 + i];
    }
    s_stig[tid] = acc;
  }
  __syncthreads();
  // GEMM over all 4 waves: C[12][64] = lf[12][128] * lWu^T
  {
    const int lane = tid & 63, wv_ = tid >> 6;
    const int pr = wv_*16 + (lane & 15);     // 0..63
    const int ks = lane >> 4;                // 4-way K split
    const int ft = pr & 1, ot = pr >> 1;     // 2 row-tiles x 32 col-tiles(2)
    const int r0 = ft*6, k0 = ks*32;
    float acc[6][2];
    for (int r = 0; r < 6; ++r){ acc[r][0] = 0.f; acc[r][1] = 0.f; }
    const float4* W4 = (const float4*)lWu;
    #pragma unroll 1
    for (int kc = 0; kc < 32; kc += 4){
      int kk = k0 + ((kc + ks*8) & 31);
      float4 w0 = W4[(ot*2+0)*32 + (kk>>2)];
      float4 w1 = W4[(ot*2+1)*32 + (kk>>2)];
      for (int r = 0; r < 6; ++r){
        float4 a = *(const float4*)&s_lf[(r0+r)*132 + kk];
        acc[r][0] += a.x*w0.x + a.y*w0.y + a.z*w0.z + a.w*w0.w;
        acc[r][1] += a.x*w1.x + a.y*w1.y + a.z*w1.z + a.w*w1.w;
      }
    }
    for (int r = 0; r < 6; ++r) for (int c = 0; c < 2; ++c){
      float v = acc[r][c];
      v += __shfl_xor(v, 16); v += __shfl_xor(v, 32);
      acc[r][c] = v;
    }
    if (ks == 0){
      for (int r = 0; r < 6; ++r) for (int c = 0; c < 2; ++c){
        int col = ot*2 + c, row = r0 + r;
        float bias = (col < 48) ? s_stig[col] : ((col < 62) ? lsb_b[col-48] : 0.f);
        s_C[row*69 + col] = acc[r][c] + bias;
      }
    }
  }
  __syncthreads();
  if (tid < 176){
    int f = tid >> 4, j = tid & 15;
    float acc = lshexp_b[j];
    const float* ein = &s_C[f*69 + 48];
    for (int i = 0; i < 14; ++i) acc += ein[i] * lshexp_W[j*14+i];
    s_sh[f*17 + j] = acc;
  }
  __syncthreads();
  if (tid < 88){
    int st = tid / 11, f = tid % 11;
    float ein[14];
    for (int i = 0; i < 14; ++i) ein[i] = s_C[f*69 + 48 + i];
    float lg[6], mx = -1e30f;
    for (int g = 0; g < 6; ++g){ lg[g] = s_C[f*69 + st*6 + g]; mx = fmaxf(mx, lg[g]); }
    float sum = 0.f;
    for (int g = 0; g < 6; ++g){ lg[g] = __expf(lg[g]-mx); sum += lg[g]; }
    float inv = 1.f/sum;
    float wv[4] = {0,0,0,0};
    for (int g = 0; g < 4; ++g){
      float gg = lg[g]*inv;
      for (int m = 0; m < 4; ++m) wv[m] += gg * s_sh[f*17 + g*4 + m];
    }
    for (int ee = 0; ee < 2; ++ee){
      float gg = lg[4+ee]*inv;
      for (int m = 0; m < 4; ++m){
        float acc = lspexp_b[(st*2+ee)*4+m];
        const float* wp = lspexp_W + ((st*2+ee)*4+m)*14;
        for (int i = 0; i < 14; ++i) acc += ein[i] * wp[i];
        wv[m] += gg*acc;
      }
    }
    float4 o4; o4.x = wv[0]; o4.y = wv[1]; o4.z = wv[2]; o4.w = wv[3];
    *(float4*)&s_w[st*44 + f*4] = o4;
  }
  __syncthreads();
  if (tid < 88){
    int st = tid / 11, oo = tid % 11;
    float acc = ltower_b[st*11+oo];
    const float* tw = ltower_W + (st*11+oo)*44;
    const float* wp = s_w + st*44;
    for (int i = 0; i < 44; ++i) acc += wp[i] * tw[i];
    lt1[(size_t)(st*11+oo)*B_ + b] = acc;
  }
}

// -------- linf: bn(lt)->softmax over fields, weighted lfields -> h[:,128:] --
__global__ __launch_bounds__(128) void k_linf(
    const int* __restrict__ cat, const float* __restrict__ lfields,
    const float* __restrict__ lt1, const float* __restrict__ stl,
    const float* __restrict__ bias_p, float* __restrict__ hbuf)
{
  __shared__ float s_lf[NF_*E_];
  __shared__ float s_lw[22];
  const int b = blockIdx.x, e = threadIdx.x;
  const int scen = cat[(size_t)b*10];
  for (int k = e; k < NF_*E_; k += 128) s_lf[k] = lfields[(size_t)b*NF_*E_ + k];
  if (e < 22){
    int t = e/11, f = e%11, row = (scen*T_+t)*11 + f;
    s_lw[e] = (lt1[(size_t)row*B_+b] - stl[row*2]) * stl[row*2+1];
  }
  __syncthreads();
  if (e < 2){
    int t = e; float mx = -1e30f;
    for (int f = 0; f < 11; ++f) mx = fmaxf(mx, s_lw[t*11+f]);
    float sum = 0.f;
    for (int f = 0; f < 11; ++f){ float x = __expf(s_lw[t*11+f]-mx); s_lw[t*11+f] = x; sum += x; }
    float inv = 1.f/sum;
    for (int f = 0; f < 11; ++f) s_lw[t*11+f] *= inv;
  }
  __syncthreads();
  for (int t = 0; t < 2; ++t){
    float acc = bias_p[(size_t)(t*S_+scen)*E_ + e];
    for (int f = 0; f < 11; ++f) acc += s_lw[t*11+f] * s_lf[f*E_+e];
    hbuf[(size_t)(t*256+128+e)*B_ + b] = acc;
  }
}

// -------- final MLP ---------------------------------------------------------
__global__ __launch_bounds__(256) void k_last1(const float* __restrict__ hbuf,
    const float* __restrict__ W1, const float* __restrict__ b1, float* __restrict__ h1){
  int bz = blockIdx.x, t = bz/80, r = bz%80, og = r/16, bc = r%16;
  __shared__ float s_w1[8*256];
  int tid = threadIdx.x;
  for (int k = tid; k < 2048; k += 256){
    int oo = k>>8, i = k&255;
    s_w1[k] = W1[(size_t)(t*40 + og*8 + oo)*256 + i];
  }
  __syncthreads();
  int b = bc*256 + tid;
  float acc[8];
  for (int oo = 0; oo < 8; ++oo) acc[oo] = b1[t*40 + og*8 + oo];
  for (int i = 0; i < 256; ++i){
    float hv = hbuf[(size_t)(t*256+i)*B_ + b];
    for (int oo = 0; oo < 8; ++oo) acc[oo] += hv * s_w1[oo*256+i];
  }
  for (int oo = 0; oo < 8; ++oo) h1[(size_t)(t*40 + og*8 + oo)*B_ + b] = acc[oo];
}

__global__ __launch_bounds__(256) void k_last2(const float* __restrict__ h1, const float* __restrict__ st1,
    const float* __restrict__ W2, const float* __restrict__ b2v, float* __restrict__ h2){
  int bz = blockIdx.x, t = bz/16, bc = bz%16, tid = threadIdx.x, b = bc*256 + tid;
  __shared__ float s_w2[1280];
  for (int k = tid; k < 1280; k += 256) s_w2[k] = W2[t*1280 + k];
  __syncthreads();
  float hv[40];
  for (int i = 0; i < 40; ++i){
    int row = t*40 + i;
    hv[i] = fmaxf((h1[(size_t)row*B_+b] - st1[row*2]) * st1[row*2+1], 0.f);
  }
  for (int o = 0; o < 32; ++o){
    float acc = b2v[t*32+o];
    for (int i = 0; i < 40; ++i) acc += hv[i] * s_w2[o*40+i];
    h2[(size_t)(t*32+o)*B_ + b] = acc;
  }
}

__global__ __launch_bounds__(256) void k_last3(const float* __restrict__ h2, const float* __restrict__ st2,
    const float* __restrict__ W3, const float* __restrict__ b3v, float* __restrict__ h3){
  int bz = blockIdx.x, t = bz/16, bc = bz%16, tid = threadIdx.x, b = bc*256 + tid;
  __shared__ float s_w3[256];
  if (tid < 256) s_w3[tid] = W3[t*256 + tid];
  __syncthreads();
  float hv[32];
  for (int i = 0; i < 32; ++i){
    int row = t*32 + i;
    hv[i] = fmaxf((h2[(size_t)row*B_+b] - st2[row*2]) * st2[row*2+1], 0.f);
  }
  for (int o = 0; o < 8; ++o){
    float acc = b3v[t*8+o];
    for (int i = 0; i < 32; ++i) acc += hv[i] * s_w3[o*32+i];
    h3[(size_t)(t*8+o)*B_ + b] = acc;
  }
}

__global__ __launch_bounds__(256) void k_out(const float* __restrict__ h3, const float* __restrict__ st3,
    const float* __restrict__ W4, const float* __restrict__ b4v, float* __restrict__ out){
  int idx = blockIdx.x*256 + threadIdx.x;
  int t = idx / B_, b = idx % B_;
  float acc = b4v[t];
  for (int i = 0; i < 8; ++i){
    int row = t*8 + i;
    float v = fmaxf((h3[(size_t)row*B_+b] - st3[row*2]) * st3[row*2+1], 0.f);
    acc += v * W4[t*8+i];
  }
  out[idx] = 1.f/(1.f + __expf(-acc));
}

extern "C" void kernel_launch(void* const* d_in, const int* in_sizes, int n_in,
                              void* d_out, int out_size, void* d_ws, size_t ws_size,
                              hipStream_t stream)
{
  const int*   cat      = (const int*)  d_in[0];
  const float* num      = (const float*)d_in[1];
  const float* embT     = (const float*)d_in[2];
  const float* linT     = (const float*)d_in[3];
  const float* uW = (const float*)d_in[4];  const float* ub = (const float*)d_in[5];
  const float* iW = (const float*)d_in[6];  const float* ib = (const float*)d_in[7];
  const float* ulW = (const float*)d_in[8]; const float* ulb = (const float*)d_in[9];
  const float* ilW = (const float*)d_in[10];const float* ilb = (const float*)d_in[11];
  const float* scen_emb = (const float*)d_in[12];
  const float* task_emb = (const float*)d_in[13];
  const float* st_w     = (const float*)d_in[14];
  const float* interact_w=(const float*)d_in[15];
  const float* sbW = (const float*)d_in[16]; const float* sbb = (const float*)d_in[17];
  const float* lsbW = (const float*)d_in[18];const float* lsbb = (const float*)d_in[19];
  const float* shW = (const float*)d_in[20]; const float* shb = (const float*)d_in[21];
  const float* spW = (const float*)d_in[22]; const float* spb = (const float*)d_in[23];
  const float* lshW = (const float*)d_in[24];const float* lshb = (const float*)d_in[25];
  const float* lspW = (const float*)d_in[26];const float* lspb = (const float*)d_in[27];
  const float* gW = (const float*)d_in[28];  const float* gb = (const float*)d_in[29];
  const float* lgW = (const float*)d_in[30]; const float* lgb = (const float*)d_in[31];
  const float* mW = (const float*)d_in[32];  const float* mb = (const float*)d_in[33];
  const float* attW = (const float*)d_in[34];
  const float* ltW = (const float*)d_in[35]; const float* ltb = (const float*)d_in[36];
  const float* biasP = (const float*)d_in[37];
  const float* W1 = (const float*)d_in[38];  const float* b1 = (const float*)d_in[39];
  const float* W2 = (const float*)d_in[40];  const float* b2v = (const float*)d_in[41];
  const float* W3 = (const float*)d_in[42];  const float* b3v = (const float*)d_in[43];
  const float* W4 = (const float*)d_in[44];  const float* b4v = (const float*)d_in[45];
  float* out = (float*)d_out;

  float* ws = (float*)d_ws;
  size_t o = 0;
  float* fieldsB  = ws + o; o += (size_t)B_*NF_*E_;
  float* lfieldsB = ws + o; o += (size_t)B_*NF_*E_;
  float* Wu   = ws + o; o += 8192;
  float* lWu  = ws + o; o += 8192;
  float* w_g  = ws + o; o += (size_t)B_*8*224;
  float* m1   = ws + o; o += (size_t)440*B_;
  float* stm  = ws + o; o += 880;
  float* lt1  = ws + o; o += (size_t)88*B_;
  float* stl  = ws + o; o += 176;
  float* hbuf = ws + o; o += (size_t)T_*256*B_;
  float* h1   = ws + o; o += (size_t)80*B_;
  float* st1  = ws + o; o += 160;
  float* h2   = ws + o; o += (size_t)64*B_;
  float* st2  = ws + o; o += 128;
  float* h3   = ws + o; o += (size_t)16*B_;
  float* st3  = ws + o; o += 32;

  k_prep<<<64, 256, 0, stream>>>(gW, lgW, sbW, lsbW, Wu, lWu);
  k_fields<<<B_, 128, 0, stream>>>(cat, num, embT, linT, uW, ub, iW, ib, ulW, ulb, ilW, ilb, fieldsB, lfieldsB);
  k_moe1<<<B_, 128, 0, stream>>>(cat, scen_emb, task_emb, st_w, interact_w, sbb, shW, shb,
                                 spW, spb, gW, gb, fieldsB, Wu, w_g);
  k_mask<<<512, 256, 0, stream>>>(w_g, mW, mb, m1);
  k_moe2<<<B_, 256, 0, stream>>>(cat, scen_emb, task_emb, st_w, lsbb, lshW, lshb,
                                 lspW, lspb, lgW, lgb, ltW, ltb, lfieldsB, lWu, lt1);
  k_stats2<<<528, 256, 0, stream>>>(m1, lt1, 440, stm, stl);
  k_inter<<<B_, 128, 0, stream>>>(cat, fieldsB, m1, stm, attW, interact_w, hbuf);
  k_linf<<<B_, 128, 0, stream>>>(cat, lfieldsB, lt1, stl, biasP, hbuf);
  k_last1<<<160, 256, 0, stream>>>(hbuf, W1, b1, h1);
  k_stats<<<80, 256, 0, stream>>>(h1, st1);
  k_last2<<<32, 256, 0, stream>>>(h1, st1, W2, b2v, h2);
  k_stats<<<64, 256, 0, stream>>>(h2, st2);
  k_last3<<<32, 256, 0, stream>>>(h2, st2, W3, b3v, h3);
  k_stats<<<16, 256, 0, stream>>>(h3, st3);
  k_out<<<32, 256, 0, stream>>>(h3, st3, W4, b4v, out);
}

// Round 7
// 482.662 us; speedup vs baseline: 1.1286x; 1.0101x over previous
//
#include <hip/hip_runtime.h>
#include <hip/hip_bf16.h>

#define B_ 4096
#define T_ 2
#define S_ 4
#define E_ 128
#define NF_ 11
#define ID_ 55
#define MID_ 4
#define NG_ 6
#define SI_ 4
#define EPSf 1e-5f

// triu_indices(11, k=1) pairs, padded to 64 rows (rows 55..63: PR=PC=0, masked by iw=0)
__device__ const int PR[64]={0,0,0,0,0,0,0,0,0,0,1,1,1,1,1,1,1,1,1,2,2,2,2,2,2,2,2,3,3,3,3,3,3,3,4,4,4,4,4,4,5,5,5,5,5,6,6,6,6,7,7,7,8,8,9,0,0,0,0,0,0,0,0,0};
__device__ const int PC[64]={1,2,3,4,5,6,7,8,9,10,2,3,4,5,6,7,8,9,10,3,4,5,6,7,8,9,10,4,5,6,7,8,9,10,5,6,7,8,9,10,6,7,8,9,10,7,8,9,10,8,9,10,9,10,10,0,0,0,0,0,0,0,0,0};

// -------- prep: unified weight matrices Wu/lWu [64 rows][128 k] -------------
// rows 0-47: gate (st*6+g) E-part; rows 48-61: sb_W; rows 62-63: zero
__global__ void k_prep(const float* __restrict__ gW, const float* __restrict__ lgW,
                       const float* __restrict__ sbW, const float* __restrict__ lsbW,
                       float* __restrict__ Wu, float* __restrict__ lWu){
  int k = blockIdx.x*256 + threadIdx.x;
  if (k < 16384){
    int arr = k >> 13, rem = k & 8191;
    int o = rem >> 7, e = rem & 127;
    const float* g = arr ? lgW : gW;
    const float* s = arr ? lsbW : sbW;
    float v;
    if (o < 48) v = g[o*132 + 4 + e];
    else if (o < 62) v = s[(o-48)*128 + e];
    else v = 0.f;
    (arr ? lWu : Wu)[o*128 + e] = v;
  }
}

// -------- fields: gathers + user/item projections ---------------------------
__global__ __launch_bounds__(128) void k_fields(
    const int* __restrict__ cat, const float* __restrict__ num,
    const float* __restrict__ embT, const float* __restrict__ linT,
    const float* __restrict__ uW, const float* __restrict__ ub,
    const float* __restrict__ iW, const float* __restrict__ ib,
    const float* __restrict__ ulW, const float* __restrict__ ulb,
    const float* __restrict__ ilW, const float* __restrict__ ilb,
    float* __restrict__ fields, float* __restrict__ lfields)
{
  const int b = blockIdx.x, e = threadIdx.x;
  __shared__ float s_num[63];
  if (e < 63) s_num[e] = num[(size_t)b*63 + e];
  __syncthreads();
  const int* cb = cat + (size_t)b*10;
  float* fo = fields  + (size_t)b*NF_*E_;
  float* lo = lfields + (size_t)b*NF_*E_;
  for (int j = 0; j < 9; ++j){
    int id = cb[1+j] + j*1000;
    fo[j*E_+e] = embT[(size_t)id*E_+e];
    lo[j*E_+e] = linT[(size_t)id*E_+e];
  }
  float a0 = ub[e], a1 = ulb[e];
  for (int k = 0; k < 23; ++k){ float x = s_num[k]; a0 += x*uW[e*23+k]; a1 += x*ulW[e*23+k]; }
  fo[9*E_+e] = a0; lo[9*E_+e] = a1;
  float a2 = ib[e], a3 = ilb[e];
  for (int k = 0; k < 40; ++k){ float x = s_num[23+k]; a2 += x*iW[e*40+k]; a3 += x*ilW[e*40+k]; }
  fo[10*E_+e] = a2; lo[10*E_+e] = a3;
}

// -------- moe1: G=4 batches/block, broadcast-Wu GEMM -> experts -> w_g ------
// 512 threads, 1024 blocks. row=tid&63 (wave covers all 64 rows), colgroup=
// tid>>6 (wave-uniform -> Wu reads are same-address broadcasts, conflict-free).
// Per k4/thread: 8 fld + 8 Wu b128 serving 4 batches -> 1024 wave-instr/batch
// (R3 was 1536). LDS 63.2 KB -> 2 blk/CU = 16 waves/CU (saturation regime).
// Post-phases run in 2 passes of 2 batches (s_C/s_sh overlay s_Wu); w_g is
// written directly (coalesced per-st runs), no s_w staging. Per-element K
// summation order identical to R3 -> bit-identical output.
// LDS floats: s_fld 4x1452=5808 | s_stig 192 | s_Wu 8192 (overlay: s_C 2x4160,
//   s_sh 2x935) -> total 16190 (63.2 KB)
__global__ __launch_bounds__(512) __attribute__((amdgpu_waves_per_eu(4))) void k_moe1(
    const int* __restrict__ cat,
    const float* __restrict__ scen_emb, const float* __restrict__ task_emb,
    const float* __restrict__ st_w, const float* __restrict__ interact_w,
    const float* __restrict__ sb_b,
    const float* __restrict__ shexp_W, const float* __restrict__ shexp_b,
    const float* __restrict__ spexp_W, const float* __restrict__ spexp_b,
    const float* __restrict__ gate_W, const float* __restrict__ gate_b,
    const float* __restrict__ fields, const float* __restrict__ Wu,
    float* __restrict__ w_g)
{
  __shared__ float sm[16190];
  float* s_fld  = sm;           // 4 x 1452
  float* s_stig = sm + 5808;    // 4 x 48
  float* s_Wu   = sm + 6000;    // 64 x 128 (GEMM phase)
  float* s_C    = sm + 6000;    // overlay: 2 x (64 x 65)
  float* s_sh   = sm + 14320;   // overlay: 2 x (55 x 17)
  const int tid = threadIdx.x;
  const int b0 = blockIdx.x * 4;

  // stage 4 field sets (stride 132), Wu (linear), 4x stig
  for (int idx = tid; idx < 4*352; idx += 512){
    int g = idx / 352, rem = idx % 352;
    int f = rem >> 5, q = rem & 31;
    *(float4*)&s_fld[g*1452 + f*132 + q*4] =
        *(const float4*)&fields[(size_t)(b0+g)*1408 + rem*4];
  }
  for (int idx = tid; idx < 2048; idx += 512)
    *(float4*)&s_Wu[idx*4] = *(const float4*)&Wu[idx*4];
  if (tid < 192){
    int g = tid / 48, o = tid % 48;
    int scen = cat[(size_t)(b0+g)*10];
    int t = (o/6) % T_;
    float stw = st_w[t*S_ + scen];
    float acc = gate_b[o];
    for (int i = 0; i < 4; ++i){
      float sti = scen_emb[scen*4+i] * task_emb[t*4+i] * stw;
      acc += sti * gate_W[o*132 + i];
    }
    s_stig[g*48 + o] = acc;
  }
  __syncthreads();

  // GEMM: thread owns row (tid&63) x cols [8*(tid>>6), +8) for 4 batches
  const int row = tid & 63;
  const int w8 = (tid >> 6) * 8;      // wave-uniform col-group base
  {
    const int ra = PR[row]*132, ca = PC[row]*132;
    float acc[4][8];
    for (int g = 0; g < 4; ++g) for (int c = 0; c < 8; ++c) acc[g][c] = 0.f;
    #pragma unroll 1
    for (int kk = 0; kk < 128; kk += 4){
      float4 p[4];
      for (int g = 0; g < 4; ++g){
        float4 x = *(const float4*)&s_fld[g*1452 + ra + kk];
        float4 y = *(const float4*)&s_fld[g*1452 + ca + kk];
        p[g].x = x.x*y.x; p[g].y = x.y*y.y; p[g].z = x.z*y.z; p[g].w = x.w*y.w;
      }
      for (int c = 0; c < 8; ++c){
        float4 wv = *(const float4*)&s_Wu[(w8 + c)*128 + kk];  // broadcast
        for (int g = 0; g < 4; ++g)
          acc[g][c] += p[g].x*wv.x + p[g].y*wv.y + p[g].z*wv.z + p[g].w*wv.w;
      }
    }
    __syncthreads();   // all s_Wu/s_fld GEMM reads done before s_C overlays

    const float iw = (row < 55) ? interact_w[row] : 0.f;  // iw out of K-sum
    for (int pass = 0; pass < 2; ++pass){
      // write C for batches pass*2, pass*2+1
      for (int gi = 0; gi < 2; ++gi){
        int g = pass*2 + gi;
        for (int c = 0; c < 8; ++c){
          int col = w8 + c;
          float bias = (col < 48) ? s_stig[g*48 + col]
                                  : ((col < 62) ? sb_b[col-48] : 0.f);
          s_C[gi*4160 + row*65 + col] = acc[g][c]*iw + bias;
        }
      }
      __syncthreads();
      // shared experts: 2 batches x 880
      for (int o = tid; o < 1760; o += 512){
        int gi = o / 880, rem = o % 880;
        int f = rem >> 4, j = rem & 15;
        float a = shexp_b[j];
        const float* ein = &s_C[gi*4160 + f*65 + 48];
        const float* wp = &shexp_W[j*14];
        for (int i = 0; i < 14; ++i) a += ein[i] * wp[i];
        s_sh[gi*935 + f*17 + j] = a;
      }
      __syncthreads();
      // softmax + specific experts + mixture, direct w_g write
      for (int task = tid; task < 880; task += 512){
        int gi = task / 440, rem = task % 440;
        int st = rem / 55, f = rem % 55;
        int g = pass*2 + gi;
        float ein[14];
        for (int i = 0; i < 14; ++i) ein[i] = s_C[gi*4160 + f*65 + 48 + i];
        float lg[6], mx = -1e30f;
        for (int q = 0; q < 6; ++q){ lg[q] = s_C[gi*4160 + f*65 + st*6 + q]; mx = fmaxf(mx, lg[q]); }
        float sum = 0.f;
        for (int q = 0; q < 6; ++q){ lg[q] = __expf(lg[q]-mx); sum += lg[q]; }
        float inv = 1.f/sum;
        float wv[4] = {0,0,0,0};
        for (int q = 0; q < 4; ++q){
          float gg = lg[q]*inv;
          for (int m = 0; m < 4; ++m) wv[m] += gg * s_sh[gi*935 + f*17 + q*4 + m];
        }
        for (int ee = 0; ee < 2; ++ee){
          float gg = lg[4+ee]*inv;
          for (int m = 0; m < 4; ++m){
            float a = spexp_b[(st*2+ee)*4+m];
            const float* wp = spexp_W + ((st*2+ee)*4+m)*14;
            for (int i = 0; i < 14; ++i) a += ein[i] * wp[i];
            wv[m] += gg*a;
          }
        }
        float4 o4; o4.x = wv[0]; o4.y = wv[1]; o4.z = wv[2]; o4.w = wv[3];
        *(float4*)&w_g[((size_t)(b0+g)*8 + st)*224 + f*4] = o4;
      }
      // zero-pad cols 220..223 for this pass's 2 batches x 8 st
      if (tid < 16){
        int gi = tid / 8, st = tid % 8;
        int g = pass*2 + gi;
        float4 z = {0,0,0,0};
        *(float4*)&w_g[((size_t)(b0+g)*8 + st)*224 + 220] = z;
      }
      if (pass == 0) __syncthreads();   // pass-0 readers done before pass-1 C-write
    }
  }
}

// -------- mask batch GEMM: m1[st*55+oo][b] = mW[st] x w^T + mb --------------
// grid: 512 blocks = 8 st x 64 b-tiles(64). LDS: s_mw[56*116] + s_wb[64*116]
__global__ __launch_bounds__(256) void k_mask(
    const float* __restrict__ w_g, const float* __restrict__ mask_W,
    const float* __restrict__ mask_b, float* __restrict__ m1)
{
  __shared__ float s_mw[56*116];
  __shared__ float s_wb[64*116];
  const int tid = threadIdx.x;
  const int st = blockIdx.x >> 6, bt = blockIdx.x & 63;
  const int b0 = bt*64;
  const int btl = tid & 15, ot = tid >> 4;   // ot<14 active
  float acc[4][4];
  for (int c = 0; c < 4; ++c) for (int j = 0; j < 4; ++j) acc[c][j] = 0.f;

  for (int kc = 0; kc < 2; ++kc){
    __syncthreads();
    for (int idx = tid; idx < 64*112; idx += 256){
      int r = idx / 112, k = idx % 112;
      s_wb[r*116 + k] = w_g[((size_t)(b0+r)*8 + st)*224 + kc*112 + k];
    }
    for (int idx = tid; idx < 56*112; idx += 256){
      int r = idx / 112, k = idx % 112;
      int kg = kc*112 + k;
      s_mw[r*116 + k] = (r < 55 && kg < 220) ? mask_W[((size_t)st*55 + r)*220 + kg] : 0.f;
    }
    __syncthreads();
    if (ot < 14){
      for (int k4 = 0; k4 < 112; k4 += 4){
        float4 a[4], wb[4];
        for (int c = 0; c < 4; ++c) a[c]  = *(float4*)&s_mw[(ot*4+c)*116 + k4];
        for (int j = 0; j < 4; ++j) wb[j] = *(float4*)&s_wb[(btl*4+j)*116 + k4];
        for (int c = 0; c < 4; ++c)
          for (int j = 0; j < 4; ++j)
            acc[c][j] += a[c].x*wb[j].x + a[c].y*wb[j].y + a[c].z*wb[j].z + a[c].w*wb[j].w;
      }
    }
  }
  if (ot < 14){
    for (int c = 0; c < 4; ++c){
      int row = ot*4 + c;
      if (row < 55){
        float mb = mask_b[st*55 + row];
        float4 v; v.x = acc[c][0]+mb; v.y = acc[c][1]+mb; v.z = acc[c][2]+mb; v.w = acc[c][3]+mb;
        *(float4*)&m1[(size_t)(st*55+row)*B_ + b0 + btl*4] = v;
      }
    }
  }
}

// -------- per-row batch stats (mean, rsqrt(var+eps)) ------------------------
__global__ __launch_bounds__(256) void k_stats(const float* __restrict__ x, float* __restrict__ stats){
  const int row = blockIdx.x, tid = threadIdx.x;
  const float* xr = x + (size_t)row*B_;
  float s = 0.f, s2 = 0.f;
  for (int i = tid; i < B_; i += 256){ float v = xr[i]; s += v; s2 += v*v; }
  for (int off = 32; off > 0; off >>= 1){ s += __shfl_down(s, off); s2 += __shfl_down(s2, off); }
  __shared__ float red[8];
  if ((tid & 63) == 0){ red[(tid>>6)*2] = s; red[(tid>>6)*2+1] = s2; }
  __syncthreads();
  if (tid == 0){
    float Ssum = red[0]+red[2]+red[4]+red[6], S2 = red[1]+red[3]+red[5]+red[7];
    float mean = Ssum*(1.f/B_), var = S2*(1.f/B_) - mean*mean;
    stats[row*2] = mean; stats[row*2+1] = rsqrtf(fmaxf(var, 0.f) + EPSf);
  }
}

// -------- fused stats for two row-batches (m1: n1 rows, then x2) ------------
__global__ __launch_bounds__(256) void k_stats2(const float* __restrict__ x1, const float* __restrict__ x2,
                                                int n1, float* __restrict__ st1o, float* __restrict__ st2o){
  const int row = blockIdx.x, tid = threadIdx.x;
  const float* xr; float* sto;
  if (row < n1){ xr = x1 + (size_t)row*B_; sto = st1o + row*2; }
  else { int r = row - n1; xr = x2 + (size_t)r*B_; sto = st2o + r*2; }
  float s = 0.f, s2 = 0.f;
  for (int i = tid; i < B_; i += 256){ float v = xr[i]; s += v; s2 += v*v; }
  for (int off = 32; off > 0; off >>= 1){ s += __shfl_down(s, off); s2 += __shfl_down(s2, off); }
  __shared__ float red[8];
  if ((tid & 63) == 0){ red[(tid>>6)*2] = s; red[(tid>>6)*2+1] = s2; }
  __syncthreads();
  if (tid == 0){
    float Ssum = red[0]+red[2]+red[4]+red[6], S2 = red[1]+red[3]+red[5]+red[7];
    float mean = Ssum*(1.f/B_), var = S2*(1.f/B_) - mean*mean;
    sto[0] = mean; sto[1] = rsqrtf(fmaxf(var, 0.f) + EPSf);
  }
}

// -------- inter: bn(m)->tanh->relu, weighted pe contraction -> h[:, :128] ---
__global__ __launch_bounds__(128) void k_inter(
    const int* __restrict__ cat, const float* __restrict__ fields,
    const float* __restrict__ m1, const float* __restrict__ stm,
    const float* __restrict__ att_W, const float* __restrict__ interact_w,
    float* __restrict__ hbuf)
{
  __shared__ float s_fld[NF_*E_];
  __shared__ float s_co[110];
  const int b = blockIdx.x, e = threadIdx.x;
  const int scen = cat[(size_t)b*10];
  for (int k = e; k < NF_*E_; k += 128) s_fld[k] = fields[(size_t)b*NF_*E_ + k];
  if (e < 110){
    int t = e/55, f = e%55, row = (scen*T_+t)*55 + f;
    float v = (m1[(size_t)row*B_+b] - stm[row*2]) * stm[row*2+1];
    v = fmaxf(tanhf(v), 0.f);
    s_co[e] = v * att_W[(scen*T_+t)*55 + f];
  }
  __syncthreads();
  float a0 = 0.f, a1 = 0.f;
  for (int f = 0; f < 55; ++f){
    float pe = s_fld[PR[f]*E_+e] * s_fld[PC[f]*E_+e] * interact_w[f];
    a0 += s_co[f]*pe; a1 += s_co[55+f]*pe;
  }
  hbuf[(size_t)(0*256+e)*B_ + b] = a0;
  hbuf[(size_t)(1*256+e)*B_ + b] = a1;
}

// -------- moe2 (linear path, F=11): 4-wave GEMM + experts + ltower ----------
// LDS floats: s_lf[12*132]=1584 | s_C[12*69]=828 | s_w[352] | s_sh[187] | s_stig[48]
__global__ __launch_bounds__(256) void k_moe2(
    const int* __restrict__ cat,
    const float* __restrict__ scen_emb, const float* __restrict__ task_emb, const float* __restrict__ st_w,
    const float* __restrict__ lsb_b,
    const float* __restrict__ lshexp_W, const float* __restrict__ lshexp_b,
    const float* __restrict__ lspexp_W, const float* __restrict__ lspexp_b,
    const float* __restrict__ lgate_W, const float* __restrict__ lgate_b,
    const float* __restrict__ ltower_W, const float* __restrict__ ltower_b,
    const float* __restrict__ lfields, const float* __restrict__ lWu,
    float* __restrict__ lt1)
{
  __shared__ float sm[2999];
  float* s_lf = sm;            // 12 x 132
  float* s_C  = sm + 1584;     // 12 x 69
  float* s_w  = sm + 2412;     // 8 x 44
  float* s_sh = sm + 2764;     // 11 x 17
  float* s_stig = sm + 2951;   // 48
  const int tid = threadIdx.x, b = blockIdx.x;
  const int scen = cat[(size_t)b*10];

  for (int idx = tid; idx < 352; idx += 256){
    int f = idx >> 5, q = idx & 31;
    *(float4*)&s_lf[f*132 + q*4] = *(const float4*)&lfields[(size_t)b*1408 + f*128 + q*4];
  }
  if (tid >= 224){ // zero row 11 (32 threads)
    int q = tid - 224;
    float4 z = {0,0,0,0}; *(float4*)&s_lf[11*132 + q*4] = z;
  }
  if (tid < 48){
    int st = tid/6, t = (tid/6)%T_;
    float stw = st_w[t*S_ + scen];
    float acc = lgate_b[tid];
    for (int i = 0; i < 4; ++i){
      float sti = scen_emb[scen*4+i] * task_emb[t*4+i] * stw;
      acc += sti * lgate_W[tid*132 + i];
    }
    s_stig[tid] = acc;
  }
  __syncthreads();
  // GEMM over all 4 waves: C[12][64] = lf[12][128] * lWu^T
  {
    const int lane = tid & 63, wv_ = tid >> 6;
    const int pr = wv_*16 + (lane & 15);     // 0..63
    const int ks = lane >> 4;                // 4-way K split
    const int ft = pr & 1, ot = pr >> 1;     // 2 row-tiles x 32 col-tiles(2)
    const int r0 = ft*6, k0 = ks*32;
    float acc[6][2];
    for (int r = 0; r < 6; ++r){ acc[r][0] = 0.f; acc[r][1] = 0.f; }
    const float4* W4 = (const float4*)lWu;
    #pragma unroll 1
    for (int kc = 0; kc < 32; kc += 4){
      int kk = k0 + ((kc + ks*8) & 31);
      float4 w0 = W4[(ot*2+0)*32 + (kk>>2)];
      float4 w1 = W4[(ot*2+1)*32 + (kk>>2)];
      for (int r = 0; r < 6; ++r){
        float4 a = *(const float4*)&s_lf[(r0+r)*132 + kk];
        acc[r][0] += a.x*w0.x + a.y*w0.y + a.z*w0.z + a.w*w0.w;
        acc[r][1] += a.x*w1.x + a.y*w1.y + a.z*w1.z + a.w*w1.w;
      }
    }
    for (int r = 0; r < 6; ++r) for (int c = 0; c < 2; ++c){
      float v = acc[r][c];
      v += __shfl_xor(v, 16); v += __shfl_xor(v, 32);
      acc[r][c] = v;
    }
    if (ks == 0){
      for (int r = 0; r < 6; ++r) for (int c = 0; c < 2; ++c){
        int col = ot*2 + c, row = r0 + r;
        float bias = (col < 48) ? s_stig[col] : ((col < 62) ? lsb_b[col-48] : 0.f);
        s_C[row*69 + col] = acc[r][c] + bias;
      }
    }
  }
  __syncthreads();
  if (tid < 176){
    int f = tid >> 4, j = tid & 15;
    float acc = lshexp_b[j];
    const float* ein = &s_C[f*69 + 48];
    for (int i = 0; i < 14; ++i) acc += ein[i] * lshexp_W[j*14+i];
    s_sh[f*17 + j] = acc;
  }
  __syncthreads();
  if (tid < 88){
    int st = tid / 11, f = tid % 11;
    float ein[14];
    for (int i = 0; i < 14; ++i) ein[i] = s_C[f*69 + 48 + i];
    float lg[6], mx = -1e30f;
    for (int g = 0; g < 6; ++g){ lg[g] = s_C[f*69 + st*6 + g]; mx = fmaxf(mx, lg[g]); }
    float sum = 0.f;
    for (int g = 0; g < 6; ++g){ lg[g] = __expf(lg[g]-mx); sum += lg[g]; }
    float inv = 1.f/sum;
    float wv[4] = {0,0,0,0};
    for (int g = 0; g < 4; ++g){
      float gg = lg[g]*inv;
      for (int m = 0; m < 4; ++m) wv[m] += gg * s_sh[f*17 + g*4 + m];
    }
    for (int ee = 0; ee < 2; ++ee){
      float gg = lg[4+ee]*inv;
      for (int m = 0; m < 4; ++m){
        float acc = lspexp_b[(st*2+ee)*4+m];
        const float* wp = lspexp_W + ((st*2+ee)*4+m)*14;
        for (int i = 0; i < 14; ++i) acc += ein[i] * wp[i];
        wv[m] += gg*acc;
      }
    }
    float4 o4; o4.x = wv[0]; o4.y = wv[1]; o4.z = wv[2]; o4.w = wv[3];
    *(float4*)&s_w[st*44 + f*4] = o4;
  }
  __syncthreads();
  if (tid < 88){
    int st = tid / 11, oo = tid % 11;
    float acc = ltower_b[st*11+oo];
    const float* tw = ltower_W + (st*11+oo)*44;
    const float* wp = s_w + st*44;
    for (int i = 0; i < 44; ++i) acc += wp[i] * tw[i];
    lt1[(size_t)(st*11+oo)*B_ + b] = acc;
  }
}

// -------- linf: bn(lt)->softmax over fields, weighted lfields -> h[:,128:] --
__global__ __launch_bounds__(128) void k_linf(
    const int* __restrict__ cat, const float* __restrict__ lfields,
    const float* __restrict__ lt1, const float* __restrict__ stl,
    const float* __restrict__ bias_p, float* __restrict__ hbuf)
{
  __shared__ float s_lf[NF_*E_];
  __shared__ float s_lw[22];
  const int b = blockIdx.x, e = threadIdx.x;
  const int scen = cat[(size_t)b*10];
  for (int k = e; k < NF_*E_; k += 128) s_lf[k] = lfields[(size_t)b*NF_*E_ + k];
  if (e < 22){
    int t = e/11, f = e%11, row = (scen*T_+t)*11 + f;
    s_lw[e] = (lt1[(size_t)row*B_+b] - stl[row*2]) * stl[row*2+1];
  }
  __syncthreads();
  if (e < 2){
    int t = e; float mx = -1e30f;
    for (int f = 0; f < 11; ++f) mx = fmaxf(mx, s_lw[t*11+f]);
    float sum = 0.f;
    for (int f = 0; f < 11; ++f){ float x = __expf(s_lw[t*11+f]-mx); s_lw[t*11+f] = x; sum += x; }
    float inv = 1.f/sum;
    for (int f = 0; f < 11; ++f) s_lw[t*11+f] *= inv;
  }
  __syncthreads();
  for (int t = 0; t < 2; ++t){
    float acc = bias_p[(size_t)(t*S_+scen)*E_ + e];
    for (int f = 0; f < 11; ++f) acc += s_lw[t*11+f] * s_lf[f*E_+e];
    hbuf[(size_t)(t*256+128+e)*B_ + b] = acc;
  }
}

// -------- final MLP ---------------------------------------------------------
__global__ __launch_bounds__(256) void k_last1(const float* __restrict__ hbuf,
    const float* __restrict__ W1, const float* __restrict__ b1, float* __restrict__ h1){
  int bz = blockIdx.x, t = bz/80, r = bz%80, og = r/16, bc = r%16;
  __shared__ float s_w1[8*256];
  int tid = threadIdx.x;
  for (int k = tid; k < 2048; k += 256){
    int oo = k>>8, i = k&255;
    s_w1[k] = W1[(size_t)(t*40 + og*8 + oo)*256 + i];
  }
  __syncthreads();
  int b = bc*256 + tid;
  float acc[8];
  for (int oo = 0; oo < 8; ++oo) acc[oo] = b1[t*40 + og*8 + oo];
  for (int i = 0; i < 256; ++i){
    float hv = hbuf[(size_t)(t*256+i)*B_ + b];
    for (int oo = 0; oo < 8; ++oo) acc[oo] += hv * s_w1[oo*256+i];
  }
  for (int oo = 0; oo < 8; ++oo) h1[(size_t)(t*40 + og*8 + oo)*B_ + b] = acc[oo];
}

__global__ __launch_bounds__(256) void k_last2(const float* __restrict__ h1, const float* __restrict__ st1,
    const float* __restrict__ W2, const float* __restrict__ b2v, float* __restrict__ h2){
  int bz = blockIdx.x, t = bz/16, bc = bz%16, tid = threadIdx.x, b = bc*256 + tid;
  __shared__ float s_w2[1280];
  for (int k = tid; k < 1280; k += 256) s_w2[k] = W2[t*1280 + k];
  __syncthreads();
  float hv[40];
  for (int i = 0; i < 40; ++i){
    int row = t*40 + i;
    hv[i] = fmaxf((h1[(size_t)row*B_+b] - st1[row*2]) * st1[row*2+1], 0.f);
  }
  for (int o = 0; o < 32; ++o){
    float acc = b2v[t*32+o];
    for (int i = 0; i < 40; ++i) acc += hv[i] * s_w2[o*40+i];
    h2[(size_t)(t*32+o)*B_ + b] = acc;
  }
}

__global__ __launch_bounds__(256) void k_last3(const float* __restrict__ h2, const float* __restrict__ st2,
    const float* __restrict__ W3, const float* __restrict__ b3v, float* __restrict__ h3){
  int bz = blockIdx.x, t = bz/16, bc = bz%16, tid = threadIdx.x, b = bc*256 + tid;
  __shared__ float s_w3[256];
  if (tid < 256) s_w3[tid] = W3[t*256 + tid];
  __syncthreads();
  float hv[32];
  for (int i = 0; i < 32; ++i){
    int row = t*32 + i;
    hv[i] = fmaxf((h2[(size_t)row*B_+b] - st2[row*2]) * st2[row*2+1], 0.f);
  }
  for (int o = 0; o < 8; ++o){
    float acc = b3v[t*8+o];
    for (int i = 0; i < 32; ++i) acc += hv[i] * s_w3[o*32+i];
    h3[(size_t)(t*8+o)*B_ + b] = acc;
  }
}

__global__ __launch_bounds__(256) void k_out(const float* __restrict__ h3, const float* __restrict__ st3,
    const float* __restrict__ W4, const float* __restrict__ b4v, float* __restrict__ out){
  int idx = blockIdx.x*256 + threadIdx.x;
  int t = idx / B_, b = idx % B_;
  float acc = b4v[t];
  for (int i = 0; i < 8; ++i){
    int row = t*8 + i;
    float v = fmaxf((h3[(size_t)row*B_+b] - st3[row*2]) * st3[row*2+1], 0.f);
    acc += v * W4[t*8+i];
  }
  out[idx] = 1.f/(1.f + __expf(-acc));
}

extern "C" void kernel_launch(void* const* d_in, const int* in_sizes, int n_in,
                              void* d_out, int out_size, void* d_ws, size_t ws_size,
                              hipStream_t stream)
{
  const int*   cat      = (const int*)  d_in[0];
  const float* num      = (const float*)d_in[1];
  const float* embT     = (const float*)d_in[2];
  const float* linT     = (const float*)d_in[3];
  const float* uW = (const float*)d_in[4];  const float* ub = (const float*)d_in[5];
  const float* iW = (const float*)d_in[6];  const float* ib = (const float*)d_in[7];
  const float* ulW = (const float*)d_in[8]; const float* ulb = (const float*)d_in[9];
  const float* ilW = (const float*)d_in[10];const float* ilb = (const float*)d_in[11];
  const float* scen_emb = (const float*)d_in[12];
  const float* task_emb = (const float*)d_in[13];
  const float* st_w     = (const float*)d_in[14];
  const float* interact_w=(const float*)d_in[15];
  const float* sbW = (const float*)d_in[16]; const float* sbb = (const float*)d_in[17];
  const float* lsbW = (const float*)d_in[18];const float* lsbb = (const float*)d_in[19];
  const float* shW = (const float*)d_in[20]; const float* shb = (const float*)d_in[21];
  const float* spW = (const float*)d_in[22]; const float* spb = (const float*)d_in[23];
  const float* lshW = (const float*)d_in[24];const float* lshb = (const float*)d_in[25];
  const float* lspW = (const float*)d_in[26];const float* lspb = (const float*)d_in[27];
  const float* gW = (const float*)d_in[28];  const float* gb = (const float*)d_in[29];
  const float* lgW = (const float*)d_in[30]; const float* lgb = (const float*)d_in[31];
  const float* mW = (const float*)d_in[32];  const float* mb = (const float*)d_in[33];
  const float* attW = (const float*)d_in[34];
  const float* ltW = (const float*)d_in[35]; const float* ltb = (const float*)d_in[36];
  const float* biasP = (const float*)d_in[37];
  const float* W1 = (const float*)d_in[38];  const float* b1 = (const float*)d_in[39];
  const float* W2 = (const float*)d_in[40];  const float* b2v = (const float*)d_in[41];
  const float* W3 = (const float*)d_in[42];  const float* b3v = (const float*)d_in[43];
  const float* W4 = (const float*)d_in[44];  const float* b4v = (const float*)d_in[45];
  float* out = (float*)d_out;

  float* ws = (float*)d_ws;
  size_t o = 0;
  float* fieldsB  = ws + o; o += (size_t)B_*NF_*E_;
  float* lfieldsB = ws + o; o += (size_t)B_*NF_*E_;
  float* Wu   = ws + o; o += 8192;
  float* lWu  = ws + o; o += 8192;
  float* w_g  = ws + o; o += (size_t)B_*8*224;
  float* m1   = ws + o; o += (size_t)440*B_;
  float* stm  = ws + o; o += 880;
  float* lt1  = ws + o; o += (size_t)88*B_;
  float* stl  = ws + o; o += 176;
  float* hbuf = ws + o; o += (size_t)T_*256*B_;
  float* h1   = ws + o; o += (size_t)80*B_;
  float* st1  = ws + o; o += 160;
  float* h2   = ws + o; o += (size_t)64*B_;
  float* st2  = ws + o; o += 128;
  float* h3   = ws + o; o += (size_t)16*B_;
  float* st3  = ws + o; o += 32;

  k_prep<<<64, 256, 0, stream>>>(gW, lgW, sbW, lsbW, Wu, lWu);
  k_fields<<<B_, 128, 0, stream>>>(cat, num, embT, linT, uW, ub, iW, ib, ulW, ulb, ilW, ilb, fieldsB, lfieldsB);
  k_moe1<<<B_/4, 512, 0, stream>>>(cat, scen_emb, task_emb, st_w, interact_w, sbb, shW, shb,
                                   spW, spb, gW, gb, fieldsB, Wu, w_g);
  k_mask<<<512, 256, 0, stream>>>(w_g, mW, mb, m1);
  k_moe2<<<B_, 256, 0, stream>>>(cat, scen_emb, task_emb, st_w, lsbb, lshW, lshb,
                                 lspW, lspb, lgW, lgb, ltW, ltb, lfieldsB, lWu, lt1);
  k_stats2<<<528, 256, 0, stream>>>(m1, lt1, 440, stm, stl);
  k_inter<<<B_, 128, 0, stream>>>(cat, fieldsB, m1, stm, attW, interact_w, hbuf);
  k_linf<<<B_, 128, 0, stream>>>(cat, lfieldsB, lt1, stl, biasP, hbuf);
  k_last1<<<160, 256, 0, stream>>>(hbuf, W1, b1, h1);
  k_stats<<<80, 256, 0, stream>>>(h1, st1);
  k_last2<<<32, 256, 0, stream>>>(h1, st1, W2, b2v, h2);
  k_stats<<<64, 256, 0, stream>>>(h2, st2);
  k_last3<<<32, 256, 0, stream>>>(h2, st2, W3, b3v, h3);
  k_stats<<<16, 256, 0, stream>>>(h3, st3);
  k_out<<<32, 256, 0, stream>>>(h3, st3, W4, b4v, out);
}

// Round 9
// 464.091 us; speedup vs baseline: 1.1737x; 1.0400x over previous
//
#include <hip/hip_runtime.h>
#include <hip/hip_bf16.h>

#define B_ 4096
#define T_ 2
#define S_ 4
#define E_ 128
#define NF_ 11
#define ID_ 55
#define MID_ 4
#define NG_ 6
#define SI_ 4
#define EPSf 1e-5f

// triu_indices(11, k=1) pairs, padded to 64 rows (rows 55..63: PR=PC=0, masked by iw=0)
__device__ const int PR[64]={0,0,0,0,0,0,0,0,0,0,1,1,1,1,1,1,1,1,1,2,2,2,2,2,2,2,2,3,3,3,3,3,3,3,4,4,4,4,4,4,5,5,5,5,5,6,6,6,6,7,7,7,8,8,9,0,0,0,0,0,0,0,0,0};
__device__ const int PC[64]={1,2,3,4,5,6,7,8,9,10,2,3,4,5,6,7,8,9,10,3,4,5,6,7,8,9,10,4,5,6,7,8,9,10,5,6,7,8,9,10,6,7,8,9,10,7,8,9,10,8,9,10,9,10,10,0,0,0,0,0,0,0,0,0};

// -------- prep: unified weight matrices Wu/lWu [64 rows][128 k] -------------
// rows 0-47: gate (st*6+g) E-part; rows 48-61: sb_W; rows 62-63: zero
__global__ void k_prep(const float* __restrict__ gW, const float* __restrict__ lgW,
                       const float* __restrict__ sbW, const float* __restrict__ lsbW,
                       float* __restrict__ Wu, float* __restrict__ lWu){
  int k = blockIdx.x*256 + threadIdx.x;
  if (k < 16384){
    int arr = k >> 13, rem = k & 8191;
    int o = rem >> 7, e = rem & 127;
    const float* g = arr ? lgW : gW;
    const float* s = arr ? lsbW : sbW;
    float v;
    if (o < 48) v = g[o*132 + 4 + e];
    else if (o < 62) v = s[(o-48)*128 + e];
    else v = 0.f;
    (arr ? lWu : Wu)[o*128 + e] = v;
  }
}

// -------- fields: gathers + user/item projections ---------------------------
__global__ __launch_bounds__(128) void k_fields(
    const int* __restrict__ cat, const float* __restrict__ num,
    const float* __restrict__ embT, const float* __restrict__ linT,
    const float* __restrict__ uW, const float* __restrict__ ub,
    const float* __restrict__ iW, const float* __restrict__ ib,
    const float* __restrict__ ulW, const float* __restrict__ ulb,
    const float* __restrict__ ilW, const float* __restrict__ ilb,
    float* __restrict__ fields, float* __restrict__ lfields)
{
  const int b = blockIdx.x, e = threadIdx.x;
  __shared__ float s_num[63];
  if (e < 63) s_num[e] = num[(size_t)b*63 + e];
  __syncthreads();
  const int* cb = cat + (size_t)b*10;
  float* fo = fields  + (size_t)b*NF_*E_;
  float* lo = lfields + (size_t)b*NF_*E_;
  for (int j = 0; j < 9; ++j){
    int id = cb[1+j] + j*1000;
    fo[j*E_+e] = embT[(size_t)id*E_+e];
    lo[j*E_+e] = linT[(size_t)id*E_+e];
  }
  float a0 = ub[e], a1 = ulb[e];
  for (int k = 0; k < 23; ++k){ float x = s_num[k]; a0 += x*uW[e*23+k]; a1 += x*ulW[e*23+k]; }
  fo[9*E_+e] = a0; lo[9*E_+e] = a1;
  float a2 = ib[e], a3 = ilb[e];
  for (int k = 0; k < 40; ++k){ float x = s_num[23+k]; a2 += x*iW[e*40+k]; a3 += x*ilW[e*40+k]; }
  fo[10*E_+e] = a2; lo[10*E_+e] = a3;
}

// -------- moe12: R3 moe1 (validated 125.7us) + fused moe2 -------------------
// moe1 part is byte-identical to R3: ct=tid>>5, rt=tid&31, acc[2][8], s_Wu
// staged in LDS. moe2 is appended after w_g, with its LDS overlaid inside
// moe1's footprint (no occupancy change: 37.9 KB, 4 blk/CU):
//   s_lf  @5916 (12x132=1584, inside s_w region 1760)
//   m2_w  @7676 (352) + m2_sh @8028 (187)   (inside s_sh region 935)
//   m2_C  @8611 (828) + m2_stig @9439 (48)  (tail 8611..9692)
// All K-summation orders identical to the separate kernels -> absmax 0.0.
__global__ __launch_bounds__(256) void k_moe12(
    const int* __restrict__ cat,
    const float* __restrict__ scen_emb, const float* __restrict__ task_emb,
    const float* __restrict__ st_w, const float* __restrict__ interact_w,
    const float* __restrict__ sb_b,
    const float* __restrict__ shexp_W, const float* __restrict__ shexp_b,
    const float* __restrict__ spexp_W, const float* __restrict__ spexp_b,
    const float* __restrict__ gate_W, const float* __restrict__ gate_b,
    const float* __restrict__ fields, const float* __restrict__ Wu,
    const float* __restrict__ lsb_b,
    const float* __restrict__ lshexp_W, const float* __restrict__ lshexp_b,
    const float* __restrict__ lspexp_W, const float* __restrict__ lspexp_b,
    const float* __restrict__ lgate_W, const float* __restrict__ lgate_b,
    const float* __restrict__ ltower_W, const float* __restrict__ ltower_b,
    const float* __restrict__ lfields, const float* __restrict__ lWu,
    float* __restrict__ w_g, float* __restrict__ lt1)
{
  __shared__ float sm[9692];
  float* s_fld = sm;           // 11 x 132
  float* s_stig= sm + 1452;    // 48
  float* s_Wu  = sm + 1500;    // 64 x 128 (GEMM phase)
  float* s_C   = sm + 1500;    // overlay: 64 x 69
  float* s_w   = sm + 5916;    // overlay: 8 x 220
  float* s_sh  = sm + 7676;    // overlay: 55 x 17
  // moe2 overlays (live only after moe1 completes):
  float* s_lf   = sm + 5916;   // 12 x 132
  float* m2_w   = sm + 7676;   // 8 x 44
  float* m2_sh  = sm + 8028;   // 11 x 17
  float* m2_C   = sm + 8611;   // 12 x 69
  float* m2_stig= sm + 9439;   // 48
  const int tid = threadIdx.x, b = blockIdx.x;
  const int scen = cat[(size_t)b*10];

  // ---- moe1: stage fields (stride 132), Wu (linear), stig ----
  for (int idx = tid; idx < 352; idx += 256){
    int f = idx >> 5, q = idx & 31;
    *(float4*)&s_fld[f*132 + q*4] = *(const float4*)&fields[(size_t)b*1408 + idx*4];
  }
  for (int idx = tid; idx < 2048; idx += 256)
    *(float4*)&s_Wu[idx*4] = *(const float4*)&Wu[idx*4];
  if (tid < 48){
    int t = (tid/6)%T_;
    float stw = st_w[t*S_ + scen];
    float acc = gate_b[tid];
    for (int i = 0; i < 4; ++i){
      float sti = scen_emb[scen*4+i] * task_emb[t*4+i] * stw;
      acc += sti * gate_W[tid*132 + i];
    }
    s_stig[tid] = acc;
  }
  __syncthreads();

  // ---- moe1 GEMM: rows {2rt,2rt+1} x cols [8ct,8ct+8), full K=128 ----
  {
    const int ct = tid >> 5;          // 0..7
    const int rt = tid & 31;          // 0..31
    const int r0 = rt*2;
    const int ra0 = PR[r0]*132,   ca0 = PC[r0]*132;
    const int ra1 = PR[r0+1]*132, ca1 = PC[r0+1]*132;
    float acc[2][8];
    for (int c = 0; c < 8; ++c){ acc[0][c] = 0.f; acc[1][c] = 0.f; }
    const float4* Wu4 = (const float4*)s_Wu;   // [row][k/4], row stride 32
    #pragma unroll 1
    for (int kk = 0; kk < 128; kk += 4){
      int wb = kk >> 2;
      float4 x0 = *(const float4*)&s_fld[ra0 + kk];
      float4 y0 = *(const float4*)&s_fld[ca0 + kk];
      float4 x1 = *(const float4*)&s_fld[ra1 + kk];
      float4 y1 = *(const float4*)&s_fld[ca1 + kk];
      float4 p0, p1;
      p0.x = x0.x*y0.x; p0.y = x0.y*y0.y; p0.z = x0.z*y0.z; p0.w = x0.w*y0.w;
      p1.x = x1.x*y1.x; p1.y = x1.y*y1.y; p1.z = x1.z*y1.z; p1.w = x1.w*y1.w;
      for (int h = 0; h < 2; ++h){
        float4 wv[4];
        for (int c = 0; c < 4; ++c) wv[c] = Wu4[(ct*8 + h*4 + c)*32 + wb];
        for (int c = 0; c < 4; ++c){
          acc[0][h*4+c] += p0.x*wv[c].x + p0.y*wv[c].y + p0.z*wv[c].z + p0.w*wv[c].w;
          acc[1][h*4+c] += p1.x*wv[c].x + p1.y*wv[c].y + p1.z*wv[c].z + p1.w*wv[c].w;
        }
      }
    }
    __syncthreads();   // all s_Wu reads complete before s_C overlays it
    for (int r = 0; r < 2; ++r){
      int row = r0 + r;
      float iw = (row < 55) ? interact_w[row] : 0.f;  // iw distributes out of K-sum
      for (int c = 0; c < 8; ++c){
        int col = ct*8 + c;
        float bias = (col < 48) ? s_stig[col] : ((col < 62) ? sb_b[col-48] : 0.f);
        s_C[row*69 + col] = acc[r][c]*iw + bias;
      }
    }
  }
  __syncthreads();
  // ---- moe1 shared experts ----
  for (int o = tid; o < 880; o += 256){
    int f = o >> 4, j = o & 15;
    float acc = shexp_b[j];
    const float* ein = &s_C[f*69 + 48];
    const float* wp = &shexp_W[j*14];
    for (int i = 0; i < 14; ++i) acc += ein[i] * wp[i];
    s_sh[f*17 + j] = acc;
  }
  __syncthreads();
  // ---- moe1 softmax + specific experts + mixture ----
  for (int task = tid; task < 440; task += 256){
    int st = task / 55, f = task % 55;
    float ein[14];
    for (int i = 0; i < 14; ++i) ein[i] = s_C[f*69 + 48 + i];
    float lg[6], mx = -1e30f;
    for (int g = 0; g < 6; ++g){ lg[g] = s_C[f*69 + st*6 + g]; mx = fmaxf(mx, lg[g]); }
    float sum = 0.f;
    for (int g = 0; g < 6; ++g){ lg[g] = __expf(lg[g]-mx); sum += lg[g]; }
    float inv = 1.f/sum;
    float wv[4] = {0,0,0,0};
    for (int g = 0; g < 4; ++g){
      float gg = lg[g]*inv;
      for (int m = 0; m < 4; ++m) wv[m] += gg * s_sh[f*17 + g*4 + m];
    }
    for (int ee = 0; ee < 2; ++ee){
      float gg = lg[4+ee]*inv;
      for (int m = 0; m < 4; ++m){
        float acc = spexp_b[(st*2+ee)*4+m];
        const float* wp = spexp_W + ((st*2+ee)*4+m)*14;
        for (int i = 0; i < 14; ++i) acc += ein[i] * wp[i];
        wv[m] += gg*acc;
      }
    }
    float4 o4; o4.x = wv[0]; o4.y = wv[1]; o4.z = wv[2]; o4.w = wv[3];
    *(float4*)&s_w[st*220 + f*4] = o4;
  }
  __syncthreads();
  // ---- moe1 w_g write (zero-padded cols 220..223) ----
  for (int idx = tid; idx < 448; idx += 256){
    int st = idx / 56, q = idx % 56;
    float4 v;
    if (q < 55) v = *(float4*)&s_w[st*220 + q*4];
    else { v.x=v.y=v.z=v.w=0.f; }
    *(float4*)&w_g[((size_t)b*8 + st)*224 + q*4] = v;
  }
  __syncthreads();   // s_w reads done before s_lf overlays it

  // ---- moe2: stage lfields + stig2 ----
  for (int idx = tid; idx < 352; idx += 256){
    int f = idx >> 5, q = idx & 31;
    *(float4*)&s_lf[f*132 + q*4] = *(const float4*)&lfields[(size_t)b*1408 + f*128 + q*4];
  }
  if (tid >= 224){ // zero row 11 (32 threads)
    int q = tid - 224;
    float4 z = {0,0,0,0}; *(float4*)&s_lf[11*132 + q*4] = z;
  }
  if (tid < 48){
    int t = (tid/6)%T_;
    float stw = st_w[t*S_ + scen];
    float acc = lgate_b[tid];
    for (int i = 0; i < 4; ++i){
      float sti = scen_emb[scen*4+i] * task_emb[t*4+i] * stw;
      acc += sti * lgate_W[tid*132 + i];
    }
    m2_stig[tid] = acc;
  }
  __syncthreads();
  // ---- moe2 GEMM over 4 waves: C[12][64] = lf[12][128] * lWu^T ----
  {
    const int lane = tid & 63, wv_ = tid >> 6;
    const int pr = wv_*16 + (lane & 15);     // 0..63
    const int ks = lane >> 4;                // 4-way K split
    const int ft = pr & 1, ot = pr >> 1;     // 2 row-tiles x 32 col-tiles(2)
    const int r0 = ft*6, k0 = ks*32;
    float acc[6][2];
    for (int r = 0; r < 6; ++r){ acc[r][0] = 0.f; acc[r][1] = 0.f; }
    const float4* W4 = (const float4*)lWu;
    #pragma unroll 1
    for (int kc = 0; kc < 32; kc += 4){
      int kk = k0 + ((kc + ks*8) & 31);
      float4 w0 = W4[(ot*2+0)*32 + (kk>>2)];
      float4 w1 = W4[(ot*2+1)*32 + (kk>>2)];
      for (int r = 0; r < 6; ++r){
        float4 a = *(const float4*)&s_lf[(r0+r)*132 + kk];
        acc[r][0] += a.x*w0.x + a.y*w0.y + a.z*w0.z + a.w*w0.w;
        acc[r][1] += a.x*w1.x + a.y*w1.y + a.z*w1.z + a.w*w1.w;
      }
    }
    for (int r = 0; r < 6; ++r) for (int c = 0; c < 2; ++c){
      float v = acc[r][c];
      v += __shfl_xor(v, 16); v += __shfl_xor(v, 32);
      acc[r][c] = v;
    }
    if (ks == 0){
      for (int r = 0; r < 6; ++r) for (int c = 0; c < 2; ++c){
        int col = ot*2 + c, row = r0 + r;
        float bias = (col < 48) ? m2_stig[col] : ((col < 62) ? lsb_b[col-48] : 0.f);
        m2_C[row*69 + col] = acc[r][c] + bias;
      }
    }
  }
  __syncthreads();
  if (tid < 176){
    int f = tid >> 4, j = tid & 15;
    float acc = lshexp_b[j];
    const float* ein = &m2_C[f*69 + 48];
    for (int i = 0; i < 14; ++i) acc += ein[i] * lshexp_W[j*14+i];
    m2_sh[f*17 + j] = acc;
  }
  __syncthreads();
  if (tid < 88){
    int st = tid / 11, f = tid % 11;
    float ein[14];
    for (int i = 0; i < 14; ++i) ein[i] = m2_C[f*69 + 48 + i];
    float lg[6], mx = -1e30f;
    for (int g = 0; g < 6; ++g){ lg[g] = m2_C[f*69 + st*6 + g]; mx = fmaxf(mx, lg[g]); }
    float sum = 0.f;
    for (int g = 0; g < 6; ++g){ lg[g] = __expf(lg[g]-mx); sum += lg[g]; }
    float inv = 1.f/sum;
    float wv[4] = {0,0,0,0};
    for (int g = 0; g < 4; ++g){
      float gg = lg[g]*inv;
      for (int m = 0; m < 4; ++m) wv[m] += gg * m2_sh[f*17 + g*4 + m];
    }
    for (int ee = 0; ee < 2; ++ee){
      float gg = lg[4+ee]*inv;
      for (int m = 0; m < 4; ++m){
        float acc = lspexp_b[(st*2+ee)*4+m];
        const float* wp = lspexp_W + ((st*2+ee)*4+m)*14;
        for (int i = 0; i < 14; ++i) acc += ein[i] * wp[i];
        wv[m] += gg*acc;
      }
    }
    float4 o4; o4.x = wv[0]; o4.y = wv[1]; o4.z = wv[2]; o4.w = wv[3];
    *(float4*)&m2_w[st*44 + f*4] = o4;
  }
  __syncthreads();
  if (tid < 88){
    int st = tid / 11, oo = tid % 11;
    float acc = ltower_b[st*11+oo];
    const float* tw = ltower_W + (st*11+oo)*44;
    const float* wp = m2_w + st*44;
    for (int i = 0; i < 44; ++i) acc += wp[i] * tw[i];
    lt1[(size_t)(st*11+oo)*B_ + b] = acc;
  }
}

// -------- mask batch GEMM: m1[st*55+oo][b] = mW[st] x w^T + mb --------------
// grid: 512 blocks = 8 st x 64 b-tiles(64). LDS: s_mw[56*116] + s_wb[64*116]
__global__ __launch_bounds__(256) void k_mask(
    const float* __restrict__ w_g, const float* __restrict__ mask_W,
    const float* __restrict__ mask_b, float* __restrict__ m1)
{
  __shared__ float s_mw[56*116];
  __shared__ float s_wb[64*116];
  const int tid = threadIdx.x;
  const int st = blockIdx.x >> 6, bt = blockIdx.x & 63;
  const int b0 = bt*64;
  const int btl = tid & 15, ot = tid >> 4;   // ot<14 active
  float acc[4][4];
  for (int c = 0; c < 4; ++c) for (int j = 0; j < 4; ++j) acc[c][j] = 0.f;

  for (int kc = 0; kc < 2; ++kc){
    __syncthreads();
    for (int idx = tid; idx < 64*112; idx += 256){
      int r = idx / 112, k = idx % 112;
      s_wb[r*116 + k] = w_g[((size_t)(b0+r)*8 + st)*224 + kc*112 + k];
    }
    for (int idx = tid; idx < 56*112; idx += 256){
      int r = idx / 112, k = idx % 112;
      int kg = kc*112 + k;
      s_mw[r*116 + k] = (r < 55 && kg < 220) ? mask_W[((size_t)st*55 + r)*220 + kg] : 0.f;
    }
    __syncthreads();
    if (ot < 14){
      for (int k4 = 0; k4 < 112; k4 += 4){
        float4 a[4], wb[4];
        for (int c = 0; c < 4; ++c) a[c]  = *(float4*)&s_mw[(ot*4+c)*116 + k4];
        for (int j = 0; j < 4; ++j) wb[j] = *(float4*)&s_wb[(btl*4+j)*116 + k4];
        for (int c = 0; c < 4; ++c)
          for (int j = 0; j < 4; ++j)
            acc[c][j] += a[c].x*wb[j].x + a[c].y*wb[j].y + a[c].z*wb[j].z + a[c].w*wb[j].w;
      }
    }
  }
  if (ot < 14){
    for (int c = 0; c < 4; ++c){
      int row = ot*4 + c;
      if (row < 55){
        float mb = mask_b[st*55 + row];
        float4 v; v.x = acc[c][0]+mb; v.y = acc[c][1]+mb; v.z = acc[c][2]+mb; v.w = acc[c][3]+mb;
        *(float4*)&m1[(size_t)(st*55+row)*B_ + b0 + btl*4] = v;
      }
    }
  }
}

// -------- per-row batch stats (mean, rsqrt(var+eps)) ------------------------
__global__ __launch_bounds__(256) void k_stats(const float* __restrict__ x, float* __restrict__ stats){
  const int row = blockIdx.x, tid = threadIdx.x;
  const float* xr = x + (size_t)row*B_;
  float s = 0.f, s2 = 0.f;
  for (int i = tid; i < B_; i += 256){ float v = xr[i]; s += v; s2 += v*v; }
  for (int off = 32; off > 0; off >>= 1){ s += __shfl_down(s, off); s2 += __shfl_down(s2, off); }
  __shared__ float red[8];
  if ((tid & 63) == 0){ red[(tid>>6)*2] = s; red[(tid>>6)*2+1] = s2; }
  __syncthreads();
  if (tid == 0){
    float Ssum = red[0]+red[2]+red[4]+red[6], S2 = red[1]+red[3]+red[5]+red[7];
    float mean = Ssum*(1.f/B_), var = S2*(1.f/B_) - mean*mean;
    stats[row*2] = mean; stats[row*2+1] = rsqrtf(fmaxf(var, 0.f) + EPSf);
  }
}

// -------- fused stats for two row-batches (m1: n1 rows, then x2) ------------
__global__ __launch_bounds__(256) void k_stats2(const float* __restrict__ x1, const float* __restrict__ x2,
                                                int n1, float* __restrict__ st1o, float* __restrict__ st2o){
  const int row = blockIdx.x, tid = threadIdx.x;
  const float* xr; float* sto;
  if (row < n1){ xr = x1 + (size_t)row*B_; sto = st1o + row*2; }
  else { int r = row - n1; xr = x2 + (size_t)r*B_; sto = st2o + r*2; }
  float s = 0.f, s2 = 0.f;
  for (int i = tid; i < B_; i += 256){ float v = xr[i]; s += v; s2 += v*v; }
  for (int off = 32; off > 0; off >>= 1){ s += __shfl_down(s, off); s2 += __shfl_down(s2, off); }
  __shared__ float red[8];
  if ((tid & 63) == 0){ red[(tid>>6)*2] = s; red[(tid>>6)*2+1] = s2; }
  __syncthreads();
  if (tid == 0){
    float Ssum = red[0]+red[2]+red[4]+red[6], S2 = red[1]+red[3]+red[5]+red[7];
    float mean = Ssum*(1.f/B_), var = S2*(1.f/B_) - mean*mean;
    sto[0] = mean; sto[1] = rsqrtf(fmaxf(var, 0.f) + EPSf);
  }
}

// -------- interlinf: fused k_inter + k_linf (both per-b, 128 thr) -----------
// inter: bn(m)->tanh->relu, weighted pe contraction -> hbuf[t*256 + e]
// linf:  bn(lt)->softmax over fields, weighted lfields + bias -> hbuf[t*256+128+e]
// NOTE: s_lw staged with if(e<22) — threads 0..21 do both s_co and s_lw loads
// (R7's e>=112&&e<134 guard never fired for q>=16 in a 128-thread block).
__global__ __launch_bounds__(128) void k_interlinf(
    const int* __restrict__ cat, const float* __restrict__ fields,
    const float* __restrict__ lfields,
    const float* __restrict__ m1, const float* __restrict__ stm,
    const float* __restrict__ lt1, const float* __restrict__ stl,
    const float* __restrict__ att_W, const float* __restrict__ interact_w,
    const float* __restrict__ bias_p, float* __restrict__ hbuf)
{
  __shared__ float s_fld[NF_*E_];
  __shared__ float s_lf[NF_*E_];
  __shared__ float s_co[110];
  __shared__ float s_lw[22];
  const int b = blockIdx.x, e = threadIdx.x;
  const int scen = cat[(size_t)b*10];
  for (int k = e; k < NF_*E_; k += 128){
    s_fld[k] = fields[(size_t)b*NF_*E_ + k];
    s_lf[k]  = lfields[(size_t)b*NF_*E_ + k];
  }
  if (e < 110){
    int t = e/55, f = e%55, row = (scen*T_+t)*55 + f;
    float v = (m1[(size_t)row*B_+b] - stm[row*2]) * stm[row*2+1];
    v = fmaxf(tanhf(v), 0.f);
    s_co[e] = v * att_W[(scen*T_+t)*55 + f];
  }
  if (e < 22){
    int t = e/11, f = e%11, row = (scen*T_+t)*11 + f;
    s_lw[e] = (lt1[(size_t)row*B_+b] - stl[row*2]) * stl[row*2+1];
  }
  __syncthreads();
  if (e < 2){
    int t = e; float mx = -1e30f;
    for (int f = 0; f < 11; ++f) mx = fmaxf(mx, s_lw[t*11+f]);
    float sum = 0.f;
    for (int f = 0; f < 11; ++f){ float x = __expf(s_lw[t*11+f]-mx); s_lw[t*11+f] = x; sum += x; }
    float inv = 1.f/sum;
    for (int f = 0; f < 11; ++f) s_lw[t*11+f] *= inv;
  }
  __syncthreads();
  // inter half
  {
    float a0 = 0.f, a1 = 0.f;
    for (int f = 0; f < 55; ++f){
      float pe = s_fld[PR[f]*E_+e] * s_fld[PC[f]*E_+e] * interact_w[f];
      a0 += s_co[f]*pe; a1 += s_co[55+f]*pe;
    }
    hbuf[(size_t)(0*256+e)*B_ + b] = a0;
    hbuf[(size_t)(1*256+e)*B_ + b] = a1;
  }
  // linf half
  for (int t = 0; t < 2; ++t){
    float acc = bias_p[(size_t)(t*S_+scen)*E_ + e];
    for (int f = 0; f < 11; ++f) acc += s_lw[t*11+f] * s_lf[f*E_+e];
    hbuf[(size_t)(t*256+128+e)*B_ + b] = acc;
  }
}

// -------- final MLP ---------------------------------------------------------
__global__ __launch_bounds__(256) void k_last1(const float* __restrict__ hbuf,
    const float* __restrict__ W1, const float* __restrict__ b1, float* __restrict__ h1){
  int bz = blockIdx.x, t = bz/80, r = bz%80, og = r/16, bc = r%16;
  __shared__ float s_w1[8*256];
  int tid = threadIdx.x;
  for (int k = tid; k < 2048; k += 256){
    int oo = k>>8, i = k&255;
    s_w1[k] = W1[(size_t)(t*40 + og*8 + oo)*256 + i];
  }
  __syncthreads();
  int b = bc*256 + tid;
  float acc[8];
  for (int oo = 0; oo < 8; ++oo) acc[oo] = b1[t*40 + og*8 + oo];
  for (int i = 0; i < 256; ++i){
    float hv = hbuf[(size_t)(t*256+i)*B_ + b];
    for (int oo = 0; oo < 8; ++oo) acc[oo] += hv * s_w1[oo*256+i];
  }
  for (int oo = 0; oo < 8; ++oo) h1[(size_t)(t*40 + og*8 + oo)*B_ + b] = acc[oo];
}

__global__ __launch_bounds__(256) void k_last2(const float* __restrict__ h1, const float* __restrict__ st1,
    const float* __restrict__ W2, const float* __restrict__ b2v, float* __restrict__ h2){
  int bz = blockIdx.x, t = bz/16, bc = bz%16, tid = threadIdx.x, b = bc*256 + tid;
  __shared__ float s_w2[1280];
  for (int k = tid; k < 1280; k += 256) s_w2[k] = W2[t*1280 + k];
  __syncthreads();
  float hv[40];
  for (int i = 0; i < 40; ++i){
    int row = t*40 + i;
    hv[i] = fmaxf((h1[(size_t)row*B_+b] - st1[row*2]) * st1[row*2+1], 0.f);
  }
  for (int o = 0; o < 32; ++o){
    float acc = b2v[t*32+o];
    for (int i = 0; i < 40; ++i) acc += hv[i] * s_w2[o*40+i];
    h2[(size_t)(t*32+o)*B_ + b] = acc;
  }
}

__global__ __launch_bounds__(256) void k_last3(const float* __restrict__ h2, const float* __restrict__ st2,
    const float* __restrict__ W3, const float* __restrict__ b3v, float* __restrict__ h3){
  int bz = blockIdx.x, t = bz/16, bc = bz%16, tid = threadIdx.x, b = bc*256 + tid;
  __shared__ float s_w3[256];
  if (tid < 256) s_w3[tid] = W3[t*256 + tid];
  __syncthreads();
  float hv[32];
  for (int i = 0; i < 32; ++i){
    int row = t*32 + i;
    hv[i] = fmaxf((h2[(size_t)row*B_+b] - st2[row*2]) * st2[row*2+1], 0.f);
  }
  for (int o = 0; o < 8; ++o){
    float acc = b3v[t*8+o];
    for (int i = 0; i < 32; ++i) acc += hv[i] * s_w3[o*32+i];
    h3[(size_t)(t*8+o)*B_ + b] = acc;
  }
}

__global__ __launch_bounds__(256) void k_out(const float* __restrict__ h3, const float* __restrict__ st3,
    const float* __restrict__ W4, const float* __restrict__ b4v, float* __restrict__ out){
  int idx = blockIdx.x*256 + threadIdx.x;
  int t = idx / B_, b = idx % B_;
  float acc = b4v[t];
  for (int i = 0; i < 8; ++i){
    int row = t*8 + i;
    float v = fmaxf((h3[(size_t)row*B_+b] - st3[row*2]) * st3[row*2+1], 0.f);
    acc += v * W4[t*8+i];
  }
  out[idx] = 1.f/(1.f + __expf(-acc));
}

extern "C" void kernel_launch(void* const* d_in, const int* in_sizes, int n_in,
                              void* d_out, int out_size, void* d_ws, size_t ws_size,
                              hipStream_t stream)
{
  const int*   cat      = (const int*)  d_in[0];
  const float* num      = (const float*)d_in[1];
  const float* embT     = (const float*)d_in[2];
  const float* linT     = (const float*)d_in[3];
  const float* uW = (const float*)d_in[4];  const float* ub = (const float*)d_in[5];
  const float* iW = (const float*)d_in[6];  const float* ib = (const float*)d_in[7];
  const float* ulW = (const float*)d_in[8]; const float* ulb = (const float*)d_in[9];
  const float* ilW = (const float*)d_in[10];const float* ilb = (const float*)d_in[11];
  const float* scen_emb = (const float*)d_in[12];
  const float* task_emb = (const float*)d_in[13];
  const float* st_w     = (const float*)d_in[14];
  const float* interact_w=(const float*)d_in[15];
  const float* sbW = (const float*)d_in[16]; const float* sbb = (const float*)d_in[17];
  const float* lsbW = (const float*)d_in[18];const float* lsbb = (const float*)d_in[19];
  const float* shW = (const float*)d_in[20]; const float* shb = (const float*)d_in[21];
  const float* spW = (const float*)d_in[22]; const float* spb = (const float*)d_in[23];
  const float* lshW = (const float*)d_in[24];const float* lshb = (const float*)d_in[25];
  const float* lspW = (const float*)d_in[26];const float* lspb = (const float*)d_in[27];
  const float* gW = (const float*)d_in[28];  const float* gb = (const float*)d_in[29];
  const float* lgW = (const float*)d_in[30]; const float* lgb = (const float*)d_in[31];
  const float* mW = (const float*)d_in[32];  const float* mb = (const float*)d_in[33];
  const float* attW = (const float*)d_in[34];
  const float* ltW = (const float*)d_in[35]; const float* ltb = (const float*)d_in[36];
  const float* biasP = (const float*)d_in[37];
  const float* W1 = (const float*)d_in[38];  const float* b1 = (const float*)d_in[39];
  const float* W2 = (const float*)d_in[40];  const float* b2v = (const float*)d_in[41];
  const float* W3 = (const float*)d_in[42];  const float* b3v = (const float*)d_in[43];
  const float* W4 = (const float*)d_in[44];  const float* b4v = (const float*)d_in[45];
  float* out = (float*)d_out;

  float* ws = (float*)d_ws;
  size_t o = 0;
  float* fieldsB  = ws + o; o += (size_t)B_*NF_*E_;
  float* lfieldsB = ws + o; o += (size_t)B_*NF_*E_;
  float* Wu   = ws + o; o += 8192;
  float* lWu  = ws + o; o += 8192;
  float* w_g  = ws + o; o += (size_t)B_*8*224;
  float* m1   = ws + o; o += (size_t)440*B_;
  float* stm  = ws + o; o += 880;
  float* lt1  = ws + o; o += (size_t)88*B_;
  float* stl  = ws + o; o += 176;
  float* hbuf = ws + o; o += (size_t)T_*256*B_;
  float* h1   = ws + o; o += (size_t)80*B_;
  float* st1  = ws + o; o += 160;
  float* h2   = ws + o; o += (size_t)64*B_;
  float* st2  = ws + o; o += 128;
  float* h3   = ws + o; o += (size_t)16*B_;
  float* st3  = ws + o; o += 32;

  k_prep<<<64, 256, 0, stream>>>(gW, lgW, sbW, lsbW, Wu, lWu);
  k_fields<<<B_, 128, 0, stream>>>(cat, num, embT, linT, uW, ub, iW, ib, ulW, ulb, ilW, ilb, fieldsB, lfieldsB);
  k_moe12<<<B_, 256, 0, stream>>>(cat, scen_emb, task_emb, st_w, interact_w, sbb, shW, shb,
                                  spW, spb, gW, gb, fieldsB, Wu,
                                  lsbb, lshW, lshb, lspW, lspb, lgW, lgb, ltW, ltb,
                                  lfieldsB, lWu, w_g, lt1);
  k_mask<<<512, 256, 0, stream>>>(w_g, mW, mb, m1);
  k_stats2<<<528, 256, 0, stream>>>(m1, lt1, 440, stm, stl);
  k_interlinf<<<B_, 128, 0, stream>>>(cat, fieldsB, lfieldsB, m1, stm, lt1, stl,
                                      attW, interact_w, biasP, hbuf);
  k_last1<<<160, 256, 0, stream>>>(hbuf, W1, b1, h1);
  k_stats<<<80, 256, 0, stream>>>(h1, st1);
  k_last2<<<32, 256, 0, stream>>>(h1, st1, W2, b2v, h2);
  k_stats<<<64, 256, 0, stream>>>(h2, st2);
  k_last3<<<32, 256, 0, stream>>>(h2, st2, W3, b3v, h3);
  k_stats<<<16, 256, 0, stream>>>(h3, st3);
  k_out<<<32, 256, 0, stream>>>(h3, st3, W4, b4v, out);
}

// Round 10
// 462.925 us; speedup vs baseline: 1.1767x; 1.0025x over previous
//
#include <hip/hip_runtime.h>
#include <hip/hip_bf16.h>

#define B_ 4096
#define T_ 2
#define S_ 4
#define E_ 128
#define NF_ 11
#define ID_ 55
#define MID_ 4
#define NG_ 6
#define SI_ 4
#define EPSf 1e-5f

// triu_indices(11, k=1) pairs, padded to 64 rows (rows 55..63: PR=PC=0, masked by iw=0)
__device__ const int PR[64]={0,0,0,0,0,0,0,0,0,0,1,1,1,1,1,1,1,1,1,2,2,2,2,2,2,2,2,3,3,3,3,3,3,3,4,4,4,4,4,4,5,5,5,5,5,6,6,6,6,7,7,7,8,8,9,0,0,0,0,0,0,0,0,0};
__device__ const int PC[64]={1,2,3,4,5,6,7,8,9,10,2,3,4,5,6,7,8,9,10,3,4,5,6,7,8,9,10,4,5,6,7,8,9,10,5,6,7,8,9,10,6,7,8,9,10,7,8,9,10,8,9,10,9,10,10,0,0,0,0,0,0,0,0,0};

// -------- prep: unified weight matrices Wu/lWu [64 rows][128 k] -------------
// rows 0-47: gate (st*6+g) E-part; rows 48-61: sb_W; rows 62-63: zero
__global__ void k_prep(const float* __restrict__ gW, const float* __restrict__ lgW,
                       const float* __restrict__ sbW, const float* __restrict__ lsbW,
                       float* __restrict__ Wu, float* __restrict__ lWu){
  int k = blockIdx.x*256 + threadIdx.x;
  if (k < 16384){
    int arr = k >> 13, rem = k & 8191;
    int o = rem >> 7, e = rem & 127;
    const float* g = arr ? lgW : gW;
    const float* s = arr ? lsbW : sbW;
    float v;
    if (o < 48) v = g[o*132 + 4 + e];
    else if (o < 62) v = s[(o-48)*128 + e];
    else v = 0.f;
    (arr ? lWu : Wu)[o*128 + e] = v;
  }
}

// -------- moe12: R3 moe1 + fused moe2, with in-kernel field generation ------
// Fields/lfields are regenerated in LDS from embT/linT gathers (coalesced
// 512B rows, tables L2-resident) + user/item projections (exact k_fields
// loop order -> bit-identical). No fieldsB/lfieldsB materialization.
// moe1 GEMM byte-identical to R3 (validated 125.7us structure).
// LDS layout identical to R9 (38.9 KB, 4 blk/CU).
__global__ __launch_bounds__(256) void k_moe12(
    const int* __restrict__ cat, const float* __restrict__ num,
    const float* __restrict__ embT, const float* __restrict__ linT,
    const float* __restrict__ uW, const float* __restrict__ ub,
    const float* __restrict__ iW, const float* __restrict__ ib,
    const float* __restrict__ ulW, const float* __restrict__ ulb,
    const float* __restrict__ ilW, const float* __restrict__ ilb,
    const float* __restrict__ scen_emb, const float* __restrict__ task_emb,
    const float* __restrict__ st_w, const float* __restrict__ interact_w,
    const float* __restrict__ sb_b,
    const float* __restrict__ shexp_W, const float* __restrict__ shexp_b,
    const float* __restrict__ spexp_W, const float* __restrict__ spexp_b,
    const float* __restrict__ gate_W, const float* __restrict__ gate_b,
    const float* __restrict__ Wu,
    const float* __restrict__ lsb_b,
    const float* __restrict__ lshexp_W, const float* __restrict__ lshexp_b,
    const float* __restrict__ lspexp_W, const float* __restrict__ lspexp_b,
    const float* __restrict__ lgate_W, const float* __restrict__ lgate_b,
    const float* __restrict__ ltower_W, const float* __restrict__ ltower_b,
    const float* __restrict__ lWu,
    float* __restrict__ w_g, float* __restrict__ lt1)
{
  __shared__ float sm[9692];
  float* s_fld = sm;           // 11 x 132
  float* s_stig= sm + 1452;    // 48
  float* s_Wu  = sm + 1500;    // 64 x 128 (GEMM phase)
  float* s_C   = sm + 1500;    // overlay: 64 x 69
  float* s_w   = sm + 5916;    // overlay: 8 x 220
  float* s_sh  = sm + 7676;    // overlay: 55 x 17
  // moe2 overlays (live only after moe1 completes):
  float* s_lf   = sm + 5916;   // 12 x 132
  float* m2_w   = sm + 7676;   // 8 x 44
  float* m2_sh  = sm + 8028;   // 11 x 17
  float* m2_C   = sm + 8611;   // 12 x 69
  float* m2_stig= sm + 9439;   // 48
  const int tid = threadIdx.x, b = blockIdx.x;
  const int* cb = cat + (size_t)b*10;
  const int scen = cb[0];
  const int e = tid & 127, half = tid >> 7;

  // ---- moe1: generate fields into s_fld (stride 132), stage Wu, stig ----
  if (half == 0){
    for (int j = 0; j < 9; j += 2){
      int id = cb[1+j] + j*1000;
      s_fld[j*132 + e] = embT[(size_t)id*128 + e];
    }
    float a0 = ub[e];
    for (int k = 0; k < 23; ++k) a0 += num[(size_t)b*63 + k] * uW[e*23 + k];
    s_fld[9*132 + e] = a0;
  } else {
    for (int j = 1; j < 9; j += 2){
      int id = cb[1+j] + j*1000;
      s_fld[j*132 + e] = embT[(size_t)id*128 + e];
    }
    float a2 = ib[e];
    for (int k = 0; k < 40; ++k) a2 += num[(size_t)b*63 + 23 + k] * iW[e*40 + k];
    s_fld[10*132 + e] = a2;
  }
  for (int idx = tid; idx < 2048; idx += 256)
    *(float4*)&s_Wu[idx*4] = *(const float4*)&Wu[idx*4];
  if (tid < 48){
    int t = (tid/6)%T_;
    float stw = st_w[t*S_ + scen];
    float acc = gate_b[tid];
    for (int i = 0; i < 4; ++i){
      float sti = scen_emb[scen*4+i] * task_emb[t*4+i] * stw;
      acc += sti * gate_W[tid*132 + i];
    }
    s_stig[tid] = acc;
  }
  __syncthreads();

  // ---- moe1 GEMM: rows {2rt,2rt+1} x cols [8ct,8ct+8), full K=128 ----
  {
    const int ct = tid >> 5;          // 0..7
    const int rt = tid & 31;          // 0..31
    const int r0 = rt*2;
    const int ra0 = PR[r0]*132,   ca0 = PC[r0]*132;
    const int ra1 = PR[r0+1]*132, ca1 = PC[r0+1]*132;
    float acc[2][8];
    for (int c = 0; c < 8; ++c){ acc[0][c] = 0.f; acc[1][c] = 0.f; }
    const float4* Wu4 = (const float4*)s_Wu;   // [row][k/4], row stride 32
    #pragma unroll 1
    for (int kk = 0; kk < 128; kk += 4){
      int wb = kk >> 2;
      float4 x0 = *(const float4*)&s_fld[ra0 + kk];
      float4 y0 = *(const float4*)&s_fld[ca0 + kk];
      float4 x1 = *(const float4*)&s_fld[ra1 + kk];
      float4 y1 = *(const float4*)&s_fld[ca1 + kk];
      float4 p0, p1;
      p0.x = x0.x*y0.x; p0.y = x0.y*y0.y; p0.z = x0.z*y0.z; p0.w = x0.w*y0.w;
      p1.x = x1.x*y1.x; p1.y = x1.y*y1.y; p1.z = x1.z*y1.z; p1.w = x1.w*y1.w;
      for (int h = 0; h < 2; ++h){
        float4 wv[4];
        for (int c = 0; c < 4; ++c) wv[c] = Wu4[(ct*8 + h*4 + c)*32 + wb];
        for (int c = 0; c < 4; ++c){
          acc[0][h*4+c] += p0.x*wv[c].x + p0.y*wv[c].y + p0.z*wv[c].z + p0.w*wv[c].w;
          acc[1][h*4+c] += p1.x*wv[c].x + p1.y*wv[c].y + p1.z*wv[c].z + p1.w*wv[c].w;
        }
      }
    }
    __syncthreads();   // all s_Wu reads complete before s_C overlays it
    for (int r = 0; r < 2; ++r){
      int row = r0 + r;
      float iw = (row < 55) ? interact_w[row] : 0.f;  // iw distributes out of K-sum
      for (int c = 0; c < 8; ++c){
        int col = ct*8 + c;
        float bias = (col < 48) ? s_stig[col] : ((col < 62) ? sb_b[col-48] : 0.f);
        s_C[row*69 + col] = acc[r][c]*iw + bias;
      }
    }
  }
  __syncthreads();
  // ---- moe1 shared experts ----
  for (int o = tid; o < 880; o += 256){
    int f = o >> 4, j = o & 15;
    float acc = shexp_b[j];
    const float* ein = &s_C[f*69 + 48];
    const float* wp = &shexp_W[j*14];
    for (int i = 0; i < 14; ++i) acc += ein[i] * wp[i];
    s_sh[f*17 + j] = acc;
  }
  __syncthreads();
  // ---- moe1 softmax + specific experts + mixture ----
  for (int task = tid; task < 440; task += 256){
    int st = task / 55, f = task % 55;
    float ein[14];
    for (int i = 0; i < 14; ++i) ein[i] = s_C[f*69 + 48 + i];
    float lg[6], mx = -1e30f;
    for (int g = 0; g < 6; ++g){ lg[g] = s_C[f*69 + st*6 + g]; mx = fmaxf(mx, lg[g]); }
    float sum = 0.f;
    for (int g = 0; g < 6; ++g){ lg[g] = __expf(lg[g]-mx); sum += lg[g]; }
    float inv = 1.f/sum;
    float wv[4] = {0,0,0,0};
    for (int g = 0; g < 4; ++g){
      float gg = lg[g]*inv;
      for (int m = 0; m < 4; ++m) wv[m] += gg * s_sh[f*17 + g*4 + m];
    }
    for (int ee = 0; ee < 2; ++ee){
      float gg = lg[4+ee]*inv;
      for (int m = 0; m < 4; ++m){
        float acc = spexp_b[(st*2+ee)*4+m];
        const float* wp = spexp_W + ((st*2+ee)*4+m)*14;
        for (int i = 0; i < 14; ++i) acc += ein[i] * wp[i];
        wv[m] += gg*acc;
      }
    }
    float4 o4; o4.x = wv[0]; o4.y = wv[1]; o4.z = wv[2]; o4.w = wv[3];
    *(float4*)&s_w[st*220 + f*4] = o4;
  }
  __syncthreads();
  // ---- moe1 w_g write (zero-padded cols 220..223) ----
  for (int idx = tid; idx < 448; idx += 256){
    int st = idx / 56, q = idx % 56;
    float4 v;
    if (q < 55) v = *(float4*)&s_w[st*220 + q*4];
    else { v.x=v.y=v.z=v.w=0.f; }
    *(float4*)&w_g[((size_t)b*8 + st)*224 + q*4] = v;
  }
  __syncthreads();   // s_w reads done before s_lf overlays it

  // ---- moe2: generate lfields into s_lf + stig2 ----
  if (half == 0){
    for (int j = 0; j < 9; j += 2){
      int id = cb[1+j] + j*1000;
      s_lf[j*132 + e] = linT[(size_t)id*128 + e];
    }
    float a1 = ulb[e];
    for (int k = 0; k < 23; ++k) a1 += num[(size_t)b*63 + k] * ulW[e*23 + k];
    s_lf[9*132 + e] = a1;
  } else {
    for (int j = 1; j < 9; j += 2){
      int id = cb[1+j] + j*1000;
      s_lf[j*132 + e] = linT[(size_t)id*128 + e];
    }
    float a3 = ilb[e];
    for (int k = 0; k < 40; ++k) a3 += num[(size_t)b*63 + 23 + k] * ilW[e*40 + k];
    s_lf[10*132 + e] = a3;
  }
  if (tid >= 224){ // zero row 11 (32 threads; disjoint from rows 0..10 writes)
    int q = tid - 224;
    float4 z = {0,0,0,0}; *(float4*)&s_lf[11*132 + q*4] = z;
  }
  if (tid < 48){
    int t = (tid/6)%T_;
    float stw = st_w[t*S_ + scen];
    float acc = lgate_b[tid];
    for (int i = 0; i < 4; ++i){
      float sti = scen_emb[scen*4+i] * task_emb[t*4+i] * stw;
      acc += sti * lgate_W[tid*132 + i];
    }
    m2_stig[tid] = acc;
  }
  __syncthreads();
  // ---- moe2 GEMM over 4 waves: C[12][64] = lf[12][128] * lWu^T ----
  {
    const int lane = tid & 63, wv_ = tid >> 6;
    const int pr = wv_*16 + (lane & 15);     // 0..63
    const int ks = lane >> 4;                // 4-way K split
    const int ft = pr & 1, ot = pr >> 1;     // 2 row-tiles x 32 col-tiles(2)
    const int r0 = ft*6, k0 = ks*32;
    float acc[6][2];
    for (int r = 0; r < 6; ++r){ acc[r][0] = 0.f; acc[r][1] = 0.f; }
    const float4* W4 = (const float4*)lWu;
    #pragma unroll 1
    for (int kc = 0; kc < 32; kc += 4){
      int kk = k0 + ((kc + ks*8) & 31);
      float4 w0 = W4[(ot*2+0)*32 + (kk>>2)];
      float4 w1 = W4[(ot*2+1)*32 + (kk>>2)];
      for (int r = 0; r < 6; ++r){
        float4 a = *(const float4*)&s_lf[(r0+r)*132 + kk];
        acc[r][0] += a.x*w0.x + a.y*w0.y + a.z*w0.z + a.w*w0.w;
        acc[r][1] += a.x*w1.x + a.y*w1.y + a.z*w1.z + a.w*w1.w;
      }
    }
    for (int r = 0; r < 6; ++r) for (int c = 0; c < 2; ++c){
      float v = acc[r][c];
      v += __shfl_xor(v, 16); v += __shfl_xor(v, 32);
      acc[r][c] = v;
    }
    if (ks == 0){
      for (int r = 0; r < 6; ++r) for (int c = 0; c < 2; ++c){
        int col = ot*2 + c, row = r0 + r;
        float bias = (col < 48) ? m2_stig[col] : ((col < 62) ? lsb_b[col-48] : 0.f);
        m2_C[row*69 + col] = acc[r][c] + bias;
      }
    }
  }
  __syncthreads();
  if (tid < 176){
    int f = tid >> 4, j = tid & 15;
    float acc = lshexp_b[j];
    const float* ein = &m2_C[f*69 + 48];
    for (int i = 0; i < 14; ++i) acc += ein[i] * lshexp_W[j*14+i];
    m2_sh[f*17 + j] = acc;
  }
  __syncthreads();
  if (tid < 88){
    int st = tid / 11, f = tid % 11;
    float ein[14];
    for (int i = 0; i < 14; ++i) ein[i] = m2_C[f*69 + 48 + i];
    float lg[6], mx = -1e30f;
    for (int g = 0; g < 6; ++g){ lg[g] = m2_C[f*69 + st*6 + g]; mx = fmaxf(mx, lg[g]); }
    float sum = 0.f;
    for (int g = 0; g < 6; ++g){ lg[g] = __expf(lg[g]-mx); sum += lg[g]; }
    float inv = 1.f/sum;
    float wv[4] = {0,0,0,0};
    for (int g = 0; g < 4; ++g){
      float gg = lg[g]*inv;
      for (int m = 0; m < 4; ++m) wv[m] += gg * m2_sh[f*17 + g*4 + m];
    }
    for (int ee = 0; ee < 2; ++ee){
      float gg = lg[4+ee]*inv;
      for (int m = 0; m < 4; ++m){
        float acc = lspexp_b[(st*2+ee)*4+m];
        const float* wp = lspexp_W + ((st*2+ee)*4+m)*14;
        for (int i = 0; i < 14; ++i) acc += ein[i] * wp[i];
        wv[m] += gg*acc;
      }
    }
    float4 o4; o4.x = wv[0]; o4.y = wv[1]; o4.z = wv[2]; o4.w = wv[3];
    *(float4*)&m2_w[st*44 + f*4] = o4;
  }
  __syncthreads();
  if (tid < 88){
    int st = tid / 11, oo = tid % 11;
    float acc = ltower_b[st*11+oo];
    const float* tw = ltower_W + (st*11+oo)*44;
    const float* wp = m2_w + st*44;
    for (int i = 0; i < 44; ++i) acc += wp[i] * tw[i];
    lt1[(size_t)(st*11+oo)*B_ + b] = acc;
  }
}

// -------- mask batch GEMM: m1[st*55+oo][b] = mW[st] x w^T + mb --------------
// grid: 512 blocks = 8 st x 64 b-tiles(64). LDS: s_mw[56*116] + s_wb[64*116]
__global__ __launch_bounds__(256) void k_mask(
    const float* __restrict__ w_g, const float* __restrict__ mask_W,
    const float* __restrict__ mask_b, float* __restrict__ m1)
{
  __shared__ float s_mw[56*116];
  __shared__ float s_wb[64*116];
  const int tid = threadIdx.x;
  const int st = blockIdx.x >> 6, bt = blockIdx.x & 63;
  const int b0 = bt*64;
  const int btl = tid & 15, ot = tid >> 4;   // ot<14 active
  float acc[4][4];
  for (int c = 0; c < 4; ++c) for (int j = 0; j < 4; ++j) acc[c][j] = 0.f;

  for (int kc = 0; kc < 2; ++kc){
    __syncthreads();
    for (int idx = tid; idx < 64*112; idx += 256){
      int r = idx / 112, k = idx % 112;
      s_wb[r*116 + k] = w_g[((size_t)(b0+r)*8 + st)*224 + kc*112 + k];
    }
    for (int idx = tid; idx < 56*112; idx += 256){
      int r = idx / 112, k = idx % 112;
      int kg = kc*112 + k;
      s_mw[r*116 + k] = (r < 55 && kg < 220) ? mask_W[((size_t)st*55 + r)*220 + kg] : 0.f;
    }
    __syncthreads();
    if (ot < 14){
      for (int k4 = 0; k4 < 112; k4 += 4){
        float4 a[4], wb[4];
        for (int c = 0; c < 4; ++c) a[c]  = *(float4*)&s_mw[(ot*4+c)*116 + k4];
        for (int j = 0; j < 4; ++j) wb[j] = *(float4*)&s_wb[(btl*4+j)*116 + k4];
        for (int c = 0; c < 4; ++c)
          for (int j = 0; j < 4; ++j)
            acc[c][j] += a[c].x*wb[j].x + a[c].y*wb[j].y + a[c].z*wb[j].z + a[c].w*wb[j].w;
      }
    }
  }
  if (ot < 14){
    for (int c = 0; c < 4; ++c){
      int row = ot*4 + c;
      if (row < 55){
        float mb = mask_b[st*55 + row];
        float4 v; v.x = acc[c][0]+mb; v.y = acc[c][1]+mb; v.z = acc[c][2]+mb; v.w = acc[c][3]+mb;
        *(float4*)&m1[(size_t)(st*55+row)*B_ + b0 + btl*4] = v;
      }
    }
  }
}

// -------- per-row batch stats (mean, rsqrt(var+eps)) ------------------------
__global__ __launch_bounds__(256) void k_stats(const float* __restrict__ x, float* __restrict__ stats){
  const int row = blockIdx.x, tid = threadIdx.x;
  const float* xr = x + (size_t)row*B_;
  float s = 0.f, s2 = 0.f;
  for (int i = tid; i < B_; i += 256){ float v = xr[i]; s += v; s2 += v*v; }
  for (int off = 32; off > 0; off >>= 1){ s += __shfl_down(s, off); s2 += __shfl_down(s2, off); }
  __shared__ float red[8];
  if ((tid & 63) == 0){ red[(tid>>6)*2] = s; red[(tid>>6)*2+1] = s2; }
  __syncthreads();
  if (tid == 0){
    float Ssum = red[0]+red[2]+red[4]+red[6], S2 = red[1]+red[3]+red[5]+red[7];
    float mean = Ssum*(1.f/B_), var = S2*(1.f/B_) - mean*mean;
    stats[row*2] = mean; stats[row*2+1] = rsqrtf(fmaxf(var, 0.f) + EPSf);
  }
}

// -------- fused stats for two row-batches (m1: n1 rows, then x2) ------------
__global__ __launch_bounds__(256) void k_stats2(const float* __restrict__ x1, const float* __restrict__ x2,
                                                int n1, float* __restrict__ st1o, float* __restrict__ st2o){
  const int row = blockIdx.x, tid = threadIdx.x;
  const float* xr; float* sto;
  if (row < n1){ xr = x1 + (size_t)row*B_; sto = st1o + row*2; }
  else { int r = row - n1; xr = x2 + (size_t)r*B_; sto = st2o + r*2; }
  float s = 0.f, s2 = 0.f;
  for (int i = tid; i < B_; i += 256){ float v = xr[i]; s += v; s2 += v*v; }
  for (int off = 32; off > 0; off >>= 1){ s += __shfl_down(s, off); s2 += __shfl_down(s2, off); }
  __shared__ float red[8];
  if ((tid & 63) == 0){ red[(tid>>6)*2] = s; red[(tid>>6)*2+1] = s2; }
  __syncthreads();
  if (tid == 0){
    float Ssum = red[0]+red[2]+red[4]+red[6], S2 = red[1]+red[3]+red[5]+red[7];
    float mean = Ssum*(1.f/B_), var = S2*(1.f/B_) - mean*mean;
    sto[0] = mean; sto[1] = rsqrtf(fmaxf(var, 0.f) + EPSf);
  }
}

// -------- interlinf+last1: bn/tanh/relu inter + softmax linf + W1 GEMM ------
// Regenerates fields/lfields in LDS (same math as old k_fields -> identical).
// h features kept in s_h[512]; 80 threads then compute h1 = W1 @ h + b1
// directly (same ascending-i accumulation order as old k_last1).
__global__ __launch_bounds__(128) void k_interlinf(
    const int* __restrict__ cat, const float* __restrict__ num,
    const float* __restrict__ embT, const float* __restrict__ linT,
    const float* __restrict__ uW, const float* __restrict__ ub,
    const float* __restrict__ iW, const float* __restrict__ ib,
    const float* __restrict__ ulW, const float* __restrict__ ulb,
    const float* __restrict__ ilW, const float* __restrict__ ilb,
    const float* __restrict__ m1, const float* __restrict__ stm,
    const float* __restrict__ lt1, const float* __restrict__ stl,
    const float* __restrict__ att_W, const float* __restrict__ interact_w,
    const float* __restrict__ bias_p,
    const float* __restrict__ W1, const float* __restrict__ b1,
    float* __restrict__ h1)
{
  __shared__ float s_fld[NF_*E_];
  __shared__ float s_lf[NF_*E_];
  __shared__ float s_co[110];
  __shared__ float s_lw[22];
  __shared__ float s_h[512];
  const int b = blockIdx.x, e = threadIdx.x;
  const int* cb = cat + (size_t)b*10;
  const int scen = cb[0];

  // regenerate fields/lfields (exact k_fields math/order)
  for (int j = 0; j < 9; ++j){
    int id = cb[1+j] + j*1000;
    s_fld[j*E_+e] = embT[(size_t)id*128 + e];
    s_lf[j*E_+e]  = linT[(size_t)id*128 + e];
  }
  {
    float a0 = ub[e], a1 = ulb[e];
    for (int k = 0; k < 23; ++k){ float x = num[(size_t)b*63 + k]; a0 += x*uW[e*23+k]; a1 += x*ulW[e*23+k]; }
    s_fld[9*E_+e] = a0; s_lf[9*E_+e] = a1;
    float a2 = ib[e], a3 = ilb[e];
    for (int k = 0; k < 40; ++k){ float x = num[(size_t)b*63 + 23 + k]; a2 += x*iW[e*40+k]; a3 += x*ilW[e*40+k]; }
    s_fld[10*E_+e] = a2; s_lf[10*E_+e] = a3;
  }
  if (e < 110){
    int t = e/55, f = e%55, row = (scen*T_+t)*55 + f;
    float v = (m1[(size_t)row*B_+b] - stm[row*2]) * stm[row*2+1];
    v = fmaxf(tanhf(v), 0.f);
    s_co[e] = v * att_W[(scen*T_+t)*55 + f];
  }
  if (e < 22){
    int t = e/11, f = e%11, row = (scen*T_+t)*11 + f;
    s_lw[e] = (lt1[(size_t)row*B_+b] - stl[row*2]) * stl[row*2+1];
  }
  __syncthreads();
  if (e < 2){
    int t = e; float mx = -1e30f;
    for (int f = 0; f < 11; ++f) mx = fmaxf(mx, s_lw[t*11+f]);
    float sum = 0.f;
    for (int f = 0; f < 11; ++f){ float x = __expf(s_lw[t*11+f]-mx); s_lw[t*11+f] = x; sum += x; }
    float inv = 1.f/sum;
    for (int f = 0; f < 11; ++f) s_lw[t*11+f] *= inv;
  }
  __syncthreads();
  // inter half -> s_h[t*256 + e]
  {
    float a0 = 0.f, a1 = 0.f;
    for (int f = 0; f < 55; ++f){
      float pe = s_fld[PR[f]*E_+e] * s_fld[PC[f]*E_+e] * interact_w[f];
      a0 += s_co[f]*pe; a1 += s_co[55+f]*pe;
    }
    s_h[0*256 + e] = a0;
    s_h[1*256 + e] = a1;
  }
  // linf half -> s_h[t*256 + 128 + e]
  for (int t = 0; t < 2; ++t){
    float acc = bias_p[(size_t)(t*S_+scen)*E_ + e];
    for (int f = 0; f < 11; ++f) acc += s_lw[t*11+f] * s_lf[f*E_+e];
    s_h[t*256 + 128 + e] = acc;
  }
  __syncthreads();
  // last1: h1[t*40+o][b] = b1 + dot(W1 row, s_h[t*256..])  (ascending i)
  if (e < 80){
    int t = e / 40, o = e % 40;
    float acc = b1[t*40 + o];
    const float4* wr = (const float4*)(W1 + (size_t)(t*40 + o)*256);
    const float4* hh = (const float4*)(s_h + t*256);
    for (int i = 0; i < 64; ++i){
      float4 w = wr[i], h = hh[i];
      acc += h.x*w.x; acc += h.y*w.y; acc += h.z*w.z; acc += h.w*w.w;
    }
    h1[(size_t)(t*40 + o)*B_ + b] = acc;
  }
}

// -------- final MLP tail ----------------------------------------------------
__global__ __launch_bounds__(256) void k_last2(const float* __restrict__ h1, const float* __restrict__ st1,
    const float* __restrict__ W2, const float* __restrict__ b2v, float* __restrict__ h2){
  int bz = blockIdx.x, t = bz/16, bc = bz%16, tid = threadIdx.x, b = bc*256 + tid;
  __shared__ float s_w2[1280];
  for (int k = tid; k < 1280; k += 256) s_w2[k] = W2[t*1280 + k];
  __syncthreads();
  float hv[40];
  for (int i = 0; i < 40; ++i){
    int row = t*40 + i;
    hv[i] = fmaxf((h1[(size_t)row*B_+b] - st1[row*2]) * st1[row*2+1], 0.f);
  }
  for (int o = 0; o < 32; ++o){
    float acc = b2v[t*32+o];
    for (int i = 0; i < 40; ++i) acc += hv[i] * s_w2[o*40+i];
    h2[(size_t)(t*32+o)*B_ + b] = acc;
  }
}

__global__ __launch_bounds__(256) void k_last3(const float* __restrict__ h2, const float* __restrict__ st2,
    const float* __restrict__ W3, const float* __restrict__ b3v, float* __restrict__ h3){
  int bz = blockIdx.x, t = bz/16, bc = bz%16, tid = threadIdx.x, b = bc*256 + tid;
  __shared__ float s_w3[256];
  if (tid < 256) s_w3[tid] = W3[t*256 + tid];
  __syncthreads();
  float hv[32];
  for (int i = 0; i < 32; ++i){
    int row = t*32 + i;
    hv[i] = fmaxf((h2[(size_t)row*B_+b] - st2[row*2]) * st2[row*2+1], 0.f);
  }
  for (int o = 0; o < 8; ++o){
    float acc = b3v[t*8+o];
    for (int i = 0; i < 32; ++i) acc += hv[i] * s_w3[o*32+i];
    h3[(size_t)(t*8+o)*B_ + b] = acc;
  }
}

__global__ __launch_bounds__(256) void k_out(const float* __restrict__ h3, const float* __restrict__ st3,
    const float* __restrict__ W4, const float* __restrict__ b4v, float* __restrict__ out){
  int idx = blockIdx.x*256 + threadIdx.x;
  int t = idx / B_, b = idx % B_;
  float acc = b4v[t];
  for (int i = 0; i < 8; ++i){
    int row = t*8 + i;
    float v = fmaxf((h3[(size_t)row*B_+b] - st3[row*2]) * st3[row*2+1], 0.f);
    acc += v * W4[t*8+i];
  }
  out[idx] = 1.f/(1.f + __expf(-acc));
}

extern "C" void kernel_launch(void* const* d_in, const int* in_sizes, int n_in,
                              void* d_out, int out_size, void* d_ws, size_t ws_size,
                              hipStream_t stream)
{
  const int*   cat      = (const int*)  d_in[0];
  const float* num      = (const float*)d_in[1];
  const float* embT     = (const float*)d_in[2];
  const float* linT     = (const float*)d_in[3];
  const float* uW = (const float*)d_in[4];  const float* ub = (const float*)d_in[5];
  const float* iW = (const float*)d_in[6];  const float* ib = (const float*)d_in[7];
  const float* ulW = (const float*)d_in[8]; const float* ulb = (const float*)d_in[9];
  const float* ilW = (const float*)d_in[10];const float* ilb = (const float*)d_in[11];
  const float* scen_emb = (const float*)d_in[12];
  const float* task_emb = (const float*)d_in[13];
  const float* st_w     = (const float*)d_in[14];
  const float* interact_w=(const float*)d_in[15];
  const float* sbW = (const float*)d_in[16]; const float* sbb = (const float*)d_in[17];
  const float* lsbW = (const float*)d_in[18];const float* lsbb = (const float*)d_in[19];
  const float* shW = (const float*)d_in[20]; const float* shb = (const float*)d_in[21];
  const float* spW = (const float*)d_in[22]; const float* spb = (const float*)d_in[23];
  const float* lshW = (const float*)d_in[24];const float* lshb = (const float*)d_in[25];
  const float* lspW = (const float*)d_in[26];const float* lspb = (const float*)d_in[27];
  const float* gW = (const float*)d_in[28];  const float* gb = (const float*)d_in[29];
  const float* lgW = (const float*)d_in[30]; const float* lgb = (const float*)d_in[31];
  const float* mW = (const float*)d_in[32];  const float* mb = (const float*)d_in[33];
  const float* attW = (const float*)d_in[34];
  const float* ltW = (const float*)d_in[35]; const float* ltb = (const float*)d_in[36];
  const float* biasP = (const float*)d_in[37];
  const float* W1 = (const float*)d_in[38];  const float* b1 = (const float*)d_in[39];
  const float* W2 = (const float*)d_in[40];  const float* b2v = (const float*)d_in[41];
  const float* W3 = (const float*)d_in[42];  const float* b3v = (const float*)d_in[43];
  const float* W4 = (const float*)d_in[44];  const float* b4v = (const float*)d_in[45];
  float* out = (float*)d_out;

  float* ws = (float*)d_ws;
  size_t o = 0;
  float* Wu   = ws + o; o += 8192;
  float* lWu  = ws + o; o += 8192;
  float* w_g  = ws + o; o += (size_t)B_*8*224;
  float* m1   = ws + o; o += (size_t)440*B_;
  float* stm  = ws + o; o += 880;
  float* lt1  = ws + o; o += (size_t)88*B_;
  float* stl  = ws + o; o += 176;
  float* h1   = ws + o; o += (size_t)80*B_;
  float* st1  = ws + o; o += 160;
  float* h2   = ws + o; o += (size_t)64*B_;
  float* st2  = ws + o; o += 128;
  float* h3   = ws + o; o += (size_t)16*B_;
  float* st3  = ws + o; o += 32;

  k_prep<<<64, 256, 0, stream>>>(gW, lgW, sbW, lsbW, Wu, lWu);
  k_moe12<<<B_, 256, 0, stream>>>(cat, num, embT, linT, uW, ub, iW, ib, ulW, ulb, ilW, ilb,
                                  scen_emb, task_emb, st_w, interact_w, sbb, shW, shb,
                                  spW, spb, gW, gb, Wu,
                                  lsbb, lshW, lshb, lspW, lspb, lgW, lgb, ltW, ltb,
                                  lWu, w_g, lt1);
  k_mask<<<512, 256, 0, stream>>>(w_g, mW, mb, m1);
  k_stats2<<<528, 256, 0, stream>>>(m1, lt1, 440, stm, stl);
  k_interlinf<<<B_, 128, 0, stream>>>(cat, num, embT, linT, uW, ub, iW, ib, ulW, ulb, ilW, ilb,
                                      m1, stm, lt1, stl, attW, interact_w, biasP,
                                      W1, b1, h1);
  k_stats<<<80, 256, 0, stream>>>(h1, st1);
  k_last2<<<32, 256, 0, stream>>>(h1, st1, W2, b2v, h2);
  k_stats<<<64, 256, 0, stream>>>(h2, st2);
  k_last3<<<32, 256, 0, stream>>>(h2, st2, W3, b3v, h3);
  k_stats<<<16, 256, 0, stream>>>(h3, st3);
  k_out<<<32, 256, 0, stream>>>(h3, st3, W4, b4v, out);
}

// Round 11
// 448.392 us; speedup vs baseline: 1.2148x; 1.0324x over previous
//
#include <hip/hip_runtime.h>
#include <hip/hip_bf16.h>

#define B_ 4096
#define T_ 2
#define S_ 4
#define E_ 128
#define NF_ 11
#define ID_ 55
#define MID_ 4
#define NG_ 6
#define SI_ 4
#define EPSf 1e-5f

typedef __attribute__((ext_vector_type(8))) short bf16x8;
typedef __attribute__((ext_vector_type(4))) float f32x4;

__device__ inline unsigned short f2bf(float f){
  unsigned int u = __float_as_uint(f);
  unsigned int r = (u + 0x7FFFu + ((u >> 16) & 1u)) >> 16;
  return (unsigned short)r;
}

// triu_indices(11, k=1) pairs, padded to 64 rows (rows 55..63: PR=PC=0, masked by iw=0)
__device__ const int PR[64]={0,0,0,0,0,0,0,0,0,0,1,1,1,1,1,1,1,1,1,2,2,2,2,2,2,2,2,3,3,3,3,3,3,3,4,4,4,4,4,4,5,5,5,5,5,6,6,6,6,7,7,7,8,8,9,0,0,0,0,0,0,0,0,0};
__device__ const int PC[64]={1,2,3,4,5,6,7,8,9,10,2,3,4,5,6,7,8,9,10,3,4,5,6,7,8,9,10,4,5,6,7,8,9,10,5,6,7,8,9,10,6,7,8,9,10,7,8,9,10,8,9,10,9,10,10,0,0,0,0,0,0,0,0,0};

// -------- prep: lWu fp32 [64][128] + Wub bf16 [64][136] ---------------------
// lWu rows 0-47: lgate E-part; 48-61: lsb_W; 62-63 zero.  Wub = same layout
// from gW/sbW, bf16, row stride 136 (16B-aligned rows, 4-bank shift/row).
__global__ void k_prep(const float* __restrict__ gW, const float* __restrict__ lgW,
                       const float* __restrict__ sbW, const float* __restrict__ lsbW,
                       float* __restrict__ Wu, float* __restrict__ lWu,
                       unsigned short* __restrict__ Wub){
  int k = blockIdx.x*256 + threadIdx.x;
  if (k < 16384){
    int arr = k >> 13, rem = k & 8191;
    int o = rem >> 7, e = rem & 127;
    const float* g = arr ? lgW : gW;
    const float* s = arr ? lsbW : sbW;
    float v;
    if (o < 48) v = g[o*132 + 4 + e];
    else if (o < 62) v = s[(o-48)*128 + e];
    else v = 0.f;
    (arr ? lWu : Wu)[o*128 + e] = v;
  }
  if (k < 64*136){
    int o = k / 136, e = k % 136;
    float v = 0.f;
    if (e < 128){
      if (o < 48) v = gW[o*132 + 4 + e];
      else if (o < 62) v = sbW[(o-48)*128 + e];
    }
    Wub[k] = f2bf(v);
  }
}

// -------- moe12: MFMA moe1 + fused moe2, in-kernel field generation ---------
// moe1 GEMM via v_mfma_f32_16x16x32_bf16: pe and Wu bf16-rounded (output check
// is bf16-tolerant); 4 waves x 4 row-tiles x 4 K-steps, acc 4 f32/lane/tile.
// Frag layout (m89-verified family): A row=lane&15,k=(lane>>4)*8+i; B col=
// lane&15; D col=lane&15,row=(lane>>4)*4+reg. Rows >=55 garbage, never read.
// LDS floats (9592 = 37.5KB, 4 blk/CU):
//   s_fld 0..1452 | s_stig 1452..1500 | s_peb 1500..5240 (55x136 bf16)
//   s_Wub 5240..9592 (64x136 bf16)
// overlays after GEMM barrier: s_C@1500 (64x69) | s_w@5916 | s_sh@7676
// moe2 overlays: s_lf@5916 | m2_w@7676 | m2_sh@8028 | m2_C@8611 | m2_stig@9439
__global__ __launch_bounds__(256) void k_moe12(
    const int* __restrict__ cat, const float* __restrict__ num,
    const float* __restrict__ embT, const float* __restrict__ linT,
    const float* __restrict__ uW, const float* __restrict__ ub,
    const float* __restrict__ iW, const float* __restrict__ ib,
    const float* __restrict__ ulW, const float* __restrict__ ulb,
    const float* __restrict__ ilW, const float* __restrict__ ilb,
    const float* __restrict__ scen_emb, const float* __restrict__ task_emb,
    const float* __restrict__ st_w, const float* __restrict__ interact_w,
    const float* __restrict__ sb_b,
    const float* __restrict__ shexp_W, const float* __restrict__ shexp_b,
    const float* __restrict__ spexp_W, const float* __restrict__ spexp_b,
    const float* __restrict__ gate_W, const float* __restrict__ gate_b,
    const unsigned short* __restrict__ Wub,
    const float* __restrict__ lsb_b,
    const float* __restrict__ lshexp_W, const float* __restrict__ lshexp_b,
    const float* __restrict__ lspexp_W, const float* __restrict__ lspexp_b,
    const float* __restrict__ lgate_W, const float* __restrict__ lgate_b,
    const float* __restrict__ ltower_W, const float* __restrict__ ltower_b,
    const float* __restrict__ lWu,
    float* __restrict__ w_g, float* __restrict__ lt1)
{
  __shared__ float sm[9592];
  float* s_fld = sm;           // 11 x 132
  float* s_stig= sm + 1452;    // 48
  unsigned short* s_peb = (unsigned short*)(sm + 1500);  // 55 x 136 bf16
  unsigned short* s_wub = (unsigned short*)(sm + 5240);  // 64 x 136 bf16
  float* s_C   = sm + 1500;    // overlay: 64 x 69
  float* s_w   = sm + 5916;    // overlay: 8 x 220
  float* s_sh  = sm + 7676;    // overlay: 55 x 17
  // moe2 overlays (live only after moe1 completes):
  float* s_lf   = sm + 5916;   // 12 x 132
  float* m2_w   = sm + 7676;   // 8 x 44
  float* m2_sh  = sm + 8028;   // 11 x 17
  float* m2_C   = sm + 8611;   // 12 x 69
  float* m2_stig= sm + 9439;   // 48
  const int tid = threadIdx.x, b = blockIdx.x;
  const int* cb = cat + (size_t)b*10;
  const int scen = cb[0];
  const int e = tid & 127, half = tid >> 7;

  // ---- stage: fields -> s_fld, Wub -> s_wub, stig ----
  if (half == 0){
    for (int j = 0; j < 9; j += 2){
      int id = cb[1+j] + j*1000;
      s_fld[j*132 + e] = embT[(size_t)id*128 + e];
    }
    float a0 = ub[e];
    for (int k = 0; k < 23; ++k) a0 += num[(size_t)b*63 + k] * uW[e*23 + k];
    s_fld[9*132 + e] = a0;
  } else {
    for (int j = 1; j < 9; j += 2){
      int id = cb[1+j] + j*1000;
      s_fld[j*132 + e] = embT[(size_t)id*128 + e];
    }
    float a2 = ib[e];
    for (int k = 0; k < 40; ++k) a2 += num[(size_t)b*63 + 23 + k] * iW[e*40 + k];
    s_fld[10*132 + e] = a2;
  }
  for (int idx = tid; idx < 1088; idx += 256)     // 4352 floats of bf16 Wub
    ((float4*)s_wub)[idx] = ((const float4*)Wub)[idx];
  if (tid < 48){
    int t = (tid/6)%T_;
    float stw = st_w[t*S_ + scen];
    float acc = gate_b[tid];
    for (int i = 0; i < 4; ++i){
      float sti = scen_emb[scen*4+i] * task_emb[t*4+i] * stw;
      acc += sti * gate_W[tid*132 + i];
    }
    s_stig[tid] = acc;
  }
  __syncthreads();

  // ---- build pe bf16 (iw applied in epilogue) ----
  for (int idx = tid; idx < 1760; idx += 256){    // 55 rows x 32 quads
    int row = idx >> 5, q = idx & 31;
    float4 x = *(const float4*)&s_fld[PR[row]*132 + q*4];
    float4 y = *(const float4*)&s_fld[PC[row]*132 + q*4];
    ushort4 o;
    o.x = f2bf(x.x*y.x); o.y = f2bf(x.y*y.y); o.z = f2bf(x.z*y.z); o.w = f2bf(x.w*y.w);
    *(ushort4*)&s_peb[row*136 + q*4] = o;
  }
  __syncthreads();

  // ---- MFMA GEMM: C[64][64] = pe x Wu^T, wave w owns cols [16w,16w+16) ----
  const int w = tid >> 6, lane = tid & 63;
  const int cg = lane >> 4, cc = lane & 15;
  f32x4 acc0 = {0.f,0.f,0.f,0.f}, acc1 = acc0, acc2 = acc0, acc3 = acc0;
  {
    const int kb = cg * 8;
    #pragma unroll
    for (int ks = 0; ks < 4; ++ks){
      int ko = ks*32 + kb;
      bf16x8 bfr = *(const bf16x8*)&s_wub[(w*16 + cc)*136 + ko];
      bf16x8 a0 = *(const bf16x8*)&s_peb[( 0 + cc)*136 + ko];
      bf16x8 a1 = *(const bf16x8*)&s_peb[(16 + cc)*136 + ko];
      bf16x8 a2 = *(const bf16x8*)&s_peb[(32 + cc)*136 + ko];
      bf16x8 a3 = *(const bf16x8*)&s_peb[(48 + cc)*136 + ko];
      acc0 = __builtin_amdgcn_mfma_f32_16x16x32_bf16(a0, bfr, acc0, 0, 0, 0);
      acc1 = __builtin_amdgcn_mfma_f32_16x16x32_bf16(a1, bfr, acc1, 0, 0, 0);
      acc2 = __builtin_amdgcn_mfma_f32_16x16x32_bf16(a2, bfr, acc2, 0, 0, 0);
      acc3 = __builtin_amdgcn_mfma_f32_16x16x32_bf16(a3, bfr, acc3, 0, 0, 0);
    }
  }
  __syncthreads();   // all peb/wub reads done before s_C overlays them
  // ---- epilogue: C = acc*iw + bias (rows<55 only; rows>=55 never read) ----
  {
    const int col = w*16 + cc;
    const float bias = (col < 48) ? s_stig[col] : ((col < 62) ? sb_b[col-48] : 0.f);
    #pragma unroll
    for (int r = 0; r < 4; ++r){
      int row0 = cg*4 + r;
      float v0 = (r==0)?acc0.x:((r==1)?acc0.y:((r==2)?acc0.z:acc0.w));
      float v1 = (r==0)?acc1.x:((r==1)?acc1.y:((r==2)?acc1.z:acc1.w));
      float v2 = (r==0)?acc2.x:((r==1)?acc2.y:((r==2)?acc2.z:acc2.w));
      float v3 = (r==0)?acc3.x:((r==1)?acc3.y:((r==2)?acc3.z:acc3.w));
      s_C[(row0     )*69 + col] = v0*interact_w[row0     ] + bias;
      s_C[(row0 + 16)*69 + col] = v1*interact_w[row0 + 16] + bias;
      s_C[(row0 + 32)*69 + col] = v2*interact_w[row0 + 32] + bias;
      if (row0 + 48 < 55)
        s_C[(row0 + 48)*69 + col] = v3*interact_w[row0 + 48] + bias;
    }
  }
  __syncthreads();
  // ---- moe1 shared experts ----
  for (int o = tid; o < 880; o += 256){
    int f = o >> 4, j = o & 15;
    float acc = shexp_b[j];
    const float* ein = &s_C[f*69 + 48];
    const float* wp = &shexp_W[j*14];
    for (int i = 0; i < 14; ++i) acc += ein[i] * wp[i];
    s_sh[f*17 + j] = acc;
  }
  __syncthreads();
  // ---- moe1 softmax + specific experts + mixture ----
  for (int task = tid; task < 440; task += 256){
    int st = task / 55, f = task % 55;
    float ein[14];
    for (int i = 0; i < 14; ++i) ein[i] = s_C[f*69 + 48 + i];
    float lg[6], mx = -1e30f;
    for (int g = 0; g < 6; ++g){ lg[g] = s_C[f*69 + st*6 + g]; mx = fmaxf(mx, lg[g]); }
    float sum = 0.f;
    for (int g = 0; g < 6; ++g){ lg[g] = __expf(lg[g]-mx); sum += lg[g]; }
    float inv = 1.f/sum;
    float wv[4] = {0,0,0,0};
    for (int g = 0; g < 4; ++g){
      float gg = lg[g]*inv;
      for (int m = 0; m < 4; ++m) wv[m] += gg * s_sh[f*17 + g*4 + m];
    }
    for (int ee = 0; ee < 2; ++ee){
      float gg = lg[4+ee]*inv;
      for (int m = 0; m < 4; ++m){
        float acc = spexp_b[(st*2+ee)*4+m];
        const float* wp = spexp_W + ((st*2+ee)*4+m)*14;
        for (int i = 0; i < 14; ++i) acc += ein[i] * wp[i];
        wv[m] += gg*acc;
      }
    }
    float4 o4; o4.x = wv[0]; o4.y = wv[1]; o4.z = wv[2]; o4.w = wv[3];
    *(float4*)&s_w[st*220 + f*4] = o4;
  }
  __syncthreads();
  // ---- moe1 w_g write (zero-padded cols 220..223) ----
  for (int idx = tid; idx < 448; idx += 256){
    int st = idx / 56, q = idx % 56;
    float4 v;
    if (q < 55) v = *(float4*)&s_w[st*220 + q*4];
    else { v.x=v.y=v.z=v.w=0.f; }
    *(float4*)&w_g[((size_t)b*8 + st)*224 + q*4] = v;
  }
  __syncthreads();   // s_w reads done before s_lf overlays it

  // ---- moe2: generate lfields into s_lf + stig2 ----
  if (half == 0){
    for (int j = 0; j < 9; j += 2){
      int id = cb[1+j] + j*1000;
      s_lf[j*132 + e] = linT[(size_t)id*128 + e];
    }
    float a1 = ulb[e];
    for (int k = 0; k < 23; ++k) a1 += num[(size_t)b*63 + k] * ulW[e*23 + k];
    s_lf[9*132 + e] = a1;
  } else {
    for (int j = 1; j < 9; j += 2){
      int id = cb[1+j] + j*1000;
      s_lf[j*132 + e] = linT[(size_t)id*128 + e];
    }
    float a3 = ilb[e];
    for (int k = 0; k < 40; ++k) a3 += num[(size_t)b*63 + 23 + k] * ilW[e*40 + k];
    s_lf[10*132 + e] = a3;
  }
  if (tid >= 224){ // zero row 11 (32 threads; disjoint from rows 0..10 writes)
    int q = tid - 224;
    float4 z = {0,0,0,0}; *(float4*)&s_lf[11*132 + q*4] = z;
  }
  if (tid < 48){
    int t = (tid/6)%T_;
    float stw = st_w[t*S_ + scen];
    float acc = lgate_b[tid];
    for (int i = 0; i < 4; ++i){
      float sti = scen_emb[scen*4+i] * task_emb[t*4+i] * stw;
      acc += sti * lgate_W[tid*132 + i];
    }
    m2_stig[tid] = acc;
  }
  __syncthreads();
  // ---- moe2 GEMM over 4 waves: C[12][64] = lf[12][128] * lWu^T ----
  {
    const int lane2 = tid & 63, wv_ = tid >> 6;
    const int pr = wv_*16 + (lane2 & 15);    // 0..63
    const int ks = lane2 >> 4;               // 4-way K split
    const int ft = pr & 1, ot = pr >> 1;     // 2 row-tiles x 32 col-tiles(2)
    const int r0 = ft*6, k0 = ks*32;
    float acc[6][2];
    for (int r = 0; r < 6; ++r){ acc[r][0] = 0.f; acc[r][1] = 0.f; }
    const float4* W4 = (const float4*)lWu;
    #pragma unroll 1
    for (int kc = 0; kc < 32; kc += 4){
      int kk = k0 + ((kc + ks*8) & 31);
      float4 w0 = W4[(ot*2+0)*32 + (kk>>2)];
      float4 w1 = W4[(ot*2+1)*32 + (kk>>2)];
      for (int r = 0; r < 6; ++r){
        float4 a = *(const float4*)&s_lf[(r0+r)*132 + kk];
        acc[r][0] += a.x*w0.x + a.y*w0.y + a.z*w0.z + a.w*w0.w;
        acc[r][1] += a.x*w1.x + a.y*w1.y + a.z*w1.z + a.w*w1.w;
      }
    }
    for (int r = 0; r < 6; ++r) for (int c = 0; c < 2; ++c){
      float v = acc[r][c];
      v += __shfl_xor(v, 16); v += __shfl_xor(v, 32);
      acc[r][c] = v;
    }
    if (ks == 0){
      for (int r = 0; r < 6; ++r) for (int c = 0; c < 2; ++c){
        int col = ot*2 + c, row = r0 + r;
        float bias = (col < 48) ? m2_stig[col] : ((col < 62) ? lsb_b[col-48] : 0.f);
        m2_C[row*69 + col] = acc[r][c] + bias;
      }
    }
  }
  __syncthreads();
  if (tid < 176){
    int f = tid >> 4, j = tid & 15;
    float acc = lshexp_b[j];
    const float* ein = &m2_C[f*69 + 48];
    for (int i = 0; i < 14; ++i) acc += ein[i] * lshexp_W[j*14+i];
    m2_sh[f*17 + j] = acc;
  }
  __syncthreads();
  if (tid < 88){
    int st = tid / 11, f = tid % 11;
    float ein[14];
    for (int i = 0; i < 14; ++i) ein[i] = m2_C[f*69 + 48 + i];
    float lg[6], mx = -1e30f;
    for (int g = 0; g < 6; ++g){ lg[g] = m2_C[f*69 + st*6 + g]; mx = fmaxf(mx, lg[g]); }
    float sum = 0.f;
    for (int g = 0; g < 6; ++g){ lg[g] = __expf(lg[g]-mx); sum += lg[g]; }
    float inv = 1.f/sum;
    float wv[4] = {0,0,0,0};
    for (int g = 0; g < 4; ++g){
      float gg = lg[g]*inv;
      for (int m = 0; m < 4; ++m) wv[m] += gg * m2_sh[f*17 + g*4 + m];
    }
    for (int ee = 0; ee < 2; ++ee){
      float gg = lg[4+ee]*inv;
      for (int m = 0; m < 4; ++m){
        float acc = lspexp_b[(st*2+ee)*4+m];
        const float* wp = lspexp_W + ((st*2+ee)*4+m)*14;
        for (int i = 0; i < 14; ++i) acc += ein[i] * wp[i];
        wv[m] += gg*acc;
      }
    }
    float4 o4; o4.x = wv[0]; o4.y = wv[1]; o4.z = wv[2]; o4.w = wv[3];
    *(float4*)&m2_w[st*44 + f*4] = o4;
  }
  __syncthreads();
  if (tid < 88){
    int st = tid / 11, oo = tid % 11;
    float acc = ltower_b[st*11+oo];
    const float* tw = ltower_W + (st*11+oo)*44;
    const float* wp = m2_w + st*44;
    for (int i = 0; i < 44; ++i) acc += wp[i] * tw[i];
    lt1[(size_t)(st*11+oo)*B_ + b] = acc;
  }
}

// -------- mask batch GEMM: m1[st*55+oo][b] = mW[st] x w^T + mb --------------
// grid: 512 blocks = 8 st x 64 b-tiles(64). LDS: s_mw[56*116] + s_wb[64*116]
__global__ __launch_bounds__(256) void k_mask(
    const float* __restrict__ w_g, const float* __restrict__ mask_W,
    const float* __restrict__ mask_b, float* __restrict__ m1)
{
  __shared__ float s_mw[56*116];
  __shared__ float s_wb[64*116];
  const int tid = threadIdx.x;
  const int st = blockIdx.x >> 6, bt = blockIdx.x & 63;
  const int b0 = bt*64;
  const int btl = tid & 15, ot = tid >> 4;   // ot<14 active
  float acc[4][4];
  for (int c = 0; c < 4; ++c) for (int j = 0; j < 4; ++j) acc[c][j] = 0.f;

  for (int kc = 0; kc < 2; ++kc){
    __syncthreads();
    for (int idx = tid; idx < 64*112; idx += 256){
      int r = idx / 112, k = idx % 112;
      s_wb[r*116 + k] = w_g[((size_t)(b0+r)*8 + st)*224 + kc*112 + k];
    }
    for (int idx = tid; idx < 56*112; idx += 256){
      int r = idx / 112, k = idx % 112;
      int kg = kc*112 + k;
      s_mw[r*116 + k] = (r < 55 && kg < 220) ? mask_W[((size_t)st*55 + r)*220 + kg] : 0.f;
    }
    __syncthreads();
    if (ot < 14){
      for (int k4 = 0; k4 < 112; k4 += 4){
        float4 a[4], wb[4];
        for (int c = 0; c < 4; ++c) a[c]  = *(float4*)&s_mw[(ot*4+c)*116 + k4];
        for (int j = 0; j < 4; ++j) wb[j] = *(float4*)&s_wb[(btl*4+j)*116 + k4];
        for (int c = 0; c < 4; ++c)
          for (int j = 0; j < 4; ++j)
            acc[c][j] += a[c].x*wb[j].x + a[c].y*wb[j].y + a[c].z*wb[j].z + a[c].w*wb[j].w;
      }
    }
  }
  if (ot < 14){
    for (int c = 0; c < 4; ++c){
      int row = ot*4 + c;
      if (row < 55){
        float mb = mask_b[st*55 + row];
        float4 v; v.x = acc[c][0]+mb; v.y = acc[c][1]+mb; v.z = acc[c][2]+mb; v.w = acc[c][3]+mb;
        *(float4*)&m1[(size_t)(st*55+row)*B_ + b0 + btl*4] = v;
      }
    }
  }
}

// -------- per-row batch stats (mean, rsqrt(var+eps)) ------------------------
__global__ __launch_bounds__(256) void k_stats(const float* __restrict__ x, float* __restrict__ stats){
  const int row = blockIdx.x, tid = threadIdx.x;
  const float* xr = x + (size_t)row*B_;
  float s = 0.f, s2 = 0.f;
  for (int i = tid; i < B_; i += 256){ float v = xr[i]; s += v; s2 += v*v; }
  for (int off = 32; off > 0; off >>= 1){ s += __shfl_down(s, off); s2 += __shfl_down(s2, off); }
  __shared__ float red[8];
  if ((tid & 63) == 0){ red[(tid>>6)*2] = s; red[(tid>>6)*2+1] = s2; }
  __syncthreads();
  if (tid == 0){
    float Ssum = red[0]+red[2]+red[4]+red[6], S2 = red[1]+red[3]+red[5]+red[7];
    float mean = Ssum*(1.f/B_), var = S2*(1.f/B_) - mean*mean;
    stats[row*2] = mean; stats[row*2+1] = rsqrtf(fmaxf(var, 0.f) + EPSf);
  }
}

// -------- fused stats for two row-batches (m1: n1 rows, then x2) ------------
__global__ __launch_bounds__(256) void k_stats2(const float* __restrict__ x1, const float* __restrict__ x2,
                                                int n1, float* __restrict__ st1o, float* __restrict__ st2o){
  const int row = blockIdx.x, tid = threadIdx.x;
  const float* xr; float* sto;
  if (row < n1){ xr = x1 + (size_t)row*B_; sto = st1o + row*2; }
  else { int r = row - n1; xr = x2 + (size_t)r*B_; sto = st2o + r*2; }
  float s = 0.f, s2 = 0.f;
  for (int i = tid; i < B_; i += 256){ float v = xr[i]; s += v; s2 += v*v; }
  for (int off = 32; off > 0; off >>= 1){ s += __shfl_down(s, off); s2 += __shfl_down(s2, off); }
  __shared__ float red[8];
  if ((tid & 63) == 0){ red[(tid>>6)*2] = s; red[(tid>>6)*2+1] = s2; }
  __syncthreads();
  if (tid == 0){
    float Ssum = red[0]+red[2]+red[4]+red[6], S2 = red[1]+red[3]+red[5]+red[7];
    float mean = Ssum*(1.f/B_), var = S2*(1.f/B_) - mean*mean;
    sto[0] = mean; sto[1] = rsqrtf(fmaxf(var, 0.f) + EPSf);
  }
}

// -------- interlinf+last1: bn/tanh/relu inter + softmax linf + W1 GEMM ------
__global__ __launch_bounds__(128) void k_interlinf(
    const int* __restrict__ cat, const float* __restrict__ num,
    const float* __restrict__ embT, const float* __restrict__ linT,
    const float* __restrict__ uW, const float* __restrict__ ub,
    const float* __restrict__ iW, const float* __restrict__ ib,
    const float* __restrict__ ulW, const float* __restrict__ ulb,
    const float* __restrict__ ilW, const float* __restrict__ ilb,
    const float* __restrict__ m1, const float* __restrict__ stm,
    const float* __restrict__ lt1, const float* __restrict__ stl,
    const float* __restrict__ att_W, const float* __restrict__ interact_w,
    const float* __restrict__ bias_p,
    const float* __restrict__ W1, const float* __restrict__ b1,
    float* __restrict__ h1)
{
  __shared__ float s_fld[NF_*E_];
  __shared__ float s_lf[NF_*E_];
  __shared__ float s_co[110];
  __shared__ float s_lw[22];
  __shared__ float s_h[512];
  const int b = blockIdx.x, e = threadIdx.x;
  const int* cb = cat + (size_t)b*10;
  const int scen = cb[0];

  for (int j = 0; j < 9; ++j){
    int id = cb[1+j] + j*1000;
    s_fld[j*E_+e] = embT[(size_t)id*128 + e];
    s_lf[j*E_+e]  = linT[(size_t)id*128 + e];
  }
  {
    float a0 = ub[e], a1 = ulb[e];
    for (int k = 0; k < 23; ++k){ float x = num[(size_t)b*63 + k]; a0 += x*uW[e*23+k]; a1 += x*ulW[e*23+k]; }
    s_fld[9*E_+e] = a0; s_lf[9*E_+e] = a1;
    float a2 = ib[e], a3 = ilb[e];
    for (int k = 0; k < 40; ++k){ float x = num[(size_t)b*63 + 23 + k]; a2 += x*iW[e*40+k]; a3 += x*ilW[e*40+k]; }
    s_fld[10*E_+e] = a2; s_lf[10*E_+e] = a3;
  }
  if (e < 110){
    int t = e/55, f = e%55, row = (scen*T_+t)*55 + f;
    float v = (m1[(size_t)row*B_+b] - stm[row*2]) * stm[row*2+1];
    v = fmaxf(tanhf(v), 0.f);
    s_co[e] = v * att_W[(scen*T_+t)*55 + f];
  }
  if (e < 22){
    int t = e/11, f = e%11, row = (scen*T_+t)*11 + f;
    s_lw[e] = (lt1[(size_t)row*B_+b] - stl[row*2]) * stl[row*2+1];
  }
  __syncthreads();
  if (e < 2){
    int t = e; float mx = -1e30f;
    for (int f = 0; f < 11; ++f) mx = fmaxf(mx, s_lw[t*11+f]);
    float sum = 0.f;
    for (int f = 0; f < 11; ++f){ float x = __expf(s_lw[t*11+f]-mx); s_lw[t*11+f] = x; sum += x; }
    float inv = 1.f/sum;
    for (int f = 0; f < 11; ++f) s_lw[t*11+f] *= inv;
  }
  __syncthreads();
  {
    float a0 = 0.f, a1 = 0.f;
    for (int f = 0; f < 55; ++f){
      float pe = s_fld[PR[f]*E_+e] * s_fld[PC[f]*E_+e] * interact_w[f];
      a0 += s_co[f]*pe; a1 += s_co[55+f]*pe;
    }
    s_h[0*256 + e] = a0;
    s_h[1*256 + e] = a1;
  }
  for (int t = 0; t < 2; ++t){
    float acc = bias_p[(size_t)(t*S_+scen)*E_ + e];
    for (int f = 0; f < 11; ++f) acc += s_lw[t*11+f] * s_lf[f*E_+e];
    s_h[t*256 + 128 + e] = acc;
  }
  __syncthreads();
  if (e < 80){
    int t = e / 40, o = e % 40;
    float acc = b1[t*40 + o];
    const float4* wr = (const float4*)(W1 + (size_t)(t*40 + o)*256);
    const float4* hh = (const float4*)(s_h + t*256);
    for (int i = 0; i < 64; ++i){
      float4 w = wr[i], h = hh[i];
      acc += h.x*w.x; acc += h.y*w.y; acc += h.z*w.z; acc += h.w*w.w;
    }
    h1[(size_t)(t*40 + o)*B_ + b] = acc;
  }
}

// -------- final MLP tail ----------------------------------------------------
__global__ __launch_bounds__(256) void k_last2(const float* __restrict__ h1, const float* __restrict__ st1,
    const float* __restrict__ W2, const float* __restrict__ b2v, float* __restrict__ h2){
  int bz = blockIdx.x, t = bz/16, bc = bz%16, tid = threadIdx.x, b = bc*256 + tid;
  __shared__ float s_w2[1280];
  for (int k = tid; k < 1280; k += 256) s_w2[k] = W2[t*1280 + k];
  __syncthreads();
  float hv[40];
  for (int i = 0; i < 40; ++i){
    int row = t*40 + i;
    hv[i] = fmaxf((h1[(size_t)row*B_+b] - st1[row*2]) * st1[row*2+1], 0.f);
  }
  for (int o = 0; o < 32; ++o){
    float acc = b2v[t*32+o];
    for (int i = 0; i < 40; ++i) acc += hv[i] * s_w2[o*40+i];
    h2[(size_t)(t*32+o)*B_ + b] = acc;
  }
}

__global__ __launch_bounds__(256) void k_last3(const float* __restrict__ h2, const float* __restrict__ st2,
    const float* __restrict__ W3, const float* __restrict__ b3v, float* __restrict__ h3){
  int bz = blockIdx.x, t = bz/16, bc = bz%16, tid = threadIdx.x, b = bc*256 + tid;
  __shared__ float s_w3[256];
  if (tid < 256) s_w3[tid] = W3[t*256 + tid];
  __syncthreads();
  float hv[32];
  for (int i = 0; i < 32; ++i){
    int row = t*32 + i;
    hv[i] = fmaxf((h2[(size_t)row*B_+b] - st2[row*2]) * st2[row*2+1], 0.f);
  }
  for (int o = 0; o < 8; ++o){
    float acc = b3v[t*8+o];
    for (int i = 0; i < 32; ++i) acc += hv[i] * s_w3[o*32+i];
    h3[(size_t)(t*8+o)*B_ + b] = acc;
  }
}

__global__ __launch_bounds__(256) void k_out(const float* __restrict__ h3, const float* __restrict__ st3,
    const float* __restrict__ W4, const float* __restrict__ b4v, float* __restrict__ out){
  int idx = blockIdx.x*256 + threadIdx.x;
  int t = idx / B_, b = idx % B_;
  float acc = b4v[t];
  for (int i = 0; i < 8; ++i){
    int row = t*8 + i;
    float v = fmaxf((h3[(size_t)row*B_+b] - st3[row*2]) * st3[row*2+1], 0.f);
    acc += v * W4[t*8+i];
  }
  out[idx] = 1.f/(1.f + __expf(-acc));
}

extern "C" void kernel_launch(void* const* d_in, const int* in_sizes, int n_in,
                              void* d_out, int out_size, void* d_ws, size_t ws_size,
                              hipStream_t stream)
{
  const int*   cat      = (const int*)  d_in[0];
  const float* num      = (const float*)d_in[1];
  const float* embT     = (const float*)d_in[2];
  const float* linT     = (const float*)d_in[3];
  const float* uW = (const float*)d_in[4];  const float* ub = (const float*)d_in[5];
  const float* iW = (const float*)d_in[6];  const float* ib = (const float*)d_in[7];
  const float* ulW = (const float*)d_in[8]; const float* ulb = (const float*)d_in[9];
  const float* ilW = (const float*)d_in[10];const float* ilb = (const float*)d_in[11];
  const float* scen_emb = (const float*)d_in[12];
  const float* task_emb = (const float*)d_in[13];
  const float* st_w     = (const float*)d_in[14];
  const float* interact_w=(const float*)d_in[15];
  const float* sbW = (const float*)d_in[16]; const float* sbb = (const float*)d_in[17];
  const float* lsbW = (const float*)d_in[18];const float* lsbb = (const float*)d_in[19];
  const float* shW = (const float*)d_in[20]; const float* shb = (const float*)d_in[21];
  const float* spW = (const float*)d_in[22]; const float* spb = (const float*)d_in[23];
  const float* lshW = (const float*)d_in[24];const float* lshb = (const float*)d_in[25];
  const float* lspW = (const float*)d_in[26];const float* lspb = (const float*)d_in[27];
  const float* gW = (const float*)d_in[28];  const float* gb = (const float*)d_in[29];
  const float* lgW = (const float*)d_in[30]; const float* lgb = (const float*)d_in[31];
  const float* mW = (const float*)d_in[32];  const float* mb = (const float*)d_in[33];
  const float* attW = (const float*)d_in[34];
  const float* ltW = (const float*)d_in[35]; const float* ltb = (const float*)d_in[36];
  const float* biasP = (const float*)d_in[37];
  const float* W1 = (const float*)d_in[38];  const float* b1 = (const float*)d_in[39];
  const float* W2 = (const float*)d_in[40];  const float* b2v = (const float*)d_in[41];
  const float* W3 = (const float*)d_in[42];  const float* b3v = (const float*)d_in[43];
  const float* W4 = (const float*)d_in[44];  const float* b4v = (const float*)d_in[45];
  float* out = (float*)d_out;

  float* ws = (float*)d_ws;
  size_t o = 0;
  float* Wu   = ws + o; o += 8192;
  float* lWu  = ws + o; o += 8192;
  float* Wub  = ws + o; o += 4352;   // bf16 64x136 as ushorts
  float* w_g  = ws + o; o += (size_t)B_*8*224;
  float* m1   = ws + o; o += (size_t)440*B_;
  float* stm  = ws + o; o += 880;
  float* lt1  = ws + o; o += (size_t)88*B_;
  float* stl  = ws + o; o += 176;
  float* h1   = ws + o; o += (size_t)80*B_;
  float* st1  = ws + o; o += 160;
  float* h2   = ws + o; o += (size_t)64*B_;
  float* st2  = ws + o; o += 128;
  float* h3   = ws + o; o += (size_t)16*B_;
  float* st3  = ws + o; o += 32;

  k_prep<<<64, 256, 0, stream>>>(gW, lgW, sbW, lsbW, Wu, lWu, (unsigned short*)Wub);
  k_moe12<<<B_, 256, 0, stream>>>(cat, num, embT, linT, uW, ub, iW, ib, ulW, ulb, ilW, ilb,
                                  scen_emb, task_emb, st_w, interact_w, sbb, shW, shb,
                                  spW, spb, gW, gb, (const unsigned short*)Wub,
                                  lsbb, lshW, lshb, lspW, lspb, lgW, lgb, ltW, ltb,
                                  lWu, w_g, lt1);
  k_mask<<<512, 256, 0, stream>>>(w_g, mW, mb, m1);
  k_stats2<<<528, 256, 0, stream>>>(m1, lt1, 440, stm, stl);
  k_interlinf<<<B_, 128, 0, stream>>>(cat, num, embT, linT, uW, ub, iW, ib, ulW, ulb, ilW, ilb,
                                      m1, stm, lt1, stl, attW, interact_w, biasP,
                                      W1, b1, h1);
  k_stats<<<80, 256, 0, stream>>>(h1, st1);
  k_last2<<<32, 256, 0, stream>>>(h1, st1, W2, b2v, h2);
  k_stats<<<64, 256, 0, stream>>>(h2, st2);
  k_last3<<<32, 256, 0, stream>>>(h2, st2, W3, b3v, h3);
  k_stats<<<16, 256, 0, stream>>>(h3, st3);
  k_out<<<32, 256, 0, stream>>>(h3, st3, W4, b4v, out);
}

// Round 12
// 402.721 us; speedup vs baseline: 1.3526x; 1.1134x over previous
//
#include <hip/hip_runtime.h>
#include <hip/hip_bf16.h>

#define B_ 4096
#define T_ 2
#define S_ 4
#define E_ 128
#define NF_ 11
#define ID_ 55
#define MID_ 4
#define NG_ 6
#define SI_ 4
#define EPSf 1e-5f

typedef __attribute__((ext_vector_type(8))) short bf16x8;
typedef __attribute__((ext_vector_type(4))) float f32x4;

__device__ inline unsigned short f2bf(float f){
  unsigned int u = __float_as_uint(f);
  unsigned int r = (u + 0x7FFFu + ((u >> 16) & 1u)) >> 16;
  return (unsigned short)r;
}

// triu_indices(11, k=1) pairs, padded to 64 rows (rows 55..63: PR=PC=0, masked by iw=0)
__device__ const int PR[64]={0,0,0,0,0,0,0,0,0,0,1,1,1,1,1,1,1,1,1,2,2,2,2,2,2,2,2,3,3,3,3,3,3,3,4,4,4,4,4,4,5,5,5,5,5,6,6,6,6,7,7,7,8,8,9,0,0,0,0,0,0,0,0,0};
__device__ const int PC[64]={1,2,3,4,5,6,7,8,9,10,2,3,4,5,6,7,8,9,10,3,4,5,6,7,8,9,10,4,5,6,7,8,9,10,5,6,7,8,9,10,6,7,8,9,10,7,8,9,10,8,9,10,9,10,10,0,0,0,0,0,0,0,0,0};

// -------- prep: Wub/lWub bf16 [64 rows][136] --------------------------------
// rows 0-47: gate (st*6+g) E-part; rows 48-61: sb_W; rest zero. Row stride 136
// (16B-aligned rows). Read as wave-fragments directly from global (L1-resident).
__global__ void k_prep(const float* __restrict__ gW, const float* __restrict__ lgW,
                       const float* __restrict__ sbW, const float* __restrict__ lsbW,
                       unsigned short* __restrict__ Wub, unsigned short* __restrict__ lWub){
  int k = blockIdx.x*256 + threadIdx.x;
  if (k < 8704){
    int o = k / 136, e = k % 136;
    float v = 0.f, lv = 0.f;
    if (e < 128){
      if (o < 48){ v = gW[o*132 + 4 + e]; lv = lgW[o*132 + 4 + e]; }
      else if (o < 62){ v = sbW[(o-48)*128 + e]; lv = lsbW[(o-48)*128 + e]; }
    }
    Wub[k] = f2bf(v);
    lWub[k] = f2bf(lv);
  }
}

// -------- moe12: MFMA moe1 + MFMA moe2, in-kernel field generation ----------
// Both GEMMs via v_mfma_f32_16x16x32_bf16 (frag layout m89-verified: A row=
// lane&15, k=(lane>>4)*8+i; B col=lane&15; D col=lane&15, row=(lane>>4)*4+r).
// B-fragments read directly from global Wub/lWub (4 indep 16B loads/lane).
// LDS floats (6595 = 25.8 KB -> 5 blk/CU w/ ~88 VGPR):
//   s_fld @0 (1452) | s_stig @1452 (48) | s_peb @1500 (55x136 bf16 = 3740 fl)
// overlay after MFMA: s_C @1500 (64x65=4160) | s_sh @5660 (935)
// moe2 overlays (post-mixture): s_lfb @1500 (16x136 bf16 = 1088 fl) |
//   m2_C @2588 (12x65=780) | m2_sh @3368 (187) | m2_stig @3555 (48) | m2_w @3603 (352)
__global__ __launch_bounds__(256) void k_moe12(
    const int* __restrict__ cat, const float* __restrict__ num,
    const float* __restrict__ embT, const float* __restrict__ linT,
    const float* __restrict__ uW, const float* __restrict__ ub,
    const float* __restrict__ iW, const float* __restrict__ ib,
    const float* __restrict__ ulW, const float* __restrict__ ulb,
    const float* __restrict__ ilW, const float* __restrict__ ilb,
    const float* __restrict__ scen_emb, const float* __restrict__ task_emb,
    const float* __restrict__ st_w, const float* __restrict__ interact_w,
    const float* __restrict__ sb_b,
    const float* __restrict__ shexp_W, const float* __restrict__ shexp_b,
    const float* __restrict__ spexp_W, const float* __restrict__ spexp_b,
    const float* __restrict__ gate_W, const float* __restrict__ gate_b,
    const unsigned short* __restrict__ Wub,
    const float* __restrict__ lsb_b,
    const float* __restrict__ lshexp_W, const float* __restrict__ lshexp_b,
    const float* __restrict__ lspexp_W, const float* __restrict__ lspexp_b,
    const float* __restrict__ lgate_W, const float* __restrict__ lgate_b,
    const float* __restrict__ ltower_W, const float* __restrict__ ltower_b,
    const unsigned short* __restrict__ lWub,
    float* __restrict__ w_g, float* __restrict__ lt1)
{
  __shared__ float sm[6595];
  float* s_fld = sm;           // 11 x 132
  float* s_stig= sm + 1452;    // 48
  unsigned short* s_peb = (unsigned short*)(sm + 1500);  // 55 x 136 bf16
  float* s_C   = sm + 1500;    // overlay: 64 x 65
  float* s_sh  = sm + 5660;    // overlay: 55 x 17
  // moe2 overlays (live only after mixture completes):
  unsigned short* s_lfb = (unsigned short*)(sm + 1500); // 16 x 136 bf16
  float* m2_C   = sm + 2588;   // 12 x 65
  float* m2_sh  = sm + 3368;   // 11 x 17
  float* m2_stig= sm + 3555;   // 48
  float* m2_w   = sm + 3603;   // 8 x 44
  const int tid = threadIdx.x, b = blockIdx.x;
  const int* cb = cat + (size_t)b*10;
  const int scen = cb[0];
  const int e = tid & 127, half = tid >> 7;
  const int w = tid >> 6, lane = tid & 63;
  const int cg = lane >> 4, cc = lane & 15;

  // ---- stage: fields -> s_fld, stig ----
  if (half == 0){
    for (int j = 0; j < 9; j += 2){
      int id = cb[1+j] + j*1000;
      s_fld[j*132 + e] = embT[(size_t)id*128 + e];
    }
    float a0 = ub[e];
    for (int k = 0; k < 23; ++k) a0 += num[(size_t)b*63 + k] * uW[e*23 + k];
    s_fld[9*132 + e] = a0;
  } else {
    for (int j = 1; j < 9; j += 2){
      int id = cb[1+j] + j*1000;
      s_fld[j*132 + e] = embT[(size_t)id*128 + e];
    }
    float a2 = ib[e];
    for (int k = 0; k < 40; ++k) a2 += num[(size_t)b*63 + 23 + k] * iW[e*40 + k];
    s_fld[10*132 + e] = a2;
  }
  if (tid < 48){
    int t = (tid/6)%T_;
    float stw = st_w[t*S_ + scen];
    float acc = gate_b[tid];
    for (int i = 0; i < 4; ++i){
      float sti = scen_emb[scen*4+i] * task_emb[t*4+i] * stw;
      acc += sti * gate_W[tid*132 + i];
    }
    s_stig[tid] = acc;
  }
  __syncthreads();

  // ---- build pe bf16 (iw applied in epilogue) ----
  for (int idx = tid; idx < 1760; idx += 256){    // 55 rows x 32 quads
    int row = idx >> 5, q = idx & 31;
    float4 x = *(const float4*)&s_fld[PR[row]*132 + q*4];
    float4 y = *(const float4*)&s_fld[PC[row]*132 + q*4];
    ushort4 o;
    o.x = f2bf(x.x*y.x); o.y = f2bf(x.y*y.y); o.z = f2bf(x.z*y.z); o.w = f2bf(x.w*y.w);
    *(ushort4*)&s_peb[row*136 + q*4] = o;
  }
  __syncthreads();

  // ---- MFMA GEMM: C[64][64] = pe x Wu^T, wave w owns cols [16w,16w+16) ----
  f32x4 acc0 = {0.f,0.f,0.f,0.f}, acc1 = acc0, acc2 = acc0, acc3 = acc0;
  {
    const int kb = cg * 8;
    #pragma unroll
    for (int ks = 0; ks < 4; ++ks){
      int ko = ks*32 + kb;
      bf16x8 bfr = *(const bf16x8*)&Wub[(w*16 + cc)*136 + ko];  // global, L1
      bf16x8 a0 = *(const bf16x8*)&s_peb[( 0 + cc)*136 + ko];
      bf16x8 a1 = *(const bf16x8*)&s_peb[(16 + cc)*136 + ko];
      bf16x8 a2 = *(const bf16x8*)&s_peb[(32 + cc)*136 + ko];
      bf16x8 a3 = *(const bf16x8*)&s_peb[(48 + cc)*136 + ko];
      acc0 = __builtin_amdgcn_mfma_f32_16x16x32_bf16(a0, bfr, acc0, 0, 0, 0);
      acc1 = __builtin_amdgcn_mfma_f32_16x16x32_bf16(a1, bfr, acc1, 0, 0, 0);
      acc2 = __builtin_amdgcn_mfma_f32_16x16x32_bf16(a2, bfr, acc2, 0, 0, 0);
      acc3 = __builtin_amdgcn_mfma_f32_16x16x32_bf16(a3, bfr, acc3, 0, 0, 0);
    }
  }
  __syncthreads();   // all peb reads done before s_C overlays
  // ---- epilogue: C = acc*iw + bias (rows<55 only; rows>=55 never read) ----
  {
    const int col = w*16 + cc;
    const float bias = (col < 48) ? s_stig[col] : ((col < 62) ? sb_b[col-48] : 0.f);
    #pragma unroll
    for (int r = 0; r < 4; ++r){
      int row0 = cg*4 + r;
      float v0 = (r==0)?acc0.x:((r==1)?acc0.y:((r==2)?acc0.z:acc0.w));
      float v1 = (r==0)?acc1.x:((r==1)?acc1.y:((r==2)?acc1.z:acc1.w));
      float v2 = (r==0)?acc2.x:((r==1)?acc2.y:((r==2)?acc2.z:acc2.w));
      float v3 = (r==0)?acc3.x:((r==1)?acc3.y:((r==2)?acc3.z:acc3.w));
      s_C[(row0     )*65 + col] = v0*interact_w[row0     ] + bias;
      s_C[(row0 + 16)*65 + col] = v1*interact_w[row0 + 16] + bias;
      s_C[(row0 + 32)*65 + col] = v2*interact_w[row0 + 32] + bias;
      if (row0 + 48 < 55)
        s_C[(row0 + 48)*65 + col] = v3*interact_w[row0 + 48] + bias;
    }
  }
  __syncthreads();
  // ---- moe1 shared experts ----
  for (int o = tid; o < 880; o += 256){
    int f = o >> 4, j = o & 15;
    float acc = shexp_b[j];
    const float* ein = &s_C[f*65 + 48];
    const float* wp = &shexp_W[j*14];
    for (int i = 0; i < 14; ++i) acc += ein[i] * wp[i];
    s_sh[f*17 + j] = acc;
  }
  __syncthreads();
  // ---- moe1 softmax + specific experts + mixture (direct w_g write) ----
  for (int task = tid; task < 440; task += 256){
    int st = task / 55, f = task % 55;
    float ein[14];
    for (int i = 0; i < 14; ++i) ein[i] = s_C[f*65 + 48 + i];
    float lg[6], mx = -1e30f;
    for (int g = 0; g < 6; ++g){ lg[g] = s_C[f*65 + st*6 + g]; mx = fmaxf(mx, lg[g]); }
    float sum = 0.f;
    for (int g = 0; g < 6; ++g){ lg[g] = __expf(lg[g]-mx); sum += lg[g]; }
    float inv = 1.f/sum;
    float wv[4] = {0,0,0,0};
    for (int g = 0; g < 4; ++g){
      float gg = lg[g]*inv;
      for (int m = 0; m < 4; ++m) wv[m] += gg * s_sh[f*17 + g*4 + m];
    }
    for (int ee = 0; ee < 2; ++ee){
      float gg = lg[4+ee]*inv;
      for (int m = 0; m < 4; ++m){
        float acc = spexp_b[(st*2+ee)*4+m];
        const float* wp = spexp_W + ((st*2+ee)*4+m)*14;
        for (int i = 0; i < 14; ++i) acc += ein[i] * wp[i];
        wv[m] += gg*acc;
      }
    }
    float4 o4; o4.x = wv[0]; o4.y = wv[1]; o4.z = wv[2]; o4.w = wv[3];
    *(float4*)&w_g[((size_t)b*8 + st)*224 + f*4] = o4;
  }
  if (tid < 8){   // zero-pad cols 220..223 per st
    float4 z = {0,0,0,0};
    *(float4*)&w_g[((size_t)b*8 + tid)*224 + 220] = z;
  }
  __syncthreads();   // s_C/s_sh reads done before s_lfb overlays

  // ---- moe2: gather lfields as bf16 + stig2 ----
  if (half == 0){
    for (int j = 0; j < 9; j += 2){
      int id = cb[1+j] + j*1000;
      s_lfb[j*136 + e] = f2bf(linT[(size_t)id*128 + e]);
    }
    float a1 = ulb[e];
    for (int k = 0; k < 23; ++k) a1 += num[(size_t)b*63 + k] * ulW[e*23 + k];
    s_lfb[9*136 + e] = f2bf(a1);
  } else {
    for (int j = 1; j < 9; j += 2){
      int id = cb[1+j] + j*1000;
      s_lfb[j*136 + e] = f2bf(linT[(size_t)id*128 + e]);
    }
    float a3 = ilb[e];
    for (int k = 0; k < 40; ++k) a3 += num[(size_t)b*63 + 23 + k] * ilW[e*40 + k];
    s_lfb[10*136 + e] = f2bf(a3);
  }
  if (tid < 48){
    int t = (tid/6)%T_;
    float stw = st_w[t*S_ + scen];
    float acc = lgate_b[tid];
    for (int i = 0; i < 4; ++i){
      float sti = scen_emb[scen*4+i] * task_emb[t*4+i] * stw;
      acc += sti * lgate_W[tid*132 + i];
    }
    m2_stig[tid] = acc;
  }
  __syncthreads();
  // ---- moe2 MFMA: C[12][64] = lf x lWu^T, wave w -> cols [16w,16w+16) ----
  // A rows 11..15 are stale LDS (garbage) -> D rows 11..15 garbage, never stored.
  {
    f32x4 macc = {0.f,0.f,0.f,0.f};
    const int kb = cg * 8;
    #pragma unroll
    for (int ks = 0; ks < 4; ++ks){
      int ko = ks*32 + kb;
      bf16x8 bfr = *(const bf16x8*)&lWub[(w*16 + cc)*136 + ko];  // global, L1
      bf16x8 av  = *(const bf16x8*)&s_lfb[cc*136 + ko];
      macc = __builtin_amdgcn_mfma_f32_16x16x32_bf16(av, bfr, macc, 0, 0, 0);
    }
    const int col = w*16 + cc;
    const float bias = (col < 48) ? m2_stig[col] : ((col < 62) ? lsb_b[col-48] : 0.f);
    #pragma unroll
    for (int r = 0; r < 4; ++r){
      int row = cg*4 + r;
      if (row < 11){
        float v = (r==0)?macc.x:((r==1)?macc.y:((r==2)?macc.z:macc.w));
        m2_C[row*65 + col] = v + bias;
      }
    }
  }
  __syncthreads();
  if (tid < 176){
    int f = tid >> 4, j = tid & 15;
    float acc = lshexp_b[j];
    const float* ein = &m2_C[f*65 + 48];
    for (int i = 0; i < 14; ++i) acc += ein[i] * lshexp_W[j*14+i];
    m2_sh[f*17 + j] = acc;
  }
  __syncthreads();
  if (tid < 88){
    int st = tid / 11, f = tid % 11;
    float ein[14];
    for (int i = 0; i < 14; ++i) ein[i] = m2_C[f*65 + 48 + i];
    float lg[6], mx = -1e30f;
    for (int g = 0; g < 6; ++g){ lg[g] = m2_C[f*65 + st*6 + g]; mx = fmaxf(mx, lg[g]); }
    float sum = 0.f;
    for (int g = 0; g < 6; ++g){ lg[g] = __expf(lg[g]-mx); sum += lg[g]; }
    float inv = 1.f/sum;
    float wv[4] = {0,0,0,0};
    for (int g = 0; g < 4; ++g){
      float gg = lg[g]*inv;
      for (int m = 0; m < 4; ++m) wv[m] += gg * m2_sh[f*17 + g*4 + m];
    }
    for (int ee = 0; ee < 2; ++ee){
      float gg = lg[4+ee]*inv;
      for (int m = 0; m < 4; ++m){
        float acc = lspexp_b[(st*2+ee)*4+m];
        const float* wp = lspexp_W + ((st*2+ee)*4+m)*14;
        for (int i = 0; i < 14; ++i) acc += ein[i] * wp[i];
        wv[m] += gg*acc;
      }
    }
    float4 o4; o4.x = wv[0]; o4.y = wv[1]; o4.z = wv[2]; o4.w = wv[3];
    *(float4*)&m2_w[st*44 + f*4] = o4;
  }
  __syncthreads();
  if (tid < 88){
    int st = tid / 11, oo = tid % 11;
    float acc = ltower_b[st*11+oo];
    const float* tw = ltower_W + (st*11+oo)*44;
    const float* wp = m2_w + st*44;
    for (int i = 0; i < 44; ++i) acc += wp[i] * tw[i];
    lt1[(size_t)(st*11+oo)*B_ + b] = acc;
  }
}

// -------- mask batch GEMM: m1[st*55+oo][b] = mW[st] x w^T + mb --------------
// grid: 512 blocks = 8 st x 64 b-tiles(64). LDS: s_mw[56*116] + s_wb[64*116]
__global__ __launch_bounds__(256) void k_mask(
    const float* __restrict__ w_g, const float* __restrict__ mask_W,
    const float* __restrict__ mask_b, float* __restrict__ m1)
{
  __shared__ float s_mw[56*116];
  __shared__ float s_wb[64*116];
  const int tid = threadIdx.x;
  const int st = blockIdx.x >> 6, bt = blockIdx.x & 63;
  const int b0 = bt*64;
  const int btl = tid & 15, ot = tid >> 4;   // ot<14 active
  float acc[4][4];
  for (int c = 0; c < 4; ++c) for (int j = 0; j < 4; ++j) acc[c][j] = 0.f;

  for (int kc = 0; kc < 2; ++kc){
    __syncthreads();
    for (int idx = tid; idx < 64*112; idx += 256){
      int r = idx / 112, k = idx % 112;
      s_wb[r*116 + k] = w_g[((size_t)(b0+r)*8 + st)*224 + kc*112 + k];
    }
    for (int idx = tid; idx < 56*112; idx += 256){
      int r = idx / 112, k = idx % 112;
      int kg = kc*112 + k;
      s_mw[r*116 + k] = (r < 55 && kg < 220) ? mask_W[((size_t)st*55 + r)*220 + kg] : 0.f;
    }
    __syncthreads();
    if (ot < 14){
      for (int k4 = 0; k4 < 112; k4 += 4){
        float4 a[4], wb[4];
        for (int c = 0; c < 4; ++c) a[c]  = *(float4*)&s_mw[(ot*4+c)*116 + k4];
        for (int j = 0; j < 4; ++j) wb[j] = *(float4*)&s_wb[(btl*4+j)*116 + k4];
        for (int c = 0; c < 4; ++c)
          for (int j = 0; j < 4; ++j)
            acc[c][j] += a[c].x*wb[j].x + a[c].y*wb[j].y + a[c].z*wb[j].z + a[c].w*wb[j].w;
      }
    }
  }
  if (ot < 14){
    for (int c = 0; c < 4; ++c){
      int row = ot*4 + c;
      if (row < 55){
        float mb = mask_b[st*55 + row];
        float4 v; v.x = acc[c][0]+mb; v.y = acc[c][1]+mb; v.z = acc[c][2]+mb; v.w = acc[c][3]+mb;
        *(float4*)&m1[(size_t)(st*55+row)*B_ + b0 + btl*4] = v;
      }
    }
  }
}

// -------- per-row batch stats (mean, rsqrt(var+eps)) ------------------------
__global__ __launch_bounds__(256) void k_stats(const float* __restrict__ x, float* __restrict__ stats){
  const int row = blockIdx.x, tid = threadIdx.x;
  const float* xr = x + (size_t)row*B_;
  float s = 0.f, s2 = 0.f;
  for (int i = tid; i < B_; i += 256){ float v = xr[i]; s += v; s2 += v*v; }
  for (int off = 32; off > 0; off >>= 1){ s += __shfl_down(s, off); s2 += __shfl_down(s2, off); }
  __shared__ float red[8];
  if ((tid & 63) == 0){ red[(tid>>6)*2] = s; red[(tid>>6)*2+1] = s2; }
  __syncthreads();
  if (tid == 0){
    float Ssum = red[0]+red[2]+red[4]+red[6], S2 = red[1]+red[3]+red[5]+red[7];
    float mean = Ssum*(1.f/B_), var = S2*(1.f/B_) - mean*mean;
    stats[row*2] = mean; stats[row*2+1] = rsqrtf(fmaxf(var, 0.f) + EPSf);
  }
}

// -------- fused stats for two row-batches (m1: n1 rows, then x2) ------------
__global__ __launch_bounds__(256) void k_stats2(const float* __restrict__ x1, const float* __restrict__ x2,
                                                int n1, float* __restrict__ st1o, float* __restrict__ st2o){
  const int row = blockIdx.x, tid = threadIdx.x;
  const float* xr; float* sto;
  if (row < n1){ xr = x1 + (size_t)row*B_; sto = st1o + row*2; }
  else { int r = row - n1; xr = x2 + (size_t)r*B_; sto = st2o + r*2; }
  float s = 0.f, s2 = 0.f;
  for (int i = tid; i < B_; i += 256){ float v = xr[i]; s += v; s2 += v*v; }
  for (int off = 32; off > 0; off >>= 1){ s += __shfl_down(s, off); s2 += __shfl_down(s2, off); }
  __shared__ float red[8];
  if ((tid & 63) == 0){ red[(tid>>6)*2] = s; red[(tid>>6)*2+1] = s2; }
  __syncthreads();
  if (tid == 0){
    float Ssum = red[0]+red[2]+red[4]+red[6], S2 = red[1]+red[3]+red[5]+red[7];
    float mean = Ssum*(1.f/B_), var = S2*(1.f/B_) - mean*mean;
    sto[0] = mean; sto[1] = rsqrtf(fmaxf(var, 0.f) + EPSf);
  }
}

// -------- interlinf+last1: bn/tanh/relu inter + softmax linf + W1 GEMM ------
__global__ __launch_bounds__(128) void k_interlinf(
    const int* __restrict__ cat, const float* __restrict__ num,
    const float* __restrict__ embT, const float* __restrict__ linT,
    const float* __restrict__ uW, const float* __restrict__ ub,
    const float* __restrict__ iW, const float* __restrict__ ib,
    const float* __restrict__ ulW, const float* __restrict__ ulb,
    const float* __restrict__ ilW, const float* __restrict__ ilb,
    const float* __restrict__ m1, const float* __restrict__ stm,
    const float* __restrict__ lt1, const float* __restrict__ stl,
    const float* __restrict__ att_W, const float* __restrict__ interact_w,
    const float* __restrict__ bias_p,
    const float* __restrict__ W1, const float* __restrict__ b1,
    float* __restrict__ h1)
{
  __shared__ float s_fld[NF_*E_];
  __shared__ float s_lf[NF_*E_];
  __shared__ float s_co[110];
  __shared__ float s_lw[22];
  __shared__ float s_h[512];
  const int b = blockIdx.x, e = threadIdx.x;
  const int* cb = cat + (size_t)b*10;
  const int scen = cb[0];

  for (int j = 0; j < 9; ++j){
    int id = cb[1+j] + j*1000;
    s_fld[j*E_+e] = embT[(size_t)id*128 + e];
    s_lf[j*E_+e]  = linT[(size_t)id*128 + e];
  }
  {
    float a0 = ub[e], a1 = ulb[e];
    for (int k = 0; k < 23; ++k){ float x = num[(size_t)b*63 + k]; a0 += x*uW[e*23+k]; a1 += x*ulW[e*23+k]; }
    s_fld[9*E_+e] = a0; s_lf[9*E_+e] = a1;
    float a2 = ib[e], a3 = ilb[e];
    for (int k = 0; k < 40; ++k){ float x = num[(size_t)b*63 + 23 + k]; a2 += x*iW[e*40+k]; a3 += x*ilW[e*40+k]; }
    s_fld[10*E_+e] = a2; s_lf[10*E_+e] = a3;
  }
  if (e < 110){
    int t = e/55, f = e%55, row = (scen*T_+t)*55 + f;
    float v = (m1[(size_t)row*B_+b] - stm[row*2]) * stm[row*2+1];
    v = fmaxf(tanhf(v), 0.f);
    s_co[e] = v * att_W[(scen*T_+t)*55 + f];
  }
  if (e < 22){
    int t = e/11, f = e%11, row = (scen*T_+t)*11 + f;
    s_lw[e] = (lt1[(size_t)row*B_+b] - stl[row*2]) * stl[row*2+1];
  }
  __syncthreads();
  if (e < 2){
    int t = e; float mx = -1e30f;
    for (int f = 0; f < 11; ++f) mx = fmaxf(mx, s_lw[t*11+f]);
    float sum = 0.f;
    for (int f = 0; f < 11; ++f){ float x = __expf(s_lw[t*11+f]-mx); s_lw[t*11+f] = x; sum += x; }
    float inv = 1.f/sum;
    for (int f = 0; f < 11; ++f) s_lw[t*11+f] *= inv;
  }
  __syncthreads();
  {
    float a0 = 0.f, a1 = 0.f;
    for (int f = 0; f < 55; ++f){
      float pe = s_fld[PR[f]*E_+e] * s_fld[PC[f]*E_+e] * interact_w[f];
      a0 += s_co[f]*pe; a1 += s_co[55+f]*pe;
    }
    s_h[0*256 + e] = a0;
    s_h[1*256 + e] = a1;
  }
  for (int t = 0; t < 2; ++t){
    float acc = bias_p[(size_t)(t*S_+scen)*E_ + e];
    for (int f = 0; f < 11; ++f) acc += s_lw[t*11+f] * s_lf[f*E_+e];
    s_h[t*256 + 128 + e] = acc;
  }
  __syncthreads();
  if (e < 80){
    int t = e / 40, o = e % 40;
    float acc = b1[t*40 + o];
    const float4* wr = (const float4*)(W1 + (size_t)(t*40 + o)*256);
    const float4* hh = (const float4*)(s_h + t*256);
    for (int i = 0; i < 64; ++i){
      float4 w = wr[i], h = hh[i];
      acc += h.x*w.x; acc += h.y*w.y; acc += h.z*w.z; acc += h.w*w.w;
    }
    h1[(size_t)(t*40 + o)*B_ + b] = acc;
  }
}

// -------- final MLP tail ----------------------------------------------------
__global__ __launch_bounds__(256) void k_last2(const float* __restrict__ h1, const float* __restrict__ st1,
    const float* __restrict__ W2, const float* __restrict__ b2v, float* __restrict__ h2){
  int bz = blockIdx.x, t = bz/16, bc = bz%16, tid = threadIdx.x, b = bc*256 + tid;
  __shared__ float s_w2[1280];
  for (int k = tid; k < 1280; k += 256) s_w2[k] = W2[t*1280 + k];
  __syncthreads();
  float hv[40];
  for (int i = 0; i < 40; ++i){
    int row = t*40 + i;
    hv[i] = fmaxf((h1[(size_t)row*B_+b] - st1[row*2]) * st1[row*2+1], 0.f);
  }
  for (int o = 0; o < 32; ++o){
    float acc = b2v[t*32+o];
    for (int i = 0; i < 40; ++i) acc += hv[i] * s_w2[o*40+i];
    h2[(size_t)(t*32+o)*B_ + b] = acc;
  }
}

__global__ __launch_bounds__(256) void k_last3(const float* __restrict__ h2, const float* __restrict__ st2,
    const float* __restrict__ W3, const float* __restrict__ b3v, float* __restrict__ h3){
  int bz = blockIdx.x, t = bz/16, bc = bz%16, tid = threadIdx.x, b = bc*256 + tid;
  __shared__ float s_w3[256];
  if (tid < 256) s_w3[tid] = W3[t*256 + tid];
  __syncthreads();
  float hv[32];
  for (int i = 0; i < 32; ++i){
    int row = t*32 + i;
    hv[i] = fmaxf((h2[(size_t)row*B_+b] - st2[row*2]) * st2[row*2+1], 0.f);
  }
  for (int o = 0; o < 8; ++o){
    float acc = b3v[t*8+o];
    for (int i = 0; i < 32; ++i) acc += hv[i] * s_w3[o*32+i];
    h3[(size_t)(t*8+o)*B_ + b] = acc;
  }
}

__global__ __launch_bounds__(256) void k_out(const float* __restrict__ h3, const float* __restrict__ st3,
    const float* __restrict__ W4, const float* __restrict__ b4v, float* __restrict__ out){
  int idx = blockIdx.x*256 + threadIdx.x;
  int t = idx / B_, b = idx % B_;
  float acc = b4v[t];
  for (int i = 0; i < 8; ++i){
    int row = t*8 + i;
    float v = fmaxf((h3[(size_t)row*B_+b] - st3[row*2]) * st3[row*2+1], 0.f);
    acc += v * W4[t*8+i];
  }
  out[idx] = 1.f/(1.f + __expf(-acc));
}

extern "C" void kernel_launch(void* const* d_in, const int* in_sizes, int n_in,
                              void* d_out, int out_size, void* d_ws, size_t ws_size,
                              hipStream_t stream)
{
  const int*   cat      = (const int*)  d_in[0];
  const float* num      = (const float*)d_in[1];
  const float* embT     = (const float*)d_in[2];
  const float* linT     = (const float*)d_in[3];
  const float* uW = (const float*)d_in[4];  const float* ub = (const float*)d_in[5];
  const float* iW = (const float*)d_in[6];  const float* ib = (const float*)d_in[7];
  const float* ulW = (const float*)d_in[8]; const float* ulb = (const float*)d_in[9];
  const float* ilW = (const float*)d_in[10];const float* ilb = (const float*)d_in[11];
  const float* scen_emb = (const float*)d_in[12];
  const float* task_emb = (const float*)d_in[13];
  const float* st_w     = (const float*)d_in[14];
  const float* interact_w=(const float*)d_in[15];
  const float* sbW = (const float*)d_in[16]; const float* sbb = (const float*)d_in[17];
  const float* lsbW = (const float*)d_in[18];const float* lsbb = (const float*)d_in[19];
  const float* shW = (const float*)d_in[20]; const float* shb = (const float*)d_in[21];
  const float* spW = (const float*)d_in[22]; const float* spb = (const float*)d_in[23];
  const float* lshW = (const float*)d_in[24];const float* lshb = (const float*)d_in[25];
  const float* lspW = (const float*)d_in[26];const float* lspb = (const float*)d_in[27];
  const float* gW = (const float*)d_in[28];  const float* gb = (const float*)d_in[29];
  const float* lgW = (const float*)d_in[30]; const float* lgb = (const float*)d_in[31];
  const float* mW = (const float*)d_in[32];  const float* mb = (const float*)d_in[33];
  const float* attW = (const float*)d_in[34];
  const float* ltW = (const float*)d_in[35]; const float* ltb = (const float*)d_in[36];
  const float* biasP = (const float*)d_in[37];
  const float* W1 = (const float*)d_in[38];  const float* b1 = (const float*)d_in[39];
  const float* W2 = (const float*)d_in[40];  const float* b2v = (const float*)d_in[41];
  const float* W3 = (const float*)d_in[42];  const float* b3v = (const float*)d_in[43];
  const float* W4 = (const float*)d_in[44];  const float* b4v = (const float*)d_in[45];
  float* out = (float*)d_out;

  float* ws = (float*)d_ws;
  size_t o = 0;
  float* Wub  = ws + o; o += 4352;   // bf16 64x136 as ushorts
  float* lWub = ws + o; o += 4352;   // bf16 64x136 as ushorts
  float* w_g  = ws + o; o += (size_t)B_*8*224;
  float* m1   = ws + o; o += (size_t)440*B_;
  float* stm  = ws + o; o += 880;
  float* lt1  = ws + o; o += (size_t)88*B_;
  float* stl  = ws + o; o += 176;
  float* h1   = ws + o; o += (size_t)80*B_;
  float* st1  = ws + o; o += 160;
  float* h2   = ws + o; o += (size_t)64*B_;
  float* st2  = ws + o; o += 128;
  float* h3   = ws + o; o += (size_t)16*B_;
  float* st3  = ws + o; o += 32;

  k_prep<<<34, 256, 0, stream>>>(gW, lgW, sbW, lsbW, (unsigned short*)Wub, (unsigned short*)lWub);
  k_moe12<<<B_, 256, 0, stream>>>(cat, num, embT, linT, uW, ub, iW, ib, ulW, ulb, ilW, ilb,
                                  scen_emb, task_emb, st_w, interact_w, sbb, shW, shb,
                                  spW, spb, gW, gb, (const unsigned short*)Wub,
                                  lsbb, lshW, lshb, lspW, lspb, lgW, lgb, ltW, ltb,
                                  (const unsigned short*)lWub, w_g, lt1);
  k_mask<<<512, 256, 0, stream>>>(w_g, mW, mb, m1);
  k_stats2<<<528, 256, 0, stream>>>(m1, lt1, 440, stm, stl);
  k_interlinf<<<B_, 128, 0, stream>>>(cat, num, embT, linT, uW, ub, iW, ib, ulW, ulb, ilW, ilb,
                                      m1, stm, lt1, stl, attW, interact_w, biasP,
                                      W1, b1, h1);
  k_stats<<<80, 256, 0, stream>>>(h1, st1);
  k_last2<<<32, 256, 0, stream>>>(h1, st1, W2, b2v, h2);
  k_stats<<<64, 256, 0, stream>>>(h2, st2);
  k_last3<<<32, 256, 0, stream>>>(h2, st2, W3, b3v, h3);
  k_stats<<<16, 256, 0, stream>>>(h3, st3);
  k_out<<<32, 256, 0, stream>>>(h3, st3, W4, b4v, out);
}